// Round 5
// baseline (629.320 us; speedup 1.0000x reference)
//
#include <hip/hip_runtime.h>
#include <hip/hip_bf16.h>
#include <math.h>

#define DIM 256
#define NB 4
#define LQ 1000
#define MLPD 512
#define LIN 21824
#define ROWS_X 4000
#define ROWS_SRC 87296
#define ATT_SCALE 0.17677669529663687f  /* 32^-0.5 */
#define LDK 72   /* padded LDS row (bf16 elems): 144 B, 16B-aligned */
#define VLAYER ((size_t)ROWS_SRC*256)

typedef __hip_bfloat16 bf16;
typedef __attribute__((ext_vector_type(8))) short short8;
typedef __attribute__((ext_vector_type(4))) float floatx4;

__device__ __forceinline__ float rdv(const void* p, int f, size_t i){
    if (f) return ((const float*)p)[i];
    unsigned u = ((unsigned)((const unsigned short*)p)[i]) << 16;
    union { unsigned u; float f; } c; c.u = u; return c.f;
}
__device__ __forceinline__ short f2bs(float v){
    bf16 h = __float2bfloat16(v);
    return *reinterpret_cast<short*>(&h);
}
__device__ __forceinline__ float bs2f(short s){
    union { unsigned u; float f; } c; c.u = ((unsigned)(unsigned short)s) << 16; return c.f;
}

// ---------- dtype detect ----------
__global__ void detect_kernel(const void* __restrict__ x, int* __restrict__ flag){
    const unsigned short* u = (const unsigned short*)x;
    int t = threadIdx.x;
    bool hit = false;
    #pragma unroll
    for (int k = 0; k < 4; ++k) {
        unsigned short b = u[(t*4 + k)*2];
        union { unsigned u; float f; } c; c.u = ((unsigned)b) << 16;
        if (!(fabsf(c.f) <= 1000.f)) hit = true;
    }
    unsigned long long m = __ballot(hit);
    __shared__ unsigned long long red[4];
    if ((t & 63) == 0) red[t >> 6] = m;
    __syncthreads();
    if (t == 0) flag[0] = ((red[0]|red[1]|red[2]|red[3]) != 0ULL) ? 1 : 0;
}

// ---------- one packed prep kernel: 13 convs + cpf + statzero + catb + pe ----------
struct PrepTab { const void* src[15]; float* dst[17]; int n[17]; int bs[18]; };
__global__ void prep_kernel(PrepTab t, const void* __restrict__ offb,
                            const void* __restrict__ awb, const void* __restrict__ pw,
                            const void* __restrict__ pb, const void* __restrict__ cp,
                            const int* __restrict__ flag){
    int f = flag[0];
    int bid = blockIdx.x;
    int j = 0;
    #pragma unroll 1
    while (bid >= t.bs[j+1]) ++j;
    int i = (bid - t.bs[j])*256 + threadIdx.x;
    if (i >= t.n[j]) return;
    if (j < 15) {
        t.dst[j][i] = t.src[j] ? rdv(t.src[j], f, i) : 0.f;
    } else if (j == 15) {           // catb -> oab[2][480]
        int layer = i / 480, idx = i - layer*480;
        float v = (idx < 320) ? rdv(offb, f, (size_t)layer*320 + idx)
                              : rdv(awb,  f, (size_t)layer*160 + idx - 320);
        t.dst[15][i] = v;
    } else {                        // pe[row][256]
        int row = i >> 8, c = i & 255;
        float cx = rdv(cp, f, (size_t)row*2), cy = rdv(cp, f, (size_t)row*2 + 1);
        t.dst[16][i] = cx*rdv(pw, f, c) + cy*rdv(pw, f, DIM + c) + rdv(pb, f, c);
    }
}

// ---------- all weight transposes in ONE launch, with optional K-dim scale fold ----------
struct WT { const void* src[8]; short* dst[8]; const float* scl[8];
            int K[8]; int N[8]; int ld[8]; int ro[8]; };
__global__ void wtransall_kernel(WT t, const int* __restrict__ flag){
    int j = blockIdx.z >> 1, b = blockIdx.z & 1;
    int K = t.K[j], N = t.N[j];
    int k0 = blockIdx.x*32, n0 = blockIdx.y*32;
    if (k0 >= K || n0 >= N) return;   // uniform per block, before any sync
    int f = flag[0];
    __shared__ float tt[32][33];
    int tx = threadIdx.x & 31, ty = threadIdx.x >> 5;
    size_t base = (size_t)b * K * N;
    for (int i = ty; i < 32; i += 8) {
        int k = k0 + i, n = n0 + tx;
        tt[i][tx] = (k < K && n < N) ? rdv(t.src[j], f, base + (size_t)k*N + n) : 0.f;
    }
    __syncthreads();
    int ld = t.ld[j], ro = t.ro[j];
    const float* sc = t.scl[j];
    for (int i = ty; i < 32; i += 8) {
        int n = n0 + i, k = k0 + tx;
        if (n < N && k < K) {
            float v = tt[tx][i];
            if (sc) v *= sc[(size_t)b*K + k];
            t.dst[j][(size_t)b*ld*K + (size_t)(ro+n)*K + k] = f2bs(v);
        }
    }
}

// ---------- bias folds: dst[b][n] = bvec[b] @ W[b][:,n] (+base[b][n]) ----------
struct BFT { const void* W[3]; const float* bv[3]; const float* base[3];
             float* dst[3]; int N[3]; };
__global__ __launch_bounds__(256) void biasfold_kernel(BFT t, const int* __restrict__ flag){
    int f = flag[0];
    int x = blockIdx.x, b = blockIdx.y;
    int j, n;
    if (x < 768)       { j = 0; n = x; }
    else if (x < 1280) { j = 1; n = x - 768; }
    else               { j = 2; n = x - 1280; }
    int N = t.N[j];
    int k = threadIdx.x;
    float part = t.bv[j][(size_t)b*256 + k] *
                 rdv(t.W[j], f, (size_t)b*256*N + (size_t)k*N + n);
    #pragma unroll
    for (int o = 32; o; o >>= 1) part += __shfl_xor(part, o, 64);
    __shared__ float red[4];
    int wave = k >> 6, lane = k & 63;
    if (lane == 0) red[wave] = part;
    __syncthreads();
    if (k == 0) {
        float s = red[0] + red[1] + red[2] + red[3];
        if (t.base[j]) s += t.base[j][(size_t)b*N + n];
        t.dst[j][(size_t)b*N + n] = s;
    }
}

// ---------- merged: src LN-normalize + x convert/sums ----------
__global__ __launch_bounds__(256) void statsconvx_kernel(const void* __restrict__ src,
        const void* __restrict__ x, const float* __restrict__ pe,
        const int* __restrict__ flag, bf16* __restrict__ srcn,
        float* __restrict__ xf, float2* __restrict__ st){
    int f = flag[0];
    int wave = threadIdx.x >> 6, lane = threadIdx.x & 63;
    int bid = blockIdx.x;
    if (bid < ROWS_SRC/4) {
        int row = bid*4 + wave;
        float v0, v1, v2, v3;
        if (f) {
            float4 xx = *(const float4*)((const float*)src + (size_t)row*DIM + lane*4);
            v0 = xx.x; v1 = xx.y; v2 = xx.z; v3 = xx.w;
        } else {
            ushort4 u = *(const ushort4*)((const unsigned short*)src + (size_t)row*DIM + lane*4);
            v0 = bs2f((short)u.x); v1 = bs2f((short)u.y);
            v2 = bs2f((short)u.z); v3 = bs2f((short)u.w);
        }
        float s  = v0 + v1 + v2 + v3;
        float s2 = v0*v0 + v1*v1 + v2*v2 + v3*v3;
        #pragma unroll
        for (int o = 32; o; o >>= 1) {
            s  += __shfl_xor(s,  o, 64);
            s2 += __shfl_xor(s2, o, 64);
        }
        float mean = s * (1.f/DIM);
        float rstd = rsqrtf(s2 * (1.f/DIM) - mean*mean + 1e-5f);
        ushort4 o4;
        o4.x = (unsigned short)f2bs((v0-mean)*rstd);
        o4.y = (unsigned short)f2bs((v1-mean)*rstd);
        o4.z = (unsigned short)f2bs((v2-mean)*rstd);
        o4.w = (unsigned short)f2bs((v3-mean)*rstd);
        *(ushort4*)((unsigned short*)srcn + (size_t)row*DIM + lane*4) = o4;
    } else {
        int row = (bid - ROWS_SRC/4)*4 + wave;
        float4 v;
        if (f) v = *(const float4*)((const float*)x + (size_t)row*DIM + lane*4);
        else {
            ushort4 u = *(const ushort4*)((const unsigned short*)x + (size_t)row*DIM + lane*4);
            v = make_float4(bs2f((short)u.x), bs2f((short)u.y), bs2f((short)u.z), bs2f((short)u.w));
        }
        *(float4*)(xf + (size_t)row*DIM + lane*4) = v;
        float4 p = *(const float4*)(pe + (size_t)row*DIM + lane*4);
        float a0 = v.x+p.x, a1 = v.y+p.y, a2 = v.z+p.z, a3 = v.w+p.w;
        float s  = a0+a1+a2+a3;
        float s2 = a0*a0+a1*a1+a2*a2+a3*a3;
        #pragma unroll
        for (int o = 32; o; o >>= 1) {
            s  += __shfl_xor(s,  o, 64);
            s2 += __shfl_xor(s2, o, 64);
        }
        if (lane == 0) st[row] = make_float2(s, s2);
    }
}

// ---------- MFMA GEMM 64 rows x 128 cols per block, register-prefetch staging ----------
// AMODE 2: A bf16; AMODE 3: A fp32 LN(g,b in LDS) +Apost; AMODE 4: normalize-only +Apre.
template<int AMODE>
__global__ __launch_bounds__(256) void mgemm_kernel(
    const void* __restrict__ Asrc, const float2* __restrict__ asums,
    const float* __restrict__ ag, const float* __restrict__ ab,
    const float* __restrict__ Apre, const float* __restrict__ Apost,
    const short* __restrict__ Wt, const float* __restrict__ bias, const float* res,
    void* Cout, int M, int K, int N, int act, int cbf,
    float2* __restrict__ statacc, const float* __restrict__ sepe,
    void* __restrict__ fin, const int* __restrict__ flag){
    __shared__ short As[64*LDK];
    __shared__ short Bs[128*LDK];
    __shared__ float gsh[256], bsh[256];
    int tid = threadIdx.x;
    int wave = tid >> 6, lane = tid & 63;
    int wm = wave >> 1, wn = wave & 1;
    int quad = lane >> 4, l16 = lane & 15;
    int row0 = blockIdx.x*64, col0 = blockIdx.y*128;
    floatx4 acc[2][4];
    #pragma unroll
    for (int i = 0; i < 2; ++i)
        #pragma unroll
        for (int j = 0; j < 4; ++j)
            acc[i][j] = (floatx4){0.f,0.f,0.f,0.f};

    int r  = tid >> 2;
    int kc = (tid & 3) * 16;
    int gr = row0 + r;
    int gc0 = col0 + r;
    int gc1 = col0 + 64 + r;
    const short8 z8 = {0,0,0,0,0,0,0,0};

    if (AMODE == 3) {
        gsh[tid] = ag[tid]; bsh[tid] = ab[tid];
        __syncthreads();
    }
    const float* aux = Apre ? Apre : Apost;   // at most one non-null per call
    float mean = 0.f, rstd = 0.f;
    if (AMODE != 2 && gr < M) {
        float2 stt = asums[gr];
        mean = stt.x * (1.f/256.f);
        rstd = rsqrtf(stt.y*(1.f/256.f) - mean*mean + 1e-5f);
    }
    // prefetch registers (k-step 0)
    short8 ra0, ra1, rb0, rb1, rb2, rb3;
    float4 rx0, rx1, rx2, rx3, rq0, rq1, rq2, rq3;
    if (gr < M) {
        if (AMODE == 2) {
            const short8* p = (const short8*)((const short*)Asrc + (size_t)gr*K + kc);
            ra0 = p[0]; ra1 = p[1];
        } else {
            const float4* p = (const float4*)((const float*)Asrc + (size_t)gr*K + kc);
            rx0 = p[0]; rx1 = p[1]; rx2 = p[2]; rx3 = p[3];
            if (aux) {
                const float4* q = (const float4*)(aux + (size_t)gr*K + kc);
                rq0 = q[0]; rq1 = q[1]; rq2 = q[2]; rq3 = q[3];
            }
        }
    }
    if (gc0 < N) {
        const short8* p = (const short8*)(Wt + (size_t)gc0*K + kc);
        rb0 = p[0]; rb1 = p[1];
    }
    if (gc1 < N) {
        const short8* p = (const short8*)(Wt + (size_t)gc1*K + kc);
        rb2 = p[0]; rb3 = p[1];
    }

    for (int k0 = 0; k0 < K; k0 += 64) {
        short8 a0 = z8, a1 = z8;
        if (gr < M) {
            if (AMODE == 2) { a0 = ra0; a1 = ra1; }
            else {
                float av[16] = {rx0.x,rx0.y,rx0.z,rx0.w, rx1.x,rx1.y,rx1.z,rx1.w,
                                rx2.x,rx2.y,rx2.z,rx2.w, rx3.x,rx3.y,rx3.z,rx3.w};
                float qv[16] = {rq0.x,rq0.y,rq0.z,rq0.w, rq1.x,rq1.y,rq1.z,rq1.w,
                                rq2.x,rq2.y,rq2.z,rq2.w, rq3.x,rq3.y,rq3.z,rq3.w};
                if (AMODE == 4) {
                    if (Apre) {
                        #pragma unroll
                        for (int j = 0; j < 16; ++j) av[j] += qv[j];
                    }
                    #pragma unroll
                    for (int j = 0; j < 16; ++j) av[j] = (av[j] - mean)*rstd;
                } else { // AMODE 3
                    #pragma unroll
                    for (int j = 0; j < 16; ++j)
                        av[j] = (av[j] - mean)*rstd*gsh[k0+kc+j] + bsh[k0+kc+j];
                    if (Apost) {
                        #pragma unroll
                        for (int j = 0; j < 16; ++j) av[j] += qv[j];
                    }
                }
                #pragma unroll
                for (int j = 0; j < 8; ++j) { a0[j] = f2bs(av[j]); a1[j] = f2bs(av[8+j]); }
            }
        }
        *(short8*)&As[r*LDK + kc]     = a0;
        *(short8*)&As[r*LDK + kc + 8] = a1;
        short8 b0 = z8, b1 = z8, b2 = z8, b3 = z8;
        if (gc0 < N) { b0 = rb0; b1 = rb1; }
        if (gc1 < N) { b2 = rb2; b3 = rb3; }
        *(short8*)&Bs[r*LDK + kc]          = b0;
        *(short8*)&Bs[r*LDK + kc + 8]      = b1;
        *(short8*)&Bs[(64+r)*LDK + kc]     = b2;
        *(short8*)&Bs[(64+r)*LDK + kc + 8] = b3;
        // issue next k-step's loads before the barrier (latency hides under MFMA)
        int kn = k0 + 64;
        if (kn < K) {
            if (gr < M) {
                if (AMODE == 2) {
                    const short8* p = (const short8*)((const short*)Asrc + (size_t)gr*K + kn + kc);
                    ra0 = p[0]; ra1 = p[1];
                } else {
                    const float4* p = (const float4*)((const float*)Asrc + (size_t)gr*K + kn + kc);
                    rx0 = p[0]; rx1 = p[1]; rx2 = p[2]; rx3 = p[3];
                    if (aux) {
                        const float4* q = (const float4*)(aux + (size_t)gr*K + kn + kc);
                        rq0 = q[0]; rq1 = q[1]; rq2 = q[2]; rq3 = q[3];
                    }
                }
            }
            if (gc0 < N) {
                const short8* p = (const short8*)(Wt + (size_t)gc0*K + kn + kc);
                rb0 = p[0]; rb1 = p[1];
            }
            if (gc1 < N) {
                const short8* p = (const short8*)(Wt + (size_t)gc1*K + kn + kc);
                rb2 = p[0]; rb3 = p[1];
            }
        }
        __syncthreads();
        #pragma unroll
        for (int kb = 0; kb < 64; kb += 32) {
            short8 af[2], bfr[4];
            #pragma unroll
            for (int mi = 0; mi < 2; ++mi)
                af[mi] = *(const short8*)&As[(wm*32 + mi*16 + l16)*LDK + kb + quad*8];
            #pragma unroll
            for (int ni = 0; ni < 4; ++ni)
                bfr[ni] = *(const short8*)&Bs[(wn*64 + ni*16 + l16)*LDK + kb + quad*8];
            #pragma unroll
            for (int mi = 0; mi < 2; ++mi)
                #pragma unroll
                for (int ni = 0; ni < 4; ++ni)
                    acc[mi][ni] = __builtin_amdgcn_mfma_f32_16x16x32_bf16(
                        af[mi], bfr[ni], acc[mi][ni], 0, 0, 0);
        }
        __syncthreads();
    }
    // epilogue
    float vout[2][4][4];
    #pragma unroll
    for (int mi = 0; mi < 2; ++mi) {
        int rbase = row0 + wm*32 + mi*16 + quad*4;
        #pragma unroll
        for (int ni = 0; ni < 4; ++ni) {
            int c = col0 + wn*64 + ni*16 + l16;
            #pragma unroll
            for (int r2 = 0; r2 < 4; ++r2) {
                int rr = rbase + r2;
                float v = 0.f;
                if (c < N && rr < M) {
                    v = acc[mi][ni][r2];
                    if (bias) v += bias[c];
                    if (act) {  // tanh-gelu == v*sigmoid(2y)
                        float z = fminf(1.5957691216057308f*(v + 0.044715f*v*v*v), 60.f);
                        float e = __expf(z);
                        v = v * e / (e + 1.f);
                    }
                    if (res) v += res[(size_t)rr*N + c];
                }
                vout[mi][ni][r2] = v;
            }
        }
    }
    int fflag = 0;
    if (fin) fflag = flag[0];
    #pragma unroll
    for (int mi = 0; mi < 2; ++mi) {
        int rbase = row0 + wm*32 + mi*16 + quad*4;
        #pragma unroll
        for (int ni = 0; ni < 4; ++ni) {
            int c = col0 + wn*64 + ni*16 + l16;
            if (c >= N) continue;
            #pragma unroll
            for (int r2 = 0; r2 < 4; ++r2) {
                int rr = rbase + r2;
                if (rr >= M) continue;
                float v = vout[mi][ni][r2];
                if (fin) {
                    float w = isfinite(v) ? v : 0.f;
                    if (fflag) ((float*)fin)[(size_t)rr*N + c] = w;
                    else       ((bf16*)fin)[(size_t)rr*N + c] = __float2bfloat16(w);
                } else if (cbf) ((bf16*)Cout)[(size_t)rr*N + c] = __float2bfloat16(v);
                else            ((float*)Cout)[(size_t)rr*N + c] = v;
            }
        }
    }
    if (statacc) {
        #pragma unroll
        for (int mi = 0; mi < 2; ++mi) {
            int rbase = row0 + wm*32 + mi*16 + quad*4;
            #pragma unroll
            for (int r2 = 0; r2 < 4; ++r2) {
                int rr = rbase + r2;
                float sv = 0.f, sq = 0.f;
                #pragma unroll
                for (int ni = 0; ni < 4; ++ni) {
                    int c = col0 + wn*64 + ni*16 + l16;
                    float v = vout[mi][ni][r2];
                    if (sepe && rr < M && c < N) v += sepe[(size_t)rr*256 + c];
                    sv += v; sq += v*v;
                }
                #pragma unroll
                for (int o = 1; o < 16; o <<= 1) {
                    sv += __shfl_xor(sv, o, 64);
                    sq += __shfl_xor(sq, o, 64);
                }
                if (l16 == 0 && rr < M) {
                    atomicAdd(&statacc[rr].x, sv);
                    atomicAdd(&statacc[rr].y, sq);
                }
            }
        }
    }
}

// ---------- MFMA GEMM 128x128, both layers' value proj, col-fastest grid ----------
// grid (4, 682): x = col tile (shares A panel across adjacent blocks), y = row tile.
// Epilogue stages C through LDS -> fully coalesced 16B head-major stores.
__global__ __launch_bounds__(256) void mgemm128_kernel(
    const short* __restrict__ A, const short* __restrict__ Wt,
    const float* __restrict__ bias, bf16* __restrict__ valall){
    const int K = 256;
    __shared__ short lds[2*128*LDK];   // As | Bs; reused as C-tile (128x136) in epilogue
    short* As = lds;
    short* Bs = lds + 128*LDK;
    int tid = threadIdx.x;
    int wave = tid >> 6, lane = tid & 63;
    int wm = wave >> 1, wn = wave & 1;
    int quad = lane >> 4, l16 = lane & 15;
    int row0 = blockIdx.y*128, col0 = blockIdx.x*128;
    floatx4 acc[4][4];
    #pragma unroll
    for (int i = 0; i < 4; ++i)
        #pragma unroll
        for (int j = 0; j < 4; ++j)
            acc[i][j] = (floatx4){0.f,0.f,0.f,0.f};

    short8 pa[2][2], pb2[2][2];
    #pragma unroll
    for (int i = 0; i < 2; ++i) {
        int idx = tid + i*256;
        int rr = idx >> 2, kk = (idx & 3)*16;
        const short8* p = (const short8*)(A + (size_t)(row0+rr)*K + kk);
        pa[i][0] = p[0]; pa[i][1] = p[1];
        const short8* pb = (const short8*)(Wt + (size_t)(col0+rr)*K + kk);
        pb2[i][0] = pb[0]; pb2[i][1] = pb[1];
    }
    for (int k0 = 0; k0 < K; k0 += 64) {
        #pragma unroll
        for (int i = 0; i < 2; ++i) {
            int idx = tid + i*256;
            int rr = idx >> 2, kk = (idx & 3)*16;
            *(short8*)&As[rr*LDK + kk]     = pa[i][0];
            *(short8*)&As[rr*LDK + kk + 8] = pa[i][1];
            *(short8*)&Bs[rr*LDK + kk]     = pb2[i][0];
            *(short8*)&Bs[rr*LDK + kk + 8] = pb2[i][1];
        }
        int kn = k0 + 64;
        if (kn < K) {
            #pragma unroll
            for (int i = 0; i < 2; ++i) {
                int idx = tid + i*256;
                int rr = idx >> 2, kk = (idx & 3)*16;
                const short8* p = (const short8*)(A + (size_t)(row0+rr)*K + kn + kk);
                pa[i][0] = p[0]; pa[i][1] = p[1];
                const short8* pb = (const short8*)(Wt + (size_t)(col0+rr)*K + kn + kk);
                pb2[i][0] = pb[0]; pb2[i][1] = pb[1];
            }
        }
        __syncthreads();
        #pragma unroll
        for (int kb = 0; kb < 64; kb += 32) {
            short8 af[4], bfr[4];
            #pragma unroll
            for (int mi = 0; mi < 4; ++mi)
                af[mi] = *(const short8*)&As[(wm*64 + mi*16 + l16)*LDK + kb + quad*8];
            #pragma unroll
            for (int ni = 0; ni < 4; ++ni)
                bfr[ni] = *(const short8*)&Bs[(wn*64 + ni*16 + l16)*LDK + kb + quad*8];
            #pragma unroll
            for (int mi = 0; mi < 4; ++mi)
                #pragma unroll
                for (int ni = 0; ni < 4; ++ni)
                    acc[mi][ni] = __builtin_amdgcn_mfma_f32_16x16x32_bf16(
                        af[mi], bfr[ni], acc[mi][ni], 0, 0, 0);
        }
        __syncthreads();
    }
    // ---- epilogue: C tile -> LDS (bf16, +bias) -> coalesced head-major stores ----
    short* Cs = lds;   // 128 x 136 shorts = 34816 B <= 36864 B
    #pragma unroll
    for (int mi = 0; mi < 4; ++mi) {
        int lr = wm*64 + mi*16 + quad*4;
        #pragma unroll
        for (int ni = 0; ni < 4; ++ni) {
            int lc = wn*64 + ni*16 + l16;
            float bv = bias[col0 + lc];
            #pragma unroll
            for (int r2 = 0; r2 < 4; ++r2)
                Cs[(lr + r2)*136 + lc] = f2bs(acc[mi][ni][r2] + bv);
        }
    }
    __syncthreads();
    #pragma unroll
    for (int g = 0; g < 4; ++g) {
        int cbase = col0 + g*32;
        int l = cbase >> 8, h = (cbase & 255) >> 5;
        #pragma unroll
        for (int p = 0; p < 2; ++p) {
            int idx = p*256 + tid;
            int rr2 = idx >> 2;          // 0..127
            int dc = (idx & 3) * 8;      // 0,8,16,24
            short8 v = *(const short8*)&Cs[rr2*136 + g*32 + dc];
            int grr = row0 + rr2;
            unsigned n = (unsigned)grr / (unsigned)LIN;
            int pos = grr - (int)n*LIN;
            *(short8*)((short*)valall + (size_t)l*VLAYER
                       + ((size_t)(n*8+h)*LIN + pos)*32 + dc) = v;
        }
    }
}

// ---------- fused flash attention with K/V register prefetch ----------
__global__ __launch_bounds__(256) void fattn_kernel(const short* __restrict__ qkv,
                                                    bf16* __restrict__ out){
    int nh = blockIdx.y;
    int n = nh >> 3, h = nh & 7;
    int q0 = blockIdx.x * 64;
    __shared__ short Ks[64*40];
    __shared__ short VsT[32*72];
    __shared__ short Ps[64*72];
    int tid = threadIdx.x;
    int wave = tid >> 6, lane = tid & 63;
    int quad = lane >> 4, l16 = lane & 15;
    int r = tid >> 2, c8 = (tid & 3) * 8;
    const short8 z8 = {0,0,0,0,0,0,0,0};

    short8 qf = z8;
    {
        int gq = q0 + wave*16 + l16;
        if (gq < LQ) {
            short8 s = *(const short8*)(qkv + ((size_t)(n*LQ+gq))*768 + h*32 + quad*8);
            #pragma unroll
            for (int j = 0; j < 8; ++j) qf[j] = f2bs(bs2f(s[j]) * ATT_SCALE);
        }
    }
    floatx4 acc[2];
    acc[0] = (floatx4){0.f,0.f,0.f,0.f};
    acc[1] = (floatx4){0.f,0.f,0.f,0.f};
    float m[4], lsum[4];
    #pragma unroll
    for (int i = 0; i < 4; ++i) { m[i] = -3.0e38f; lsum[i] = 0.f; }

    short8 kvp = z8, vvp = z8;
    if (r < LQ) {
        const short* rp = qkv + ((size_t)(n*LQ+r))*768;
        kvp = *(const short8*)(rp + 256 + h*32 + c8);
        vvp = *(const short8*)(rp + 512 + h*32 + c8);
    }
    for (int k0 = 0; k0 < LQ; k0 += 64) {
        *(short8*)&Ks[r*40 + c8] = kvp;
        #pragma unroll
        for (int j = 0; j < 8; ++j) VsT[(c8+j)*72 + r] = vvp[j];
        short8 kvn = z8, vvn = z8;
        if (k0 + 64 < LQ) {
            int gk = k0 + 64 + r;
            if (gk < LQ) {
                const short* rp = qkv + ((size_t)(n*LQ+gk))*768;
                kvn = *(const short8*)(rp + 256 + h*32 + c8);
                vvn = *(const short8*)(rp + 512 + h*32 + c8);
            }
        }
        __syncthreads();
        floatx4 s4[4];
        #pragma unroll
        for (int kg = 0; kg < 4; ++kg) {
            short8 bfr = *(const short8*)&Ks[(kg*16 + l16)*40 + quad*8];
            s4[kg] = __builtin_amdgcn_mfma_f32_16x16x32_bf16(
                qf, bfr, (floatx4){0.f,0.f,0.f,0.f}, 0, 0, 0);
        }
        if (k0 + 64 > LQ) {
            #pragma unroll
            for (int kg = 0; kg < 4; ++kg)
                if (k0 + kg*16 + l16 >= LQ)
                    s4[kg] = (floatx4){-3.0e38f,-3.0e38f,-3.0e38f,-3.0e38f};
        }
        float fac[4], psum[4];
        #pragma unroll
        for (int r2 = 0; r2 < 4; ++r2) {
            float v = fmaxf(fmaxf(s4[0][r2], s4[1][r2]), fmaxf(s4[2][r2], s4[3][r2]));
            v = fmaxf(v, __shfl_xor(v, 1, 64));
            v = fmaxf(v, __shfl_xor(v, 2, 64));
            v = fmaxf(v, __shfl_xor(v, 4, 64));
            v = fmaxf(v, __shfl_xor(v, 8, 64));
            float mn = fmaxf(m[r2], v);
            fac[r2] = __expf(m[r2] - mn);
            m[r2] = mn;
            psum[r2] = 0.f;
        }
        #pragma unroll
        for (int kg = 0; kg < 4; ++kg)
            #pragma unroll
            for (int r2 = 0; r2 < 4; ++r2) {
                float pv = __expf(s4[kg][r2] - m[r2]);
                psum[r2] += pv;
                Ps[(wave*16 + quad*4 + r2)*72 + kg*16 + l16] = f2bs(pv);
            }
        #pragma unroll
        for (int r2 = 0; r2 < 4; ++r2) {
            psum[r2] += __shfl_xor(psum[r2], 1, 64);
            psum[r2] += __shfl_xor(psum[r2], 2, 64);
            psum[r2] += __shfl_xor(psum[r2], 4, 64);
            psum[r2] += __shfl_xor(psum[r2], 8, 64);
            lsum[r2] = lsum[r2]*fac[r2] + psum[r2];
        }
        #pragma unroll
        for (int ni = 0; ni < 2; ++ni)
            #pragma unroll
            for (int r2 = 0; r2 < 4; ++r2)
                acc[ni][r2] *= fac[r2];
        #pragma unroll
        for (int kb = 0; kb < 64; kb += 32) {
            short8 pf = *(const short8*)&Ps[(wave*16 + l16)*72 + kb + quad*8];
            #pragma unroll
            for (int ni = 0; ni < 2; ++ni) {
                short8 vf = *(const short8*)&VsT[(ni*16 + l16)*72 + kb + quad*8];
                acc[ni] = __builtin_amdgcn_mfma_f32_16x16x32_bf16(pf, vf, acc[ni], 0, 0, 0);
            }
        }
        __syncthreads();
        kvp = kvn; vvp = vvn;
    }
    #pragma unroll
    for (int r2 = 0; r2 < 4; ++r2) {
        int row = q0 + wave*16 + quad*4 + r2;
        if (row >= LQ) continue;
        float inv = 1.f / lsum[r2];
        #pragma unroll
        for (int ni = 0; ni < 2; ++ni)
            out[((size_t)(n*LQ+row))*256 + h*32 + ni*16 + l16] =
                __float2bfloat16(acc[ni][r2] * inv);
    }
}

// ---------- deformable sampling, head-major value layout ----------
__global__ __launch_bounds__(256) void sample2_kernel(
        const bf16* __restrict__ value, const float* __restrict__ offaw,
        const float* __restrict__ cp, bf16* __restrict__ out){
    int nq = blockIdx.x;
    int n = nq / LQ;
    int d = threadIdx.x & 31, h = threadIdx.x >> 5;
    float cx = cp[nq*2], cy = cp[nq*2+1];
    const float* rowp = offaw + (size_t)nq*480;
    float o0 = rowp[h*40 + d];
    float o1 = (d < 8) ? rowp[h*40 + 32 + d] : 0.f;
    float logit = (d < 20) ? rowp[320 + h*20 + d] : -3.0e38f;
    float mx = logit;
    #pragma unroll
    for (int off = 16; off; off >>= 1) mx = fmaxf(mx, __shfl_xor(mx, off, 32));
    float p = (d < 20) ? __expf(logit - mx) : 0.f;
    float sm = p;
    #pragma unroll
    for (int off = 16; off; off >>= 1) sm += __shfl_xor(sm, off, 32);
    p *= (1.f / sm);

    const int HW[5] = {128,64,32,16,8};
    const int ST[5] = {0,16384,20480,21504,21760};
    float acc = 0.f;
    #pragma unroll
    for (int l = 0; l < 5; ++l) {
        int hw = HW[l];
        float fhw = (float)hw;
        size_t vb = ((size_t)(n*8 + h)*LIN + ST[l])*32 + d;
        #pragma unroll
        for (int pi = 0; pi < 4; ++pi) {
            const int idx = l*4 + pi;
            float w  = __shfl(p, idx, 32);
            float ox = (2*idx < 32)   ? __shfl(o0, 2*idx, 32)   : __shfl(o1, 2*idx-32, 32);
            float oy = (2*idx+1 < 32) ? __shfl(o0, 2*idx+1, 32) : __shfl(o1, 2*idx+1-32, 32);
            float gx = cx*fhw + ox - 0.5f;
            float gy = cy*fhw + oy - 0.5f;
            float x0f = floorf(gx), y0f = floorf(gy);
            float lx = gx - x0f, ly = gy - y0f;
            int x0 = (int)x0f, y0 = (int)y0f;
            int x1 = x0 + 1, y1 = y0 + 1;
            bool bx0 = (unsigned)x0 < (unsigned)hw, bx1 = (unsigned)x1 < (unsigned)hw;
            bool by0 = (unsigned)y0 < (unsigned)hw, by1 = (unsigned)y1 < (unsigned)hw;
            int x0c = min(max(x0, 0), hw-1), x1c = min(max(x1, 0), hw-1);
            int y0c = min(max(y0, 0), hw-1), y1c = min(max(y1, 0), hw-1);
            float v00 = __bfloat162float(value[vb + (size_t)(y0c*hw + x0c)*32]);
            float v01 = __bfloat162float(value[vb + (size_t)(y0c*hw + x1c)*32]);
            float v10 = __bfloat162float(value[vb + (size_t)(y1c*hw + x0c)*32]);
            float v11 = __bfloat162float(value[vb + (size_t)(y1c*hw + x1c)*32]);
            float w00 = (bx0 && by0) ? (1.f-ly)*(1.f-lx)*w : 0.f;
            float w01 = (bx1 && by0) ? (1.f-ly)*lx*w       : 0.f;
            float w10 = (bx0 && by1) ? ly*(1.f-lx)*w       : 0.f;
            float w11 = (bx1 && by1) ? ly*lx*w             : 0.f;
            acc = fmaf(w00, v00, acc);
            acc = fmaf(w01, v01, acc);
            acc = fmaf(w10, v10, acc);
            acc = fmaf(w11, v11, acc);
        }
    }
    out[(size_t)nq*256 + h*32 + d] = __float2bfloat16(acc);
}

extern "C" void kernel_launch(void* const* d_in, const int* in_sizes, int n_in,
                              void* d_out, int out_size, void* d_ws, size_t ws_size,
                              hipStream_t stream){
    const void* x_raw  = d_in[0];
    const void* src    = d_in[1];
    const void* cp_raw = d_in[2];
    char* ws = (char*)d_ws;
    size_t off = 0;
    auto alloc = [&](size_t bytes){ size_t p = off; off += (bytes + 255) & ~(size_t)255; return p; };
    int*   flag  = (int*)(ws + alloc(256));
    float* xf    = (float*)(ws + alloc((size_t)ROWS_X*DIM*4));
    float* pe    = (float*)(ws + alloc((size_t)ROWS_X*DIM*4));
    bf16*  tmpb  = (bf16*)(ws + alloc((size_t)ROWS_X*DIM*2));
    bf16*  qkv   = (bf16*)(ws + alloc((size_t)ROWS_X*768*2));
    bf16*  ffh   = (bf16*)(ws + alloc((size_t)ROWS_X*MLPD*2));
    float* offaw = (float*)(ws + alloc((size_t)ROWS_X*480*4));
    float* cpf   = (float*)(ws + alloc((size_t)ROWS_X*2*4));
    float* oab   = (float*)(ws + alloc((size_t)2*480*4));
    float2* statbuf = (float2*)(ws + alloc((size_t)6*ROWS_X*8));
    float* qkvB  = (float*)(ws + alloc((size_t)2*768*4));
    float* ff1B  = (float*)(ws + alloc((size_t)2*512*4));
    float* valB  = (float*)(ws + alloc((size_t)2*256*4));
    const int sidx[13] = {5,6,7,8,11,12,13,19,21,22,23,25,27};
    const int ssz[13]  = {512,256,512,512,512,512,512,512,512,512,512,1024,512};
    float* sp[13];
    for (int j = 0; j < 13; ++j) sp[j] = (float*)(ws + alloc((size_t)ssz[j]*4));
    short* qkvT = (short*)(ws + alloc((size_t)2*768*256*2));
    short* outT = (short*)(ws + alloc((size_t)2*256*256*2));
    short* oawT = (short*)(ws + alloc((size_t)2*480*256*2));
    short* valT = (short*)(ws + alloc((size_t)2*256*256*2));
    short* opT  = (short*)(ws + alloc((size_t)2*256*256*2));
    short* ff1T = (short*)(ws + alloc((size_t)2*512*256*2));
    short* ff2T = (short*)(ws + alloc((size_t)2*256*512*2));
    bf16*  srcn = (bf16*)(ws + alloc((size_t)ROWS_SRC*DIM*2));
    bf16*  valall = (bf16*)(ws + alloc((size_t)2*ROWS_SRC*DIM*2));
    (void)ws_size; (void)in_sizes; (void)n_in; (void)out_size;

    float* ln1_g = sp[2];  float* ln1_b = sp[3];
    float* out_b = sp[4];
    float* ln2_g = sp[5];  float* ln2_b = sp[6];
    float* val_b = sp[7];  float* op_b  = sp[8];
    float* ln3_g = sp[9];  float* ln3_b = sp[10];
    float* ff_b1 = sp[11]; float* ff_b2 = sp[12];

    detect_kernel<<<1, 256, 0, stream>>>(x_raw, flag);
    {
        PrepTab pt;
        int nb = 0;
        int nn[17];
        for (int j = 0; j < 13; ++j) { pt.src[j] = d_in[sidx[j]]; pt.dst[j] = sp[j]; nn[j] = ssz[j]; }
        pt.src[13] = cp_raw;  pt.dst[13] = cpf;  nn[13] = ROWS_X*2;
        pt.src[14] = nullptr; pt.dst[14] = (float*)(statbuf + ROWS_X); nn[14] = 5*ROWS_X*2;
        pt.dst[15] = oab;  nn[15] = 960;
        pt.dst[16] = pe;   nn[16] = ROWS_X*DIM;
        for (int j = 0; j < 17; ++j) {
            pt.n[j] = nn[j];
            pt.bs[j] = nb;
            nb += (nn[j] + 255)/256;
        }
        pt.bs[17] = nb;
        prep_kernel<<<nb, 256, 0, stream>>>(pt, d_in[15], d_in[17], d_in[5], d_in[6],
                                            cp_raw, flag);
    }
    statsconvx_kernel<<<ROWS_SRC/4 + ROWS_X/4, 256, 0, stream>>>(
        src, x_raw, pe, flag, srcn, xf, statbuf);
    {
        WT wt;
        const int widx[8] = {9,10,14,16,18,20,24,26};
        short* wdst[8] = {qkvT, outT, oawT, oawT, valT, opT, ff1T, ff2T};
        const float* wscl[8] = {ln1_g, nullptr, nullptr, nullptr, ln2_g, nullptr, ln3_g, nullptr};
        const int wK[8]  = {256,256,256,256,256,256,256,512};
        const int wN[8]  = {768,256,320,160,256,256,512,256};
        const int wld[8] = {768,256,480,480,256,256,512,256};
        const int wro[8] = {0,0,0,320,0,0,0,0};
        for (int j = 0; j < 8; ++j) {
            wt.src[j] = d_in[widx[j]]; wt.dst[j] = wdst[j]; wt.scl[j] = wscl[j];
            wt.K[j] = wK[j]; wt.N[j] = wN[j]; wt.ld[j] = wld[j]; wt.ro[j] = wro[j];
        }
        wtransall_kernel<<<dim3(16,24,16), 256, 0, stream>>>(wt, flag);
    }
    {
        BFT bt;
        bt.W[0] = d_in[9];  bt.bv[0] = ln1_b; bt.base[0] = nullptr; bt.dst[0] = qkvB; bt.N[0] = 768;
        bt.W[1] = d_in[24]; bt.bv[1] = ln3_b; bt.base[1] = ff_b1;   bt.dst[1] = ff1B; bt.N[1] = 512;
        bt.W[2] = d_in[18]; bt.bv[2] = ln2_b; bt.base[2] = val_b;   bt.dst[2] = valB; bt.N[2] = 256;
        biasfold_kernel<<<dim3(1536,2), 256, 0, stream>>>(bt, flag);
    }
    // both layers' value projections in one dispatch (head-major output, col-fastest grid)
    mgemm128_kernel<<<dim3(4, ROWS_SRC/128), 256, 0, stream>>>(
        (const short*)srcn, valT, valB, valall);

    int gmx = (ROWS_X + 63) / 64;   // 63
    for (int i = 0; i < 2; ++i) {
        float2* stA = statbuf + (size_t)(i ? 3 : 0)*ROWS_X;   // attn LN sums (x+pe)
        float2* stO = statbuf + (size_t)(i ? 4 : 1)*ROWS_X;   // offaw LN sums
        float2* stF = statbuf + (size_t)(i ? 5 : 2)*ROWS_X;   // ff LN sums
        // qkv = normalize(x+pe) @ (g1.qkv_w) + b1@qkv_w   (g,b folded)
        mgemm_kernel<4><<<dim3(gmx,6), 256, 0, stream>>>(
            xf, stA, nullptr, nullptr, pe, nullptr,
            qkvT + (size_t)i*768*256, qkvB + i*768, nullptr, qkv,
            ROWS_X, 256, 768, 0, 1, nullptr, nullptr, nullptr, flag);
        fattn_kernel<<<dim3(16,32), 256, 0, stream>>>((const short*)qkv, tmpb);
        // out-proj (+res into xf), accumulate offaw-LN sums of new xf
        mgemm_kernel<2><<<dim3(gmx,2), 256, 0, stream>>>(
            tmpb, nullptr, nullptr, nullptr, nullptr, nullptr,
            outT + (size_t)i*256*256, out_b + i*DIM, xf, xf,
            ROWS_X, 256, 256, 0, 0, stO, nullptr, nullptr, flag);
        // offaw = (LN(xf;ln2) + pe) @ [off|aw]_w + oab
        mgemm_kernel<3><<<dim3(gmx,4), 256, 0, stream>>>(
            xf, stO, ln2_g + i*DIM, ln2_b + i*DIM, nullptr, pe,
            oawT + (size_t)i*480*256, oab + i*480, nullptr, offaw,
            ROWS_X, 256, 480, 0, 0, nullptr, nullptr, nullptr, flag);
        sample2_kernel<<<ROWS_X, 256, 0, stream>>>(
            valall + (size_t)i*VLAYER, offaw, cpf, tmpb);
        // op-proj (+res into xf), accumulate ff-LN sums of new xf
        mgemm_kernel<2><<<dim3(gmx,2), 256, 0, stream>>>(
            tmpb, nullptr, nullptr, nullptr, nullptr, nullptr,
            opT + (size_t)i*256*256, op_b + i*DIM, xf, xf,
            ROWS_X, 256, 256, 0, 0, stF, nullptr, nullptr, flag);
        // ffh = gelu( normalize(xf) @ (g3.ff_w1) + (b3@ff_w1 + ff_b1) )
        mgemm_kernel<4><<<dim3(gmx,4), 256, 0, stream>>>(
            xf, stF, nullptr, nullptr, nullptr, nullptr,
            ff1T + (size_t)i*512*256, ff1B + i*MLPD, nullptr, ffh,
            ROWS_X, 256, 512, 1, 1, nullptr, nullptr, nullptr, flag);
        // ff2 (+res). layer0: accumulate next-layer attn sums (xf+pe). layer1: write d_out.
        if (i == 0) {
            mgemm_kernel<2><<<dim3(gmx,2), 256, 0, stream>>>(
                ffh, nullptr, nullptr, nullptr, nullptr, nullptr,
                ff2T + (size_t)i*256*512, ff_b2 + i*DIM, xf, xf,
                ROWS_X, 512, 256, 0, 0, statbuf + (size_t)3*ROWS_X, pe, nullptr, flag);
        } else {
            mgemm_kernel<2><<<dim3(gmx,2), 256, 0, stream>>>(
                ffh, nullptr, nullptr, nullptr, nullptr, nullptr,
                ff2T + (size_t)i*256*512, ff_b2 + i*DIM, xf, xf,
                ROWS_X, 512, 256, 0, 0, nullptr, nullptr, d_out, flag);
        }
    }
}

// Round 6
// 574.347 us; speedup vs baseline: 1.0957x; 1.0957x over previous
//
#include <hip/hip_runtime.h>
#include <hip/hip_bf16.h>
#include <math.h>

#define DIM 256
#define NB 4
#define LQ 1000
#define MLPD 512
#define LIN 21824
#define ROWS_X 4000
#define ROWS_SRC 87296
#define ATT_SCALE 0.17677669529663687f  /* 32^-0.5 */
#define LDK 72   /* padded LDS row (bf16 elems): 144 B, 16B-aligned */
#define VLAYER ((size_t)ROWS_SRC*256)

typedef __hip_bfloat16 bf16;
typedef __attribute__((ext_vector_type(8))) short short8;
typedef __attribute__((ext_vector_type(4))) float floatx4;

__device__ __forceinline__ float rdv(const void* p, int f, size_t i){
    if (f) return ((const float*)p)[i];
    unsigned u = ((unsigned)((const unsigned short*)p)[i]) << 16;
    union { unsigned u; float f; } c; c.u = u; return c.f;
}
__device__ __forceinline__ short f2bs(float v){
    bf16 h = __float2bfloat16(v);
    return *reinterpret_cast<short*>(&h);
}
__device__ __forceinline__ float bs2f(short s){
    union { unsigned u; float f; } c; c.u = ((unsigned)(unsigned short)s) << 16; return c.f;
}

// ---------- dtype detect ----------
__global__ void detect_kernel(const void* __restrict__ x, int* __restrict__ flag){
    const unsigned short* u = (const unsigned short*)x;
    int t = threadIdx.x;
    bool hit = false;
    #pragma unroll
    for (int k = 0; k < 4; ++k) {
        unsigned short b = u[(t*4 + k)*2];
        union { unsigned u; float f; } c; c.u = ((unsigned)b) << 16;
        if (!(fabsf(c.f) <= 1000.f)) hit = true;
    }
    unsigned long long m = __ballot(hit);
    __shared__ unsigned long long red[4];
    if ((t & 63) == 0) red[t >> 6] = m;
    __syncthreads();
    if (t == 0) flag[0] = ((red[0]|red[1]|red[2]|red[3]) != 0ULL) ? 1 : 0;
}

// ---------- one packed prep kernel: 13 convs + cpf + statzero + catb + pe ----------
struct PrepTab { const void* src[15]; float* dst[17]; int n[17]; int bs[18]; };
__global__ void prep_kernel(PrepTab t, const void* __restrict__ offb,
                            const void* __restrict__ awb, const void* __restrict__ pw,
                            const void* __restrict__ pb, const void* __restrict__ cp,
                            const int* __restrict__ flag){
    int f = flag[0];
    int bid = blockIdx.x;
    int j = 0;
    #pragma unroll 1
    while (bid >= t.bs[j+1]) ++j;
    int i = (bid - t.bs[j])*256 + threadIdx.x;
    if (i >= t.n[j]) return;
    if (j < 15) {
        t.dst[j][i] = t.src[j] ? rdv(t.src[j], f, i) : 0.f;
    } else if (j == 15) {           // catb -> oab[2][480]
        int layer = i / 480, idx = i - layer*480;
        float v = (idx < 320) ? rdv(offb, f, (size_t)layer*320 + idx)
                              : rdv(awb,  f, (size_t)layer*160 + idx - 320);
        t.dst[15][i] = v;
    } else {                        // pe[row][256]
        int row = i >> 8, c = i & 255;
        float cx = rdv(cp, f, (size_t)row*2), cy = rdv(cp, f, (size_t)row*2 + 1);
        t.dst[16][i] = cx*rdv(pw, f, c) + cy*rdv(pw, f, DIM + c) + rdv(pb, f, c);
    }
}

// ---------- all weight transposes in ONE launch, with optional K-dim scale fold ----------
struct WT { const void* src[8]; short* dst[8]; const float* scl[8];
            int K[8]; int N[8]; int ld[8]; int ro[8]; };
__global__ void wtransall_kernel(WT t, const int* __restrict__ flag){
    int j = blockIdx.z >> 1, b = blockIdx.z & 1;
    int K = t.K[j], N = t.N[j];
    int k0 = blockIdx.x*32, n0 = blockIdx.y*32;
    if (k0 >= K || n0 >= N) return;   // uniform per block, before any sync
    int f = flag[0];
    __shared__ float tt[32][33];
    int tx = threadIdx.x & 31, ty = threadIdx.x >> 5;
    size_t base = (size_t)b * K * N;
    for (int i = ty; i < 32; i += 8) {
        int k = k0 + i, n = n0 + tx;
        tt[i][tx] = (k < K && n < N) ? rdv(t.src[j], f, base + (size_t)k*N + n) : 0.f;
    }
    __syncthreads();
    int ld = t.ld[j], ro = t.ro[j];
    const float* sc = t.scl[j];
    for (int i = ty; i < 32; i += 8) {
        int n = n0 + i, k = k0 + tx;
        if (n < N && k < K) {
            float v = tt[tx][i];
            if (sc) v *= sc[(size_t)b*K + k];
            t.dst[j][(size_t)b*ld*K + (size_t)(ro+n)*K + k] = f2bs(v);
        }
    }
}

// ---------- bias folds: dst[b][n] = bvec[b] @ W[b][:,n] (+base[b][n]) ----------
struct BFT { const void* W[3]; const float* bv[3]; const float* base[3];
             float* dst[3]; int N[3]; };
__global__ __launch_bounds__(256) void biasfold_kernel(BFT t, const int* __restrict__ flag){
    int f = flag[0];
    int x = blockIdx.x, b = blockIdx.y;
    int j, n;
    if (x < 768)       { j = 0; n = x; }
    else if (x < 1280) { j = 1; n = x - 768; }
    else               { j = 2; n = x - 1280; }
    int N = t.N[j];
    int k = threadIdx.x;
    float part = t.bv[j][(size_t)b*256 + k] *
                 rdv(t.W[j], f, (size_t)b*256*N + (size_t)k*N + n);
    #pragma unroll
    for (int o = 32; o; o >>= 1) part += __shfl_xor(part, o, 64);
    __shared__ float red[4];
    int wave = k >> 6, lane = k & 63;
    if (lane == 0) red[wave] = part;
    __syncthreads();
    if (k == 0) {
        float s = red[0] + red[1] + red[2] + red[3];
        if (t.base[j]) s += t.base[j][(size_t)b*N + n];
        t.dst[j][(size_t)b*N + n] = s;
    }
}

// ---------- merged: src LN-normalize + x convert/sums ----------
__global__ __launch_bounds__(256) void statsconvx_kernel(const void* __restrict__ src,
        const void* __restrict__ x, const float* __restrict__ pe,
        const int* __restrict__ flag, bf16* __restrict__ srcn,
        float* __restrict__ xf, float2* __restrict__ st){
    int f = flag[0];
    int wave = threadIdx.x >> 6, lane = threadIdx.x & 63;
    int bid = blockIdx.x;
    if (bid < ROWS_SRC/4) {
        int row = bid*4 + wave;
        float v0, v1, v2, v3;
        if (f) {
            float4 xx = *(const float4*)((const float*)src + (size_t)row*DIM + lane*4);
            v0 = xx.x; v1 = xx.y; v2 = xx.z; v3 = xx.w;
        } else {
            ushort4 u = *(const ushort4*)((const unsigned short*)src + (size_t)row*DIM + lane*4);
            v0 = bs2f((short)u.x); v1 = bs2f((short)u.y);
            v2 = bs2f((short)u.z); v3 = bs2f((short)u.w);
        }
        float s  = v0 + v1 + v2 + v3;
        float s2 = v0*v0 + v1*v1 + v2*v2 + v3*v3;
        #pragma unroll
        for (int o = 32; o; o >>= 1) {
            s  += __shfl_xor(s,  o, 64);
            s2 += __shfl_xor(s2, o, 64);
        }
        float mean = s * (1.f/DIM);
        float rstd = rsqrtf(s2 * (1.f/DIM) - mean*mean + 1e-5f);
        ushort4 o4;
        o4.x = (unsigned short)f2bs((v0-mean)*rstd);
        o4.y = (unsigned short)f2bs((v1-mean)*rstd);
        o4.z = (unsigned short)f2bs((v2-mean)*rstd);
        o4.w = (unsigned short)f2bs((v3-mean)*rstd);
        *(ushort4*)((unsigned short*)srcn + (size_t)row*DIM + lane*4) = o4;
    } else {
        int row = (bid - ROWS_SRC/4)*4 + wave;
        float4 v;
        if (f) v = *(const float4*)((const float*)x + (size_t)row*DIM + lane*4);
        else {
            ushort4 u = *(const ushort4*)((const unsigned short*)x + (size_t)row*DIM + lane*4);
            v = make_float4(bs2f((short)u.x), bs2f((short)u.y), bs2f((short)u.z), bs2f((short)u.w));
        }
        *(float4*)(xf + (size_t)row*DIM + lane*4) = v;
        float4 p = *(const float4*)(pe + (size_t)row*DIM + lane*4);
        float a0 = v.x+p.x, a1 = v.y+p.y, a2 = v.z+p.z, a3 = v.w+p.w;
        float s  = a0+a1+a2+a3;
        float s2 = a0*a0+a1*a1+a2*a2+a3*a3;
        #pragma unroll
        for (int o = 32; o; o >>= 1) {
            s  += __shfl_xor(s,  o, 64);
            s2 += __shfl_xor(s2, o, 64);
        }
        if (lane == 0) st[row] = make_float2(s, s2);
    }
}

// ---------- MFMA GEMM 64x64 with register-prefetch staging (round-4 config) ----------
// AMODE 2: A bf16; AMODE 3: A fp32 LN(g,b in LDS) +Apost; AMODE 4: normalize-only +Apre.
template<int AMODE>
__global__ __launch_bounds__(256) void mgemm_kernel(
    const void* __restrict__ Asrc, const float2* __restrict__ asums,
    const float* __restrict__ ag, const float* __restrict__ ab,
    const float* __restrict__ Apre, const float* __restrict__ Apost,
    const short* __restrict__ Wt, const float* __restrict__ bias, const float* res,
    void* Cout, int M, int K, int N, int act, int cbf,
    float2* __restrict__ statacc, const float* __restrict__ sepe,
    void* __restrict__ fin, const int* __restrict__ flag){
    __shared__ short As[64*LDK];
    __shared__ short Bs[64*LDK];
    __shared__ float gsh[256], bsh[256];
    int tid = threadIdx.x;
    int wave = tid >> 6, lane = tid & 63;
    int wm = wave >> 1, wn = wave & 1;
    int quad = lane >> 4, l16 = lane & 15;
    int row0 = blockIdx.x*64, col0 = blockIdx.y*64;
    floatx4 acc[2][2];
    #pragma unroll
    for (int i = 0; i < 2; ++i)
        #pragma unroll
        for (int j = 0; j < 2; ++j)
            acc[i][j] = (floatx4){0.f,0.f,0.f,0.f};

    int r  = tid >> 2;
    int kc = (tid & 3) * 16;
    int gr = row0 + r;
    int gc = col0 + r;
    const short8 z8 = {0,0,0,0,0,0,0,0};

    if (AMODE == 3) {
        gsh[tid] = ag[tid]; bsh[tid] = ab[tid];
        __syncthreads();
    }
    const float* aux = Apre ? Apre : Apost;   // at most one non-null per call
    float mean = 0.f, rstd = 0.f;
    if (AMODE != 2 && gr < M) {
        float2 stt = asums[gr];
        mean = stt.x * (1.f/256.f);
        rstd = rsqrtf(stt.y*(1.f/256.f) - mean*mean + 1e-5f);
    }
    // prefetch registers (k-step 0)
    short8 ra0, ra1, rb0, rb1;
    float4 rx0, rx1, rx2, rx3, rq0, rq1, rq2, rq3;
    if (gr < M) {
        if (AMODE == 2) {
            const short8* p = (const short8*)((const short*)Asrc + (size_t)gr*K + kc);
            ra0 = p[0]; ra1 = p[1];
        } else {
            const float4* p = (const float4*)((const float*)Asrc + (size_t)gr*K + kc);
            rx0 = p[0]; rx1 = p[1]; rx2 = p[2]; rx3 = p[3];
            if (aux) {
                const float4* q = (const float4*)(aux + (size_t)gr*K + kc);
                rq0 = q[0]; rq1 = q[1]; rq2 = q[2]; rq3 = q[3];
            }
        }
    }
    if (gc < N) {
        const short8* p = (const short8*)(Wt + (size_t)gc*K + kc);
        rb0 = p[0]; rb1 = p[1];
    }

    for (int k0 = 0; k0 < K; k0 += 64) {
        short8 a0 = z8, a1 = z8;
        if (gr < M) {
            if (AMODE == 2) { a0 = ra0; a1 = ra1; }
            else {
                float av[16] = {rx0.x,rx0.y,rx0.z,rx0.w, rx1.x,rx1.y,rx1.z,rx1.w,
                                rx2.x,rx2.y,rx2.z,rx2.w, rx3.x,rx3.y,rx3.z,rx3.w};
                float qv[16] = {rq0.x,rq0.y,rq0.z,rq0.w, rq1.x,rq1.y,rq1.z,rq1.w,
                                rq2.x,rq2.y,rq2.z,rq2.w, rq3.x,rq3.y,rq3.z,rq3.w};
                if (AMODE == 4) {
                    if (Apre) {
                        #pragma unroll
                        for (int j = 0; j < 16; ++j) av[j] += qv[j];
                    }
                    #pragma unroll
                    for (int j = 0; j < 16; ++j) av[j] = (av[j] - mean)*rstd;
                } else { // AMODE 3
                    #pragma unroll
                    for (int j = 0; j < 16; ++j)
                        av[j] = (av[j] - mean)*rstd*gsh[k0+kc+j] + bsh[k0+kc+j];
                    if (Apost) {
                        #pragma unroll
                        for (int j = 0; j < 16; ++j) av[j] += qv[j];
                    }
                }
                #pragma unroll
                for (int j = 0; j < 8; ++j) { a0[j] = f2bs(av[j]); a1[j] = f2bs(av[8+j]); }
            }
        }
        *(short8*)&As[r*LDK + kc]     = a0;
        *(short8*)&As[r*LDK + kc + 8] = a1;
        short8 b0 = z8, b1 = z8;
        if (gc < N) { b0 = rb0; b1 = rb1; }
        *(short8*)&Bs[r*LDK + kc]     = b0;
        *(short8*)&Bs[r*LDK + kc + 8] = b1;
        // issue next k-step's loads before the barrier (latency hides under MFMA)
        int kn = k0 + 64;
        if (kn < K) {
            if (gr < M) {
                if (AMODE == 2) {
                    const short8* p = (const short8*)((const short*)Asrc + (size_t)gr*K + kn + kc);
                    ra0 = p[0]; ra1 = p[1];
                } else {
                    const float4* p = (const float4*)((const float*)Asrc + (size_t)gr*K + kn + kc);
                    rx0 = p[0]; rx1 = p[1]; rx2 = p[2]; rx3 = p[3];
                    if (aux) {
                        const float4* q = (const float4*)(aux + (size_t)gr*K + kn + kc);
                        rq0 = q[0]; rq1 = q[1]; rq2 = q[2]; rq3 = q[3];
                    }
                }
            }
            if (gc < N) {
                const short8* p = (const short8*)(Wt + (size_t)gc*K + kn + kc);
                rb0 = p[0]; rb1 = p[1];
            }
        }
        __syncthreads();
        #pragma unroll
        for (int kb = 0; kb < 64; kb += 32) {
            short8 af[2], bfr[2];
            #pragma unroll
            for (int mi = 0; mi < 2; ++mi)
                af[mi] = *(const short8*)&As[(wm*32 + mi*16 + l16)*LDK + kb + quad*8];
            #pragma unroll
            for (int ni = 0; ni < 2; ++ni)
                bfr[ni] = *(const short8*)&Bs[(wn*32 + ni*16 + l16)*LDK + kb + quad*8];
            #pragma unroll
            for (int mi = 0; mi < 2; ++mi)
                #pragma unroll
                for (int ni = 0; ni < 2; ++ni)
                    acc[mi][ni] = __builtin_amdgcn_mfma_f32_16x16x32_bf16(
                        af[mi], bfr[ni], acc[mi][ni], 0, 0, 0);
        }
        __syncthreads();
    }
    // epilogue
    float vout[2][2][4];
    #pragma unroll
    for (int mi = 0; mi < 2; ++mi) {
        int rbase = row0 + wm*32 + mi*16 + quad*4;
        #pragma unroll
        for (int ni = 0; ni < 2; ++ni) {
            int c = col0 + wn*32 + ni*16 + l16;
            #pragma unroll
            for (int r2 = 0; r2 < 4; ++r2) {
                int rr = rbase + r2;
                float v = 0.f;
                if (c < N && rr < M) {
                    v = acc[mi][ni][r2];
                    if (bias) v += bias[c];
                    if (act) {  // tanh-gelu == v*sigmoid(2y)
                        float z = fminf(1.5957691216057308f*(v + 0.044715f*v*v*v), 60.f);
                        float e = __expf(z);
                        v = v * e / (e + 1.f);
                    }
                    if (res) v += res[(size_t)rr*N + c];
                }
                vout[mi][ni][r2] = v;
            }
        }
    }
    int fflag = 0;
    if (fin) fflag = flag[0];
    #pragma unroll
    for (int mi = 0; mi < 2; ++mi) {
        int rbase = row0 + wm*32 + mi*16 + quad*4;
        #pragma unroll
        for (int ni = 0; ni < 2; ++ni) {
            int c = col0 + wn*32 + ni*16 + l16;
            if (c >= N) continue;
            #pragma unroll
            for (int r2 = 0; r2 < 4; ++r2) {
                int rr = rbase + r2;
                if (rr >= M) continue;
                float v = vout[mi][ni][r2];
                if (fin) {
                    float w = isfinite(v) ? v : 0.f;
                    if (fflag) ((float*)fin)[(size_t)rr*N + c] = w;
                    else       ((bf16*)fin)[(size_t)rr*N + c] = __float2bfloat16(w);
                } else if (cbf) ((bf16*)Cout)[(size_t)rr*N + c] = __float2bfloat16(v);
                else            ((float*)Cout)[(size_t)rr*N + c] = v;
            }
        }
    }
    if (statacc) {
        #pragma unroll
        for (int mi = 0; mi < 2; ++mi) {
            int rbase = row0 + wm*32 + mi*16 + quad*4;
            #pragma unroll
            for (int r2 = 0; r2 < 4; ++r2) {
                int rr = rbase + r2;
                float sv = 0.f, sq = 0.f;
                #pragma unroll
                for (int ni = 0; ni < 2; ++ni) {
                    int c = col0 + wn*32 + ni*16 + l16;
                    float v = vout[mi][ni][r2];
                    if (sepe && rr < M) v += sepe[(size_t)rr*256 + c];
                    sv += v; sq += v*v;
                }
                #pragma unroll
                for (int o = 1; o < 16; o <<= 1) {
                    sv += __shfl_xor(sv, o, 64);
                    sq += __shfl_xor(sq, o, 64);
                }
                if (l16 == 0 && rr < M) {
                    atomicAdd(&statacc[rr].x, sv);
                    atomicAdd(&statacc[rr].y, sq);
                }
            }
        }
    }
}

// ---------- MFMA GEMM 128x128, both layers' value proj ----------
// 1D grid 2728 with XCD-aware swizzle: the 4 col-tiles of one row-panel map to
// bids {g*32+s, +8, +16, +24} -> all same (bid%8) -> same XCD -> A-panel L2 reuse.
// Epilogue stages C through LDS -> coalesced 16B head-major stores.
__global__ __launch_bounds__(256) void mgemm128_kernel(
    const short* __restrict__ A, const short* __restrict__ Wt,
    const float* __restrict__ bias, bf16* __restrict__ valall){
    const int K = 256;
    __shared__ short lds[2*128*LDK];   // As | Bs; reused as C-tile (128x136) in epilogue
    short* As = lds;
    short* Bs = lds + 128*LDK;
    int tid = threadIdx.x;
    int wave = tid >> 6, lane = tid & 63;
    int wm = wave >> 1, wn = wave & 1;
    int quad = lane >> 4, l16 = lane & 15;
    int bid = blockIdx.x;
    int panel, col;
    if (bid < 2720) {
        int g = bid >> 5, w = bid & 31;
        panel = g*8 + (w & 7);
        col = w >> 3;
    } else {
        int idx = bid - 2720;
        panel = 680 + (idx >> 2);
        col = idx & 3;
    }
    int row0 = panel*128, col0 = col*128;
    floatx4 acc[4][4];
    #pragma unroll
    for (int i = 0; i < 4; ++i)
        #pragma unroll
        for (int j = 0; j < 4; ++j)
            acc[i][j] = (floatx4){0.f,0.f,0.f,0.f};

    short8 pa[2][2], pb2[2][2];
    #pragma unroll
    for (int i = 0; i < 2; ++i) {
        int idx = tid + i*256;
        int rr = idx >> 2, kk = (idx & 3)*16;
        const short8* p = (const short8*)(A + (size_t)(row0+rr)*K + kk);
        pa[i][0] = p[0]; pa[i][1] = p[1];
        const short8* pb = (const short8*)(Wt + (size_t)(col0+rr)*K + kk);
        pb2[i][0] = pb[0]; pb2[i][1] = pb[1];
    }
    for (int k0 = 0; k0 < K; k0 += 64) {
        #pragma unroll
        for (int i = 0; i < 2; ++i) {
            int idx = tid + i*256;
            int rr = idx >> 2, kk = (idx & 3)*16;
            *(short8*)&As[rr*LDK + kk]     = pa[i][0];
            *(short8*)&As[rr*LDK + kk + 8] = pa[i][1];
            *(short8*)&Bs[rr*LDK + kk]     = pb2[i][0];
            *(short8*)&Bs[rr*LDK + kk + 8] = pb2[i][1];
        }
        int kn = k0 + 64;
        if (kn < K) {
            #pragma unroll
            for (int i = 0; i < 2; ++i) {
                int idx = tid + i*256;
                int rr = idx >> 2, kk = (idx & 3)*16;
                const short8* p = (const short8*)(A + (size_t)(row0+rr)*K + kn + kk);
                pa[i][0] = p[0]; pa[i][1] = p[1];
                const short8* pb = (const short8*)(Wt + (size_t)(col0+rr)*K + kn + kk);
                pb2[i][0] = pb[0]; pb2[i][1] = pb[1];
            }
        }
        __syncthreads();
        #pragma unroll
        for (int kb = 0; kb < 64; kb += 32) {
            short8 af[4], bfr[4];
            #pragma unroll
            for (int mi = 0; mi < 4; ++mi)
                af[mi] = *(const short8*)&As[(wm*64 + mi*16 + l16)*LDK + kb + quad*8];
            #pragma unroll
            for (int ni = 0; ni < 4; ++ni)
                bfr[ni] = *(const short8*)&Bs[(wn*64 + ni*16 + l16)*LDK + kb + quad*8];
            #pragma unroll
            for (int mi = 0; mi < 4; ++mi)
                #pragma unroll
                for (int ni = 0; ni < 4; ++ni)
                    acc[mi][ni] = __builtin_amdgcn_mfma_f32_16x16x32_bf16(
                        af[mi], bfr[ni], acc[mi][ni], 0, 0, 0);
        }
        __syncthreads();
    }
    // ---- epilogue: C tile -> LDS (bf16, +bias) -> coalesced head-major stores ----
    short* Cs = lds;   // 128 x 136 shorts = 34816 B <= 36864 B
    #pragma unroll
    for (int mi = 0; mi < 4; ++mi) {
        int lr = wm*64 + mi*16 + quad*4;
        #pragma unroll
        for (int ni = 0; ni < 4; ++ni) {
            int lc = wn*64 + ni*16 + l16;
            float bv = bias[col0 + lc];
            #pragma unroll
            for (int r2 = 0; r2 < 4; ++r2)
                Cs[(lr + r2)*136 + lc] = f2bs(acc[mi][ni][r2] + bv);
        }
    }
    __syncthreads();
    #pragma unroll
    for (int g = 0; g < 4; ++g) {
        int cbase = col0 + g*32;
        int l = cbase >> 8, h = (cbase & 255) >> 5;
        #pragma unroll
        for (int p = 0; p < 2; ++p) {
            int idx = p*256 + tid;
            int rr2 = idx >> 2;          // 0..127
            int dc = (idx & 3) * 8;      // 0,8,16,24
            short8 v = *(const short8*)&Cs[rr2*136 + g*32 + dc];
            int grr = row0 + rr2;
            unsigned n = (unsigned)grr / (unsigned)LIN;
            int pos = grr - (int)n*LIN;
            *(short8*)((short*)valall + (size_t)l*VLAYER
                       + ((size_t)(n*8+h)*LIN + pos)*32 + dc) = v;
        }
    }
}

// ---------- fused flash attention with K/V register prefetch ----------
__global__ __launch_bounds__(256) void fattn_kernel(const short* __restrict__ qkv,
                                                    bf16* __restrict__ out){
    int nh = blockIdx.y;
    int n = nh >> 3, h = nh & 7;
    int q0 = blockIdx.x * 64;
    __shared__ short Ks[64*40];
    __shared__ short VsT[32*72];
    __shared__ short Ps[64*72];
    int tid = threadIdx.x;
    int wave = tid >> 6, lane = tid & 63;
    int quad = lane >> 4, l16 = lane & 15;
    int r = tid >> 2, c8 = (tid & 3) * 8;
    const short8 z8 = {0,0,0,0,0,0,0,0};

    short8 qf = z8;
    {
        int gq = q0 + wave*16 + l16;
        if (gq < LQ) {
            short8 s = *(const short8*)(qkv + ((size_t)(n*LQ+gq))*768 + h*32 + quad*8);
            #pragma unroll
            for (int j = 0; j < 8; ++j) qf[j] = f2bs(bs2f(s[j]) * ATT_SCALE);
        }
    }
    floatx4 acc[2];
    acc[0] = (floatx4){0.f,0.f,0.f,0.f};
    acc[1] = (floatx4){0.f,0.f,0.f,0.f};
    float m[4], lsum[4];
    #pragma unroll
    for (int i = 0; i < 4; ++i) { m[i] = -3.0e38f; lsum[i] = 0.f; }

    short8 kvp = z8, vvp = z8;
    if (r < LQ) {
        const short* rp = qkv + ((size_t)(n*LQ+r))*768;
        kvp = *(const short8*)(rp + 256 + h*32 + c8);
        vvp = *(const short8*)(rp + 512 + h*32 + c8);
    }
    for (int k0 = 0; k0 < LQ; k0 += 64) {
        *(short8*)&Ks[r*40 + c8] = kvp;
        #pragma unroll
        for (int j = 0; j < 8; ++j) VsT[(c8+j)*72 + r] = vvp[j];
        short8 kvn = z8, vvn = z8;
        if (k0 + 64 < LQ) {
            int gk = k0 + 64 + r;
            if (gk < LQ) {
                const short* rp = qkv + ((size_t)(n*LQ+gk))*768;
                kvn = *(const short8*)(rp + 256 + h*32 + c8);
                vvn = *(const short8*)(rp + 512 + h*32 + c8);
            }
        }
        __syncthreads();
        floatx4 s4[4];
        #pragma unroll
        for (int kg = 0; kg < 4; ++kg) {
            short8 bfr = *(const short8*)&Ks[(kg*16 + l16)*40 + quad*8];
            s4[kg] = __builtin_amdgcn_mfma_f32_16x16x32_bf16(
                qf, bfr, (floatx4){0.f,0.f,0.f,0.f}, 0, 0, 0);
        }
        if (k0 + 64 > LQ) {
            #pragma unroll
            for (int kg = 0; kg < 4; ++kg)
                if (k0 + kg*16 + l16 >= LQ)
                    s4[kg] = (floatx4){-3.0e38f,-3.0e38f,-3.0e38f,-3.0e38f};
        }
        float fac[4], psum[4];
        #pragma unroll
        for (int r2 = 0; r2 < 4; ++r2) {
            float v = fmaxf(fmaxf(s4[0][r2], s4[1][r2]), fmaxf(s4[2][r2], s4[3][r2]));
            v = fmaxf(v, __shfl_xor(v, 1, 64));
            v = fmaxf(v, __shfl_xor(v, 2, 64));
            v = fmaxf(v, __shfl_xor(v, 4, 64));
            v = fmaxf(v, __shfl_xor(v, 8, 64));
            float mn = fmaxf(m[r2], v);
            fac[r2] = __expf(m[r2] - mn);
            m[r2] = mn;
            psum[r2] = 0.f;
        }
        #pragma unroll
        for (int kg = 0; kg < 4; ++kg)
            #pragma unroll
            for (int r2 = 0; r2 < 4; ++r2) {
                float pv = __expf(s4[kg][r2] - m[r2]);
                psum[r2] += pv;
                Ps[(wave*16 + quad*4 + r2)*72 + kg*16 + l16] = f2bs(pv);
            }
        #pragma unroll
        for (int r2 = 0; r2 < 4; ++r2) {
            psum[r2] += __shfl_xor(psum[r2], 1, 64);
            psum[r2] += __shfl_xor(psum[r2], 2, 64);
            psum[r2] += __shfl_xor(psum[r2], 4, 64);
            psum[r2] += __shfl_xor(psum[r2], 8, 64);
            lsum[r2] = lsum[r2]*fac[r2] + psum[r2];
        }
        #pragma unroll
        for (int ni = 0; ni < 2; ++ni)
            #pragma unroll
            for (int r2 = 0; r2 < 4; ++r2)
                acc[ni][r2] *= fac[r2];
        #pragma unroll
        for (int kb = 0; kb < 64; kb += 32) {
            short8 pf = *(const short8*)&Ps[(wave*16 + l16)*72 + kb + quad*8];
            #pragma unroll
            for (int ni = 0; ni < 2; ++ni) {
                short8 vf = *(const short8*)&VsT[(ni*16 + l16)*72 + kb + quad*8];
                acc[ni] = __builtin_amdgcn_mfma_f32_16x16x32_bf16(pf, vf, acc[ni], 0, 0, 0);
            }
        }
        __syncthreads();
        kvp = kvn; vvp = vvn;
    }
    #pragma unroll
    for (int r2 = 0; r2 < 4; ++r2) {
        int row = q0 + wave*16 + quad*4 + r2;
        if (row >= LQ) continue;
        float inv = 1.f / lsum[r2];
        #pragma unroll
        for (int ni = 0; ni < 2; ++ni)
            out[((size_t)(n*LQ+row))*256 + h*32 + ni*16 + l16] =
                __float2bfloat16(acc[ni][r2] * inv);
    }
}

// ---------- deformable sampling, head-major value layout ----------
__global__ __launch_bounds__(256) void sample2_kernel(
        const bf16* __restrict__ value, const float* __restrict__ offaw,
        const float* __restrict__ cp, bf16* __restrict__ out){
    int nq = blockIdx.x;
    int n = nq / LQ;
    int d = threadIdx.x & 31, h = threadIdx.x >> 5;
    float cx = cp[nq*2], cy = cp[nq*2+1];
    const float* rowp = offaw + (size_t)nq*480;
    float o0 = rowp[h*40 + d];
    float o1 = (d < 8) ? rowp[h*40 + 32 + d] : 0.f;
    float logit = (d < 20) ? rowp[320 + h*20 + d] : -3.0e38f;
    float mx = logit;
    #pragma unroll
    for (int off = 16; off; off >>= 1) mx = fmaxf(mx, __shfl_xor(mx, off, 32));
    float p = (d < 20) ? __expf(logit - mx) : 0.f;
    float sm = p;
    #pragma unroll
    for (int off = 16; off; off >>= 1) sm += __shfl_xor(sm, off, 32);
    p *= (1.f / sm);

    const int HW[5] = {128,64,32,16,8};
    const int ST[5] = {0,16384,20480,21504,21760};
    float acc = 0.f;
    #pragma unroll
    for (int l = 0; l < 5; ++l) {
        int hw = HW[l];
        float fhw = (float)hw;
        size_t vb = ((size_t)(n*8 + h)*LIN + ST[l])*32 + d;
        #pragma unroll
        for (int pi = 0; pi < 4; ++pi) {
            const int idx = l*4 + pi;
            float w  = __shfl(p, idx, 32);
            float ox = (2*idx < 32)   ? __shfl(o0, 2*idx, 32)   : __shfl(o1, 2*idx-32, 32);
            float oy = (2*idx+1 < 32) ? __shfl(o0, 2*idx+1, 32) : __shfl(o1, 2*idx+1-32, 32);
            float gx = cx*fhw + ox - 0.5f;
            float gy = cy*fhw + oy - 0.5f;
            float x0f = floorf(gx), y0f = floorf(gy);
            float lx = gx - x0f, ly = gy - y0f;
            int x0 = (int)x0f, y0 = (int)y0f;
            int x1 = x0 + 1, y1 = y0 + 1;
            bool bx0 = (unsigned)x0 < (unsigned)hw, bx1 = (unsigned)x1 < (unsigned)hw;
            bool by0 = (unsigned)y0 < (unsigned)hw, by1 = (unsigned)y1 < (unsigned)hw;
            int x0c = min(max(x0, 0), hw-1), x1c = min(max(x1, 0), hw-1);
            int y0c = min(max(y0, 0), hw-1), y1c = min(max(y1, 0), hw-1);
            float v00 = __bfloat162float(value[vb + (size_t)(y0c*hw + x0c)*32]);
            float v01 = __bfloat162float(value[vb + (size_t)(y0c*hw + x1c)*32]);
            float v10 = __bfloat162float(value[vb + (size_t)(y1c*hw + x0c)*32]);
            float v11 = __bfloat162float(value[vb + (size_t)(y1c*hw + x1c)*32]);
            float w00 = (bx0 && by0) ? (1.f-ly)*(1.f-lx)*w : 0.f;
            float w01 = (bx1 && by0) ? (1.f-ly)*lx*w       : 0.f;
            float w10 = (bx0 && by1) ? ly*(1.f-lx)*w       : 0.f;
            float w11 = (bx1 && by1) ? ly*lx*w             : 0.f;
            acc = fmaf(w00, v00, acc);
            acc = fmaf(w01, v01, acc);
            acc = fmaf(w10, v10, acc);
            acc = fmaf(w11, v11, acc);
        }
    }
    out[(size_t)nq*256 + h*32 + d] = __float2bfloat16(acc);
}

extern "C" void kernel_launch(void* const* d_in, const int* in_sizes, int n_in,
                              void* d_out, int out_size, void* d_ws, size_t ws_size,
                              hipStream_t stream){
    const void* x_raw  = d_in[0];
    const void* src    = d_in[1];
    const void* cp_raw = d_in[2];
    char* ws = (char*)d_ws;
    size_t off = 0;
    auto alloc = [&](size_t bytes){ size_t p = off; off += (bytes + 255) & ~(size_t)255; return p; };
    int*   flag  = (int*)(ws + alloc(256));
    float* xf    = (float*)(ws + alloc((size_t)ROWS_X*DIM*4));
    float* pe    = (float*)(ws + alloc((size_t)ROWS_X*DIM*4));
    bf16*  tmpb  = (bf16*)(ws + alloc((size_t)ROWS_X*DIM*2));
    bf16*  qkv   = (bf16*)(ws + alloc((size_t)ROWS_X*768*2));
    bf16*  ffh   = (bf16*)(ws + alloc((size_t)ROWS_X*MLPD*2));
    float* offaw = (float*)(ws + alloc((size_t)ROWS_X*480*4));
    float* cpf   = (float*)(ws + alloc((size_t)ROWS_X*2*4));
    float* oab   = (float*)(ws + alloc((size_t)2*480*4));
    float2* statbuf = (float2*)(ws + alloc((size_t)6*ROWS_X*8));
    float* qkvB  = (float*)(ws + alloc((size_t)2*768*4));
    float* ff1B  = (float*)(ws + alloc((size_t)2*512*4));
    float* valB  = (float*)(ws + alloc((size_t)2*256*4));
    const int sidx[13] = {5,6,7,8,11,12,13,19,21,22,23,25,27};
    const int ssz[13]  = {512,256,512,512,512,512,512,512,512,512,512,1024,512};
    float* sp[13];
    for (int j = 0; j < 13; ++j) sp[j] = (float*)(ws + alloc((size_t)ssz[j]*4));
    short* qkvT = (short*)(ws + alloc((size_t)2*768*256*2));
    short* outT = (short*)(ws + alloc((size_t)2*256*256*2));
    short* oawT = (short*)(ws + alloc((size_t)2*480*256*2));
    short* valT = (short*)(ws + alloc((size_t)2*256*256*2));
    short* opT  = (short*)(ws + alloc((size_t)2*256*256*2));
    short* ff1T = (short*)(ws + alloc((size_t)2*512*256*2));
    short* ff2T = (short*)(ws + alloc((size_t)2*256*512*2));
    bf16*  srcn = (bf16*)(ws + alloc((size_t)ROWS_SRC*DIM*2));
    bf16*  valall = (bf16*)(ws + alloc((size_t)2*ROWS_SRC*DIM*2));
    (void)ws_size; (void)in_sizes; (void)n_in; (void)out_size;

    float* ln1_g = sp[2];  float* ln1_b = sp[3];
    float* out_b = sp[4];
    float* ln2_g = sp[5];  float* ln2_b = sp[6];
    float* val_b = sp[7];  float* op_b  = sp[8];
    float* ln3_g = sp[9];  float* ln3_b = sp[10];
    float* ff_b1 = sp[11]; float* ff_b2 = sp[12];

    detect_kernel<<<1, 256, 0, stream>>>(x_raw, flag);
    {
        PrepTab pt;
        int nb = 0;
        int nn[17];
        for (int j = 0; j < 13; ++j) { pt.src[j] = d_in[sidx[j]]; pt.dst[j] = sp[j]; nn[j] = ssz[j]; }
        pt.src[13] = cp_raw;  pt.dst[13] = cpf;  nn[13] = ROWS_X*2;
        pt.src[14] = nullptr; pt.dst[14] = (float*)(statbuf + ROWS_X); nn[14] = 5*ROWS_X*2;
        pt.dst[15] = oab;  nn[15] = 960;
        pt.dst[16] = pe;   nn[16] = ROWS_X*DIM;
        for (int j = 0; j < 17; ++j) {
            pt.n[j] = nn[j];
            pt.bs[j] = nb;
            nb += (nn[j] + 255)/256;
        }
        pt.bs[17] = nb;
        prep_kernel<<<nb, 256, 0, stream>>>(pt, d_in[15], d_in[17], d_in[5], d_in[6],
                                            cp_raw, flag);
    }
    statsconvx_kernel<<<ROWS_SRC/4 + ROWS_X/4, 256, 0, stream>>>(
        src, x_raw, pe, flag, srcn, xf, statbuf);
    {
        WT wt;
        const int widx[8] = {9,10,14,16,18,20,24,26};
        short* wdst[8] = {qkvT, outT, oawT, oawT, valT, opT, ff1T, ff2T};
        const float* wscl[8] = {ln1_g, nullptr, nullptr, nullptr, ln2_g, nullptr, ln3_g, nullptr};
        const int wK[8]  = {256,256,256,256,256,256,256,512};
        const int wN[8]  = {768,256,320,160,256,256,512,256};
        const int wld[8] = {768,256,480,480,256,256,512,256};
        const int wro[8] = {0,0,0,320,0,0,0,0};
        for (int j = 0; j < 8; ++j) {
            wt.src[j] = d_in[widx[j]]; wt.dst[j] = wdst[j]; wt.scl[j] = wscl[j];
            wt.K[j] = wK[j]; wt.N[j] = wN[j]; wt.ld[j] = wld[j]; wt.ro[j] = wro[j];
        }
        wtransall_kernel<<<dim3(16,24,16), 256, 0, stream>>>(wt, flag);
    }
    {
        BFT bt;
        bt.W[0] = d_in[9];  bt.bv[0] = ln1_b; bt.base[0] = nullptr; bt.dst[0] = qkvB; bt.N[0] = 768;
        bt.W[1] = d_in[24]; bt.bv[1] = ln3_b; bt.base[1] = ff_b1;   bt.dst[1] = ff1B; bt.N[1] = 512;
        bt.W[2] = d_in[18]; bt.bv[2] = ln2_b; bt.base[2] = val_b;   bt.dst[2] = valB; bt.N[2] = 256;
        biasfold_kernel<<<dim3(1536,2), 256, 0, stream>>>(bt, flag);
    }
    // both layers' value projections in one dispatch (XCD-grouped 1D grid)
    mgemm128_kernel<<<(ROWS_SRC/128)*4, 256, 0, stream>>>(
        (const short*)srcn, valT, valB, valall);

    int gmx = (ROWS_X + 63) / 64;   // 63
    for (int i = 0; i < 2; ++i) {
        float2* stA = statbuf + (size_t)(i ? 3 : 0)*ROWS_X;   // attn LN sums (x+pe)
        float2* stO = statbuf + (size_t)(i ? 4 : 1)*ROWS_X;   // offaw LN sums
        float2* stF = statbuf + (size_t)(i ? 5 : 2)*ROWS_X;   // ff LN sums
        // qkv = normalize(x+pe) @ (g1.qkv_w) + b1@qkv_w   (g,b folded)
        mgemm_kernel<4><<<dim3(gmx,12), 256, 0, stream>>>(
            xf, stA, nullptr, nullptr, pe, nullptr,
            qkvT + (size_t)i*768*256, qkvB + i*768, nullptr, qkv,
            ROWS_X, 256, 768, 0, 1, nullptr, nullptr, nullptr, flag);
        fattn_kernel<<<dim3(16,32), 256, 0, stream>>>((const short*)qkv, tmpb);
        // out-proj (+res into xf), accumulate offaw-LN sums of new xf
        mgemm_kernel<2><<<dim3(gmx,4), 256, 0, stream>>>(
            tmpb, nullptr, nullptr, nullptr, nullptr, nullptr,
            outT + (size_t)i*256*256, out_b + i*DIM, xf, xf,
            ROWS_X, 256, 256, 0, 0, stO, nullptr, nullptr, flag);
        // offaw = (LN(xf;ln2) + pe) @ [off|aw]_w + oab
        mgemm_kernel<3><<<dim3(gmx,8), 256, 0, stream>>>(
            xf, stO, ln2_g + i*DIM, ln2_b + i*DIM, nullptr, pe,
            oawT + (size_t)i*480*256, oab + i*480, nullptr, offaw,
            ROWS_X, 256, 480, 0, 0, nullptr, nullptr, nullptr, flag);
        sample2_kernel<<<ROWS_X, 256, 0, stream>>>(
            valall + (size_t)i*VLAYER, offaw, cpf, tmpb);
        // op-proj (+res into xf), accumulate ff-LN sums of new xf
        mgemm_kernel<2><<<dim3(gmx,4), 256, 0, stream>>>(
            tmpb, nullptr, nullptr, nullptr, nullptr, nullptr,
            opT + (size_t)i*256*256, op_b + i*DIM, xf, xf,
            ROWS_X, 256, 256, 0, 0, stF, nullptr, nullptr, flag);
        // ffh = gelu( normalize(xf) @ (g3.ff_w1) + (b3@ff_w1 + ff_b1) )
        mgemm_kernel<4><<<dim3(gmx,8), 256, 0, stream>>>(
            xf, stF, nullptr, nullptr, nullptr, nullptr,
            ff1T + (size_t)i*512*256, ff1B + i*MLPD, nullptr, ffh,
            ROWS_X, 256, 512, 1, 1, nullptr, nullptr, nullptr, flag);
        // ff2 (+res). layer0: accumulate next-layer attn sums (xf+pe). layer1: write d_out.
        if (i == 0) {
            mgemm_kernel<2><<<dim3(gmx,4), 256, 0, stream>>>(
                ffh, nullptr, nullptr, nullptr, nullptr, nullptr,
                ff2T + (size_t)i*256*512, ff_b2 + i*DIM, xf, xf,
                ROWS_X, 512, 256, 0, 0, statbuf + (size_t)3*ROWS_X, pe, nullptr, flag);
        } else {
            mgemm_kernel<2><<<dim3(gmx,4), 256, 0, stream>>>(
                ffh, nullptr, nullptr, nullptr, nullptr, nullptr,
                ff2T + (size_t)i*256*512, ff_b2 + i*DIM, xf, xf,
                ROWS_X, 512, 256, 0, 0, nullptr, nullptr, d_out, flag);
        }
    }
}

// Round 7
// 557.674 us; speedup vs baseline: 1.1285x; 1.0299x over previous
//
#include <hip/hip_runtime.h>
#include <hip/hip_bf16.h>
#include <math.h>

#define DIM 256
#define NB 4
#define LQ 1000
#define MLPD 512
#define LIN 21824
#define ROWS_X 4000
#define ROWS_SRC 87296
#define ATT_SCALE 0.17677669529663687f  /* 32^-0.5 */
#define LDK 72   /* padded LDS row (bf16 elems): 144 B, 16B-aligned */
#define VLAYER ((size_t)ROWS_SRC*256)

typedef __hip_bfloat16 bf16;
typedef __attribute__((ext_vector_type(8))) short short8;
typedef __attribute__((ext_vector_type(4))) float floatx4;

__device__ __forceinline__ float rdv(const void* p, int f, size_t i){
    if (f) return ((const float*)p)[i];
    unsigned u = ((unsigned)((const unsigned short*)p)[i]) << 16;
    union { unsigned u; float f; } c; c.u = u; return c.f;
}
__device__ __forceinline__ short f2bs(float v){
    bf16 h = __float2bfloat16(v);
    return *reinterpret_cast<short*>(&h);
}
__device__ __forceinline__ float bs2f(short s){
    union { unsigned u; float f; } c; c.u = ((unsigned)(unsigned short)s) << 16; return c.f;
}

// ---------- dtype detect ----------
__global__ void detect_kernel(const void* __restrict__ x, int* __restrict__ flag){
    const unsigned short* u = (const unsigned short*)x;
    int t = threadIdx.x;
    bool hit = false;
    #pragma unroll
    for (int k = 0; k < 4; ++k) {
        unsigned short b = u[(t*4 + k)*2];
        union { unsigned u; float f; } c; c.u = ((unsigned)b) << 16;
        if (!(fabsf(c.f) <= 1000.f)) hit = true;
    }
    unsigned long long m = __ballot(hit);
    __shared__ unsigned long long red[4];
    if ((t & 63) == 0) red[t >> 6] = m;
    __syncthreads();
    if (t == 0) flag[0] = ((red[0]|red[1]|red[2]|red[3]) != 0ULL) ? 1 : 0;
}

// ---------- one packed prep kernel: 13 convs + cpf + statzero + catb + pe ----------
struct PrepTab { const void* src[15]; float* dst[17]; int n[17]; int bs[18]; };
__global__ void prep_kernel(PrepTab t, const void* __restrict__ offb,
                            const void* __restrict__ awb, const void* __restrict__ pw,
                            const void* __restrict__ pb, const void* __restrict__ cp,
                            const int* __restrict__ flag){
    int f = flag[0];
    int bid = blockIdx.x;
    int j = 0;
    #pragma unroll 1
    while (bid >= t.bs[j+1]) ++j;
    int i = (bid - t.bs[j])*256 + threadIdx.x;
    if (i >= t.n[j]) return;
    if (j < 15) {
        t.dst[j][i] = t.src[j] ? rdv(t.src[j], f, i) : 0.f;
    } else if (j == 15) {           // catb -> oab[2][480]
        int layer = i / 480, idx = i - layer*480;
        float v = (idx < 320) ? rdv(offb, f, (size_t)layer*320 + idx)
                              : rdv(awb,  f, (size_t)layer*160 + idx - 320);
        t.dst[15][i] = v;
    } else {                        // pe[row][256]
        int row = i >> 8, c = i & 255;
        float cx = rdv(cp, f, (size_t)row*2), cy = rdv(cp, f, (size_t)row*2 + 1);
        t.dst[16][i] = cx*rdv(pw, f, c) + cy*rdv(pw, f, DIM + c) + rdv(pb, f, c);
    }
}

// ---------- all weight transposes in ONE launch, with optional K-dim scale fold ----------
struct WT { const void* src[8]; short* dst[8]; const float* scl[8];
            int K[8]; int N[8]; int ld[8]; int ro[8]; };
__global__ void wtransall_kernel(WT t, const int* __restrict__ flag){
    int j = blockIdx.z >> 1, b = blockIdx.z & 1;
    int K = t.K[j], N = t.N[j];
    int k0 = blockIdx.x*32, n0 = blockIdx.y*32;
    if (k0 >= K || n0 >= N) return;   // uniform per block, before any sync
    int f = flag[0];
    __shared__ float tt[32][33];
    int tx = threadIdx.x & 31, ty = threadIdx.x >> 5;
    size_t base = (size_t)b * K * N;
    for (int i = ty; i < 32; i += 8) {
        int k = k0 + i, n = n0 + tx;
        tt[i][tx] = (k < K && n < N) ? rdv(t.src[j], f, base + (size_t)k*N + n) : 0.f;
    }
    __syncthreads();
    int ld = t.ld[j], ro = t.ro[j];
    const float* sc = t.scl[j];
    for (int i = ty; i < 32; i += 8) {
        int n = n0 + i, k = k0 + tx;
        if (n < N && k < K) {
            float v = tt[tx][i];
            if (sc) v *= sc[(size_t)b*K + k];
            t.dst[j][(size_t)b*ld*K + (size_t)(ro+n)*K + k] = f2bs(v);
        }
    }
}

// ---------- bias folds: dst[b][n] = bvec[b] @ W[b][:,n] (+base[b][n]) ----------
struct BFT { const void* W[3]; const float* bv[3]; const float* base[3];
             float* dst[3]; int N[3]; };
__global__ __launch_bounds__(256) void biasfold_kernel(BFT t, const int* __restrict__ flag){
    int f = flag[0];
    int x = blockIdx.x, b = blockIdx.y;
    int j, n;
    if (x < 768)       { j = 0; n = x; }
    else if (x < 1280) { j = 1; n = x - 768; }
    else               { j = 2; n = x - 1280; }
    int N = t.N[j];
    int k = threadIdx.x;
    float part = t.bv[j][(size_t)b*256 + k] *
                 rdv(t.W[j], f, (size_t)b*256*N + (size_t)k*N + n);
    #pragma unroll
    for (int o = 32; o; o >>= 1) part += __shfl_xor(part, o, 64);
    __shared__ float red[4];
    int wave = k >> 6, lane = k & 63;
    if (lane == 0) red[wave] = part;
    __syncthreads();
    if (k == 0) {
        float s = red[0] + red[1] + red[2] + red[3];
        if (t.base[j]) s += t.base[j][(size_t)b*N + n];
        t.dst[j][(size_t)b*N + n] = s;
    }
}

// ---------- merged: src LN-normalize + x convert/sums + L0-attn normalized A ----------
__global__ __launch_bounds__(256) void statsconvx_kernel(const void* __restrict__ src,
        const void* __restrict__ x, const float* __restrict__ pe,
        const int* __restrict__ flag, bf16* __restrict__ srcn,
        float* __restrict__ xf, float2* __restrict__ st, bf16* __restrict__ xab){
    int f = flag[0];
    int wave = threadIdx.x >> 6, lane = threadIdx.x & 63;
    int bid = blockIdx.x;
    if (bid < ROWS_SRC/4) {
        int row = bid*4 + wave;
        float v0, v1, v2, v3;
        if (f) {
            float4 xx = *(const float4*)((const float*)src + (size_t)row*DIM + lane*4);
            v0 = xx.x; v1 = xx.y; v2 = xx.z; v3 = xx.w;
        } else {
            ushort4 u = *(const ushort4*)((const unsigned short*)src + (size_t)row*DIM + lane*4);
            v0 = bs2f((short)u.x); v1 = bs2f((short)u.y);
            v2 = bs2f((short)u.z); v3 = bs2f((short)u.w);
        }
        float s  = v0 + v1 + v2 + v3;
        float s2 = v0*v0 + v1*v1 + v2*v2 + v3*v3;
        #pragma unroll
        for (int o = 32; o; o >>= 1) {
            s  += __shfl_xor(s,  o, 64);
            s2 += __shfl_xor(s2, o, 64);
        }
        float mean = s * (1.f/DIM);
        float rstd = rsqrtf(s2 * (1.f/DIM) - mean*mean + 1e-5f);
        ushort4 o4;
        o4.x = (unsigned short)f2bs((v0-mean)*rstd);
        o4.y = (unsigned short)f2bs((v1-mean)*rstd);
        o4.z = (unsigned short)f2bs((v2-mean)*rstd);
        o4.w = (unsigned short)f2bs((v3-mean)*rstd);
        *(ushort4*)((unsigned short*)srcn + (size_t)row*DIM + lane*4) = o4;
    } else {
        int row = (bid - ROWS_SRC/4)*4 + wave;
        float4 v;
        if (f) v = *(const float4*)((const float*)x + (size_t)row*DIM + lane*4);
        else {
            ushort4 u = *(const ushort4*)((const unsigned short*)x + (size_t)row*DIM + lane*4);
            v = make_float4(bs2f((short)u.x), bs2f((short)u.y), bs2f((short)u.z), bs2f((short)u.w));
        }
        *(float4*)(xf + (size_t)row*DIM + lane*4) = v;
        float4 p = *(const float4*)(pe + (size_t)row*DIM + lane*4);
        float a0 = v.x+p.x, a1 = v.y+p.y, a2 = v.z+p.z, a3 = v.w+p.w;
        float s  = a0+a1+a2+a3;
        float s2 = a0*a0+a1*a1+a2*a2+a3*a3;
        #pragma unroll
        for (int o = 32; o; o >>= 1) {
            s  += __shfl_xor(s,  o, 64);
            s2 += __shfl_xor(s2, o, 64);
        }
        if (lane == 0) st[row] = make_float2(s, s2);
        float mean = s * (1.f/DIM);
        float rstd = rsqrtf(s2 * (1.f/DIM) - mean*mean + 1e-5f);
        ushort4 o4;
        o4.x = (unsigned short)f2bs((a0-mean)*rstd);
        o4.y = (unsigned short)f2bs((a1-mean)*rstd);
        o4.z = (unsigned short)f2bs((a2-mean)*rstd);
        o4.w = (unsigned short)f2bs((a3-mean)*rstd);
        *(ushort4*)((unsigned short*)xab + (size_t)row*DIM + lane*4) = o4;
    }
}

// ---------- xnorm: A' = LN-normalize(a [+pre]) [*g+b] [+post] -> bf16 ----------
__global__ __launch_bounds__(256) void xnorm_kernel(const float* __restrict__ a,
        const float* __restrict__ pre, const float* __restrict__ post,
        const float2* __restrict__ sums, const float* __restrict__ g,
        const float* __restrict__ b, bf16* __restrict__ out){
    int wave = threadIdx.x >> 6, lane = threadIdx.x & 63;
    int row = blockIdx.x*4 + wave;
    float4 x = *(const float4*)(a + (size_t)row*DIM + lane*4);
    if (pre) {
        float4 p = *(const float4*)(pre + (size_t)row*DIM + lane*4);
        x.x += p.x; x.y += p.y; x.z += p.z; x.w += p.w;
    }
    float2 st = sums[row];
    float mean = st.x * (1.f/256.f);
    float rstd = rsqrtf(st.y*(1.f/256.f) - mean*mean + 1e-5f);
    float v0 = (x.x-mean)*rstd, v1 = (x.y-mean)*rstd;
    float v2 = (x.z-mean)*rstd, v3 = (x.w-mean)*rstd;
    if (g) {
        int c = lane*4;
        float4 gv = *(const float4*)(g + c);
        float4 bv = *(const float4*)(b + c);
        v0 = v0*gv.x + bv.x; v1 = v1*gv.y + bv.y;
        v2 = v2*gv.z + bv.z; v3 = v3*gv.w + bv.w;
    }
    if (post) {
        float4 p = *(const float4*)(post + (size_t)row*DIM + lane*4);
        v0 += p.x; v1 += p.y; v2 += p.z; v3 += p.w;
    }
    ushort4 o4;
    o4.x = (unsigned short)f2bs(v0); o4.y = (unsigned short)f2bs(v1);
    o4.z = (unsigned short)f2bs(v2); o4.w = (unsigned short)f2bs(v3);
    *(ushort4*)((unsigned short*)out + (size_t)row*DIM + lane*4) = o4;
}

// ---------- MFMA GEMM 64x64, bf16 A only, register-prefetch staging ----------
__global__ __launch_bounds__(256) void mgemm_kernel(
    const short* __restrict__ A, const short* __restrict__ Wt,
    const float* __restrict__ bias, const float* __restrict__ res,
    void* __restrict__ Cout, int M, int K, int N, int act, int cbf,
    float2* __restrict__ statacc, const float* __restrict__ sepe,
    void* __restrict__ fin, const int* __restrict__ flag){
    __shared__ short As[64*LDK];
    __shared__ short Bs[64*LDK];
    int tid = threadIdx.x;
    int wave = tid >> 6, lane = tid & 63;
    int wm = wave >> 1, wn = wave & 1;
    int quad = lane >> 4, l16 = lane & 15;
    int row0 = blockIdx.x*64, col0 = blockIdx.y*64;
    floatx4 acc[2][2];
    #pragma unroll
    for (int i = 0; i < 2; ++i)
        #pragma unroll
        for (int j = 0; j < 2; ++j)
            acc[i][j] = (floatx4){0.f,0.f,0.f,0.f};

    int r  = tid >> 2;
    int kc = (tid & 3) * 16;
    int gr = row0 + r;
    int gc = col0 + r;
    const short8 z8 = {0,0,0,0,0,0,0,0};

    short8 ra0, ra1, rb0, rb1;
    if (gr < M) {
        const short8* p = (const short8*)(A + (size_t)gr*K + kc);
        ra0 = p[0]; ra1 = p[1];
    }
    if (gc < N) {
        const short8* p = (const short8*)(Wt + (size_t)gc*K + kc);
        rb0 = p[0]; rb1 = p[1];
    }

    for (int k0 = 0; k0 < K; k0 += 64) {
        short8 a0 = z8, a1 = z8;
        if (gr < M) { a0 = ra0; a1 = ra1; }
        *(short8*)&As[r*LDK + kc]     = a0;
        *(short8*)&As[r*LDK + kc + 8] = a1;
        short8 b0 = z8, b1 = z8;
        if (gc < N) { b0 = rb0; b1 = rb1; }
        *(short8*)&Bs[r*LDK + kc]     = b0;
        *(short8*)&Bs[r*LDK + kc + 8] = b1;
        // issue next k-step's loads before the barrier (latency hides under MFMA)
        int kn = k0 + 64;
        if (kn < K) {
            if (gr < M) {
                const short8* p = (const short8*)(A + (size_t)gr*K + kn + kc);
                ra0 = p[0]; ra1 = p[1];
            }
            if (gc < N) {
                const short8* p = (const short8*)(Wt + (size_t)gc*K + kn + kc);
                rb0 = p[0]; rb1 = p[1];
            }
        }
        __syncthreads();
        #pragma unroll
        for (int kb = 0; kb < 64; kb += 32) {
            short8 af[2], bfr[2];
            #pragma unroll
            for (int mi = 0; mi < 2; ++mi)
                af[mi] = *(const short8*)&As[(wm*32 + mi*16 + l16)*LDK + kb + quad*8];
            #pragma unroll
            for (int ni = 0; ni < 2; ++ni)
                bfr[ni] = *(const short8*)&Bs[(wn*32 + ni*16 + l16)*LDK + kb + quad*8];
            #pragma unroll
            for (int mi = 0; mi < 2; ++mi)
                #pragma unroll
                for (int ni = 0; ni < 2; ++ni)
                    acc[mi][ni] = __builtin_amdgcn_mfma_f32_16x16x32_bf16(
                        af[mi], bfr[ni], acc[mi][ni], 0, 0, 0);
        }
        __syncthreads();
    }
    // epilogue
    float vout[2][2][4];
    #pragma unroll
    for (int mi = 0; mi < 2; ++mi) {
        int rbase = row0 + wm*32 + mi*16 + quad*4;
        #pragma unroll
        for (int ni = 0; ni < 2; ++ni) {
            int c = col0 + wn*32 + ni*16 + l16;
            #pragma unroll
            for (int r2 = 0; r2 < 4; ++r2) {
                int rr = rbase + r2;
                float v = 0.f;
                if (c < N && rr < M) {
                    v = acc[mi][ni][r2];
                    if (bias) v += bias[c];
                    if (act) {  // tanh-gelu == v*sigmoid(2y)
                        float z = fminf(1.5957691216057308f*(v + 0.044715f*v*v*v), 60.f);
                        float e = __expf(z);
                        v = v * e / (e + 1.f);
                    }
                    if (res) v += res[(size_t)rr*N + c];
                }
                vout[mi][ni][r2] = v;
            }
        }
    }
    int fflag = 0;
    if (fin) fflag = flag[0];
    #pragma unroll
    for (int mi = 0; mi < 2; ++mi) {
        int rbase = row0 + wm*32 + mi*16 + quad*4;
        #pragma unroll
        for (int ni = 0; ni < 2; ++ni) {
            int c = col0 + wn*32 + ni*16 + l16;
            if (c >= N) continue;
            #pragma unroll
            for (int r2 = 0; r2 < 4; ++r2) {
                int rr = rbase + r2;
                if (rr >= M) continue;
                float v = vout[mi][ni][r2];
                if (fin) {
                    float w = isfinite(v) ? v : 0.f;
                    if (fflag) ((float*)fin)[(size_t)rr*N + c] = w;
                    else       ((bf16*)fin)[(size_t)rr*N + c] = __float2bfloat16(w);
                } else if (cbf) ((bf16*)Cout)[(size_t)rr*N + c] = __float2bfloat16(v);
                else            ((float*)Cout)[(size_t)rr*N + c] = v;
            }
        }
    }
    if (statacc) {
        #pragma unroll
        for (int mi = 0; mi < 2; ++mi) {
            int rbase = row0 + wm*32 + mi*16 + quad*4;
            #pragma unroll
            for (int r2 = 0; r2 < 4; ++r2) {
                int rr = rbase + r2;
                float sv = 0.f, sq = 0.f;
                #pragma unroll
                for (int ni = 0; ni < 2; ++ni) {
                    int c = col0 + wn*32 + ni*16 + l16;
                    float v = vout[mi][ni][r2];
                    if (sepe && rr < M) v += sepe[(size_t)rr*256 + c];
                    sv += v; sq += v*v;
                }
                #pragma unroll
                for (int o = 1; o < 16; o <<= 1) {
                    sv += __shfl_xor(sv, o, 64);
                    sq += __shfl_xor(sq, o, 64);
                }
                if (l16 == 0 && rr < M) {
                    atomicAdd(&statacc[rr].x, sv);
                    atomicAdd(&statacc[rr].y, sq);
                }
            }
        }
    }
}

// ---------- MFMA GEMM 128x128, both layers' value proj ----------
// 1D grid 2728 with XCD-aware swizzle: the 4 col-tiles of one row-panel map to
// bids {g*32+s, +8, +16, +24} -> all same (bid%8) -> same XCD -> A-panel L2 reuse.
// Epilogue stages C through LDS -> coalesced 16B head-major stores.
__global__ __launch_bounds__(256) void mgemm128_kernel(
    const short* __restrict__ A, const short* __restrict__ Wt,
    const float* __restrict__ bias, bf16* __restrict__ valall){
    const int K = 256;
    __shared__ short lds[2*128*LDK];   // As | Bs; reused as C-tile (128x136) in epilogue
    short* As = lds;
    short* Bs = lds + 128*LDK;
    int tid = threadIdx.x;
    int wave = tid >> 6, lane = tid & 63;
    int wm = wave >> 1, wn = wave & 1;
    int quad = lane >> 4, l16 = lane & 15;
    int bid = blockIdx.x;
    int panel, col;
    if (bid < 2720) {
        int g = bid >> 5, w = bid & 31;
        panel = g*8 + (w & 7);
        col = w >> 3;
    } else {
        int idx = bid - 2720;
        panel = 680 + (idx >> 2);
        col = idx & 3;
    }
    int row0 = panel*128, col0 = col*128;
    floatx4 acc[4][4];
    #pragma unroll
    for (int i = 0; i < 4; ++i)
        #pragma unroll
        for (int j = 0; j < 4; ++j)
            acc[i][j] = (floatx4){0.f,0.f,0.f,0.f};

    short8 pa[2][2], pb2[2][2];
    #pragma unroll
    for (int i = 0; i < 2; ++i) {
        int idx = tid + i*256;
        int rr = idx >> 2, kk = (idx & 3)*16;
        const short8* p = (const short8*)(A + (size_t)(row0+rr)*K + kk);
        pa[i][0] = p[0]; pa[i][1] = p[1];
        const short8* pb = (const short8*)(Wt + (size_t)(col0+rr)*K + kk);
        pb2[i][0] = pb[0]; pb2[i][1] = pb[1];
    }
    for (int k0 = 0; k0 < K; k0 += 64) {
        #pragma unroll
        for (int i = 0; i < 2; ++i) {
            int idx = tid + i*256;
            int rr = idx >> 2, kk = (idx & 3)*16;
            *(short8*)&As[rr*LDK + kk]     = pa[i][0];
            *(short8*)&As[rr*LDK + kk + 8] = pa[i][1];
            *(short8*)&Bs[rr*LDK + kk]     = pb2[i][0];
            *(short8*)&Bs[rr*LDK + kk + 8] = pb2[i][1];
        }
        int kn = k0 + 64;
        if (kn < K) {
            #pragma unroll
            for (int i = 0; i < 2; ++i) {
                int idx = tid + i*256;
                int rr = idx >> 2, kk = (idx & 3)*16;
                const short8* p = (const short8*)(A + (size_t)(row0+rr)*K + kn + kk);
                pa[i][0] = p[0]; pa[i][1] = p[1];
                const short8* pb = (const short8*)(Wt + (size_t)(col0+rr)*K + kn + kk);
                pb2[i][0] = pb[0]; pb2[i][1] = pb[1];
            }
        }
        __syncthreads();
        #pragma unroll
        for (int kb = 0; kb < 64; kb += 32) {
            short8 af[4], bfr[4];
            #pragma unroll
            for (int mi = 0; mi < 4; ++mi)
                af[mi] = *(const short8*)&As[(wm*64 + mi*16 + l16)*LDK + kb + quad*8];
            #pragma unroll
            for (int ni = 0; ni < 4; ++ni)
                bfr[ni] = *(const short8*)&Bs[(wn*64 + ni*16 + l16)*LDK + kb + quad*8];
            #pragma unroll
            for (int mi = 0; mi < 4; ++mi)
                #pragma unroll
                for (int ni = 0; ni < 4; ++ni)
                    acc[mi][ni] = __builtin_amdgcn_mfma_f32_16x16x32_bf16(
                        af[mi], bfr[ni], acc[mi][ni], 0, 0, 0);
        }
        __syncthreads();
    }
    // ---- epilogue: C tile -> LDS (bf16, +bias) -> coalesced head-major stores ----
    short* Cs = lds;   // 128 x 136 shorts = 34816 B <= 36864 B
    #pragma unroll
    for (int mi = 0; mi < 4; ++mi) {
        int lr = wm*64 + mi*16 + quad*4;
        #pragma unroll
        for (int ni = 0; ni < 4; ++ni) {
            int lc = wn*64 + ni*16 + l16;
            float bv = bias[col0 + lc];
            #pragma unroll
            for (int r2 = 0; r2 < 4; ++r2)
                Cs[(lr + r2)*136 + lc] = f2bs(acc[mi][ni][r2] + bv);
        }
    }
    __syncthreads();
    #pragma unroll
    for (int g = 0; g < 4; ++g) {
        int cbase = col0 + g*32;
        int l = cbase >> 8, h = (cbase & 255) >> 5;
        #pragma unroll
        for (int p = 0; p < 2; ++p) {
            int idx = p*256 + tid;
            int rr2 = idx >> 2;          // 0..127
            int dc = (idx & 3) * 8;      // 0,8,16,24
            short8 v = *(const short8*)&Cs[rr2*136 + g*32 + dc];
            int grr = row0 + rr2;
            unsigned n = (unsigned)grr / (unsigned)LIN;
            int pos = grr - (int)n*LIN;
            *(short8*)((short*)valall + (size_t)l*VLAYER
                       + ((size_t)(n*8+h)*LIN + pos)*32 + dc) = v;
        }
    }
}

// ---------- fused flash attention with K/V register prefetch ----------
__global__ __launch_bounds__(256) void fattn_kernel(const short* __restrict__ qkv,
                                                    bf16* __restrict__ out){
    int nh = blockIdx.y;
    int n = nh >> 3, h = nh & 7;
    int q0 = blockIdx.x * 64;
    __shared__ short Ks[64*40];
    __shared__ short VsT[32*72];
    __shared__ short Ps[64*72];
    int tid = threadIdx.x;
    int wave = tid >> 6, lane = tid & 63;
    int quad = lane >> 4, l16 = lane & 15;
    int r = tid >> 2, c8 = (tid & 3) * 8;
    const short8 z8 = {0,0,0,0,0,0,0,0};

    short8 qf = z8;
    {
        int gq = q0 + wave*16 + l16;
        if (gq < LQ) {
            short8 s = *(const short8*)(qkv + ((size_t)(n*LQ+gq))*768 + h*32 + quad*8);
            #pragma unroll
            for (int j = 0; j < 8; ++j) qf[j] = f2bs(bs2f(s[j]) * ATT_SCALE);
        }
    }
    floatx4 acc[2];
    acc[0] = (floatx4){0.f,0.f,0.f,0.f};
    acc[1] = (floatx4){0.f,0.f,0.f,0.f};
    float m[4], lsum[4];
    #pragma unroll
    for (int i = 0; i < 4; ++i) { m[i] = -3.0e38f; lsum[i] = 0.f; }

    short8 kvp = z8, vvp = z8;
    if (r < LQ) {
        const short* rp = qkv + ((size_t)(n*LQ+r))*768;
        kvp = *(const short8*)(rp + 256 + h*32 + c8);
        vvp = *(const short8*)(rp + 512 + h*32 + c8);
    }
    for (int k0 = 0; k0 < LQ; k0 += 64) {
        *(short8*)&Ks[r*40 + c8] = kvp;
        #pragma unroll
        for (int j = 0; j < 8; ++j) VsT[(c8+j)*72 + r] = vvp[j];
        short8 kvn = z8, vvn = z8;
        if (k0 + 64 < LQ) {
            int gk = k0 + 64 + r;
            if (gk < LQ) {
                const short* rp = qkv + ((size_t)(n*LQ+gk))*768;
                kvn = *(const short8*)(rp + 256 + h*32 + c8);
                vvn = *(const short8*)(rp + 512 + h*32 + c8);
            }
        }
        __syncthreads();
        floatx4 s4[4];
        #pragma unroll
        for (int kg = 0; kg < 4; ++kg) {
            short8 bfr = *(const short8*)&Ks[(kg*16 + l16)*40 + quad*8];
            s4[kg] = __builtin_amdgcn_mfma_f32_16x16x32_bf16(
                qf, bfr, (floatx4){0.f,0.f,0.f,0.f}, 0, 0, 0);
        }
        if (k0 + 64 > LQ) {
            #pragma unroll
            for (int kg = 0; kg < 4; ++kg)
                if (k0 + kg*16 + l16 >= LQ)
                    s4[kg] = (floatx4){-3.0e38f,-3.0e38f,-3.0e38f,-3.0e38f};
        }
        float fac[4], psum[4];
        #pragma unroll
        for (int r2 = 0; r2 < 4; ++r2) {
            float v = fmaxf(fmaxf(s4[0][r2], s4[1][r2]), fmaxf(s4[2][r2], s4[3][r2]));
            v = fmaxf(v, __shfl_xor(v, 1, 64));
            v = fmaxf(v, __shfl_xor(v, 2, 64));
            v = fmaxf(v, __shfl_xor(v, 4, 64));
            v = fmaxf(v, __shfl_xor(v, 8, 64));
            float mn = fmaxf(m[r2], v);
            fac[r2] = __expf(m[r2] - mn);
            m[r2] = mn;
            psum[r2] = 0.f;
        }
        #pragma unroll
        for (int kg = 0; kg < 4; ++kg)
            #pragma unroll
            for (int r2 = 0; r2 < 4; ++r2) {
                float pv = __expf(s4[kg][r2] - m[r2]);
                psum[r2] += pv;
                Ps[(wave*16 + quad*4 + r2)*72 + kg*16 + l16] = f2bs(pv);
            }
        #pragma unroll
        for (int r2 = 0; r2 < 4; ++r2) {
            psum[r2] += __shfl_xor(psum[r2], 1, 64);
            psum[r2] += __shfl_xor(psum[r2], 2, 64);
            psum[r2] += __shfl_xor(psum[r2], 4, 64);
            psum[r2] += __shfl_xor(psum[r2], 8, 64);
            lsum[r2] = lsum[r2]*fac[r2] + psum[r2];
        }
        #pragma unroll
        for (int ni = 0; ni < 2; ++ni)
            #pragma unroll
            for (int r2 = 0; r2 < 4; ++r2)
                acc[ni][r2] *= fac[r2];
        #pragma unroll
        for (int kb = 0; kb < 64; kb += 32) {
            short8 pf = *(const short8*)&Ps[(wave*16 + l16)*72 + kb + quad*8];
            #pragma unroll
            for (int ni = 0; ni < 2; ++ni) {
                short8 vf = *(const short8*)&VsT[(ni*16 + l16)*72 + kb + quad*8];
                acc[ni] = __builtin_amdgcn_mfma_f32_16x16x32_bf16(pf, vf, acc[ni], 0, 0, 0);
            }
        }
        __syncthreads();
        kvp = kvn; vvp = vvn;
    }
    #pragma unroll
    for (int r2 = 0; r2 < 4; ++r2) {
        int row = q0 + wave*16 + quad*4 + r2;
        if (row >= LQ) continue;
        float inv = 1.f / lsum[r2];
        #pragma unroll
        for (int ni = 0; ni < 2; ++ni)
            out[((size_t)(n*LQ+row))*256 + h*32 + ni*16 + l16] =
                __float2bfloat16(acc[ni][r2] * inv);
    }
}

// ---------- deformable sampling, head-major value layout ----------
__global__ __launch_bounds__(256) void sample2_kernel(
        const bf16* __restrict__ value, const float* __restrict__ offaw,
        const float* __restrict__ cp, bf16* __restrict__ out){
    int nq = blockIdx.x;
    int n = nq / LQ;
    int d = threadIdx.x & 31, h = threadIdx.x >> 5;
    float cx = cp[nq*2], cy = cp[nq*2+1];
    const float* rowp = offaw + (size_t)nq*480;
    float o0 = rowp[h*40 + d];
    float o1 = (d < 8) ? rowp[h*40 + 32 + d] : 0.f;
    float logit = (d < 20) ? rowp[320 + h*20 + d] : -3.0e38f;
    float mx = logit;
    #pragma unroll
    for (int off = 16; off; off >>= 1) mx = fmaxf(mx, __shfl_xor(mx, off, 32));
    float p = (d < 20) ? __expf(logit - mx) : 0.f;
    float sm = p;
    #pragma unroll
    for (int off = 16; off; off >>= 1) sm += __shfl_xor(sm, off, 32);
    p *= (1.f / sm);

    const int HW[5] = {128,64,32,16,8};
    const int ST[5] = {0,16384,20480,21504,21760};
    float acc = 0.f;
    #pragma unroll
    for (int l = 0; l < 5; ++l) {
        int hw = HW[l];
        float fhw = (float)hw;
        size_t vb = ((size_t)(n*8 + h)*LIN + ST[l])*32 + d;
        #pragma unroll
        for (int pi = 0; pi < 4; ++pi) {
            const int idx = l*4 + pi;
            float w  = __shfl(p, idx, 32);
            float ox = (2*idx < 32)   ? __shfl(o0, 2*idx, 32)   : __shfl(o1, 2*idx-32, 32);
            float oy = (2*idx+1 < 32) ? __shfl(o0, 2*idx+1, 32) : __shfl(o1, 2*idx+1-32, 32);
            float gx = cx*fhw + ox - 0.5f;
            float gy = cy*fhw + oy - 0.5f;
            float x0f = floorf(gx), y0f = floorf(gy);
            float lx = gx - x0f, ly = gy - y0f;
            int x0 = (int)x0f, y0 = (int)y0f;
            int x1 = x0 + 1, y1 = y0 + 1;
            bool bx0 = (unsigned)x0 < (unsigned)hw, bx1 = (unsigned)x1 < (unsigned)hw;
            bool by0 = (unsigned)y0 < (unsigned)hw, by1 = (unsigned)y1 < (unsigned)hw;
            int x0c = min(max(x0, 0), hw-1), x1c = min(max(x1, 0), hw-1);
            int y0c = min(max(y0, 0), hw-1), y1c = min(max(y1, 0), hw-1);
            float v00 = __bfloat162float(value[vb + (size_t)(y0c*hw + x0c)*32]);
            float v01 = __bfloat162float(value[vb + (size_t)(y0c*hw + x1c)*32]);
            float v10 = __bfloat162float(value[vb + (size_t)(y1c*hw + x0c)*32]);
            float v11 = __bfloat162float(value[vb + (size_t)(y1c*hw + x1c)*32]);
            float w00 = (bx0 && by0) ? (1.f-ly)*(1.f-lx)*w : 0.f;
            float w01 = (bx1 && by0) ? (1.f-ly)*lx*w       : 0.f;
            float w10 = (bx0 && by1) ? ly*(1.f-lx)*w       : 0.f;
            float w11 = (bx1 && by1) ? ly*lx*w             : 0.f;
            acc = fmaf(w00, v00, acc);
            acc = fmaf(w01, v01, acc);
            acc = fmaf(w10, v10, acc);
            acc = fmaf(w11, v11, acc);
        }
    }
    out[(size_t)nq*256 + h*32 + d] = __float2bfloat16(acc);
}

extern "C" void kernel_launch(void* const* d_in, const int* in_sizes, int n_in,
                              void* d_out, int out_size, void* d_ws, size_t ws_size,
                              hipStream_t stream){
    const void* x_raw  = d_in[0];
    const void* src    = d_in[1];
    const void* cp_raw = d_in[2];
    char* ws = (char*)d_ws;
    size_t off = 0;
    auto alloc = [&](size_t bytes){ size_t p = off; off += (bytes + 255) & ~(size_t)255; return p; };
    int*   flag  = (int*)(ws + alloc(256));
    float* xf    = (float*)(ws + alloc((size_t)ROWS_X*DIM*4));
    float* pe    = (float*)(ws + alloc((size_t)ROWS_X*DIM*4));
    bf16*  tmpb  = (bf16*)(ws + alloc((size_t)ROWS_X*DIM*2));
    bf16*  xab   = (bf16*)(ws + alloc((size_t)ROWS_X*DIM*2));
    bf16*  qkv   = (bf16*)(ws + alloc((size_t)ROWS_X*768*2));
    bf16*  ffh   = (bf16*)(ws + alloc((size_t)ROWS_X*MLPD*2));
    float* offaw = (float*)(ws + alloc((size_t)ROWS_X*480*4));
    float* cpf   = (float*)(ws + alloc((size_t)ROWS_X*2*4));
    float* oab   = (float*)(ws + alloc((size_t)2*480*4));
    float2* statbuf = (float2*)(ws + alloc((size_t)6*ROWS_X*8));
    float* qkvB  = (float*)(ws + alloc((size_t)2*768*4));
    float* ff1B  = (float*)(ws + alloc((size_t)2*512*4));
    float* valB  = (float*)(ws + alloc((size_t)2*256*4));
    const int sidx[13] = {5,6,7,8,11,12,13,19,21,22,23,25,27};
    const int ssz[13]  = {512,256,512,512,512,512,512,512,512,512,512,1024,512};
    float* sp[13];
    for (int j = 0; j < 13; ++j) sp[j] = (float*)(ws + alloc((size_t)ssz[j]*4));
    short* qkvT = (short*)(ws + alloc((size_t)2*768*256*2));
    short* outT = (short*)(ws + alloc((size_t)2*256*256*2));
    short* oawT = (short*)(ws + alloc((size_t)2*480*256*2));
    short* valT = (short*)(ws + alloc((size_t)2*256*256*2));
    short* opT  = (short*)(ws + alloc((size_t)2*256*256*2));
    short* ff1T = (short*)(ws + alloc((size_t)2*512*256*2));
    short* ff2T = (short*)(ws + alloc((size_t)2*256*512*2));
    bf16*  srcn = (bf16*)(ws + alloc((size_t)ROWS_SRC*DIM*2));
    bf16*  valall = (bf16*)(ws + alloc((size_t)2*ROWS_SRC*DIM*2));
    (void)ws_size; (void)in_sizes; (void)n_in; (void)out_size;

    float* ln1_g = sp[2];  float* ln1_b = sp[3];
    float* out_b = sp[4];
    float* ln2_g = sp[5];  float* ln2_b = sp[6];
    float* val_b = sp[7];  float* op_b  = sp[8];
    float* ln3_g = sp[9];  float* ln3_b = sp[10];
    float* ff_b1 = sp[11]; float* ff_b2 = sp[12];

    detect_kernel<<<1, 256, 0, stream>>>(x_raw, flag);
    {
        PrepTab pt;
        int nb = 0;
        int nn[17];
        for (int j = 0; j < 13; ++j) { pt.src[j] = d_in[sidx[j]]; pt.dst[j] = sp[j]; nn[j] = ssz[j]; }
        pt.src[13] = cp_raw;  pt.dst[13] = cpf;  nn[13] = ROWS_X*2;
        pt.src[14] = nullptr; pt.dst[14] = (float*)(statbuf + ROWS_X); nn[14] = 5*ROWS_X*2;
        pt.dst[15] = oab;  nn[15] = 960;
        pt.dst[16] = pe;   nn[16] = ROWS_X*DIM;
        for (int j = 0; j < 17; ++j) {
            pt.n[j] = nn[j];
            pt.bs[j] = nb;
            nb += (nn[j] + 255)/256;
        }
        pt.bs[17] = nb;
        prep_kernel<<<nb, 256, 0, stream>>>(pt, d_in[15], d_in[17], d_in[5], d_in[6],
                                            cp_raw, flag);
    }
    statsconvx_kernel<<<ROWS_SRC/4 + ROWS_X/4, 256, 0, stream>>>(
        src, x_raw, pe, flag, srcn, xf, statbuf, xab);
    {
        WT wt;
        const int widx[8] = {9,10,14,16,18,20,24,26};
        short* wdst[8] = {qkvT, outT, oawT, oawT, valT, opT, ff1T, ff2T};
        const float* wscl[8] = {ln1_g, nullptr, nullptr, nullptr, ln2_g, nullptr, ln3_g, nullptr};
        const int wK[8]  = {256,256,256,256,256,256,256,512};
        const int wN[8]  = {768,256,320,160,256,256,512,256};
        const int wld[8] = {768,256,480,480,256,256,512,256};
        const int wro[8] = {0,0,0,320,0,0,0,0};
        for (int j = 0; j < 8; ++j) {
            wt.src[j] = d_in[widx[j]]; wt.dst[j] = wdst[j]; wt.scl[j] = wscl[j];
            wt.K[j] = wK[j]; wt.N[j] = wN[j]; wt.ld[j] = wld[j]; wt.ro[j] = wro[j];
        }
        wtransall_kernel<<<dim3(16,24,16), 256, 0, stream>>>(wt, flag);
    }
    {
        BFT bt;
        bt.W[0] = d_in[9];  bt.bv[0] = ln1_b; bt.base[0] = nullptr; bt.dst[0] = qkvB; bt.N[0] = 768;
        bt.W[1] = d_in[24]; bt.bv[1] = ln3_b; bt.base[1] = ff_b1;   bt.dst[1] = ff1B; bt.N[1] = 512;
        bt.W[2] = d_in[18]; bt.bv[2] = ln2_b; bt.base[2] = val_b;   bt.dst[2] = valB; bt.N[2] = 256;
        biasfold_kernel<<<dim3(1536,2), 256, 0, stream>>>(bt, flag);
    }
    // both layers' value projections in one dispatch (XCD-grouped 1D grid)
    mgemm128_kernel<<<(ROWS_SRC/128)*4, 256, 0, stream>>>(
        (const short*)srcn, valT, valB, valall);

    int gmx = (ROWS_X + 63) / 64;   // 63
    for (int i = 0; i < 2; ++i) {
        float2* stA = statbuf + (size_t)(i ? 3 : 0)*ROWS_X;   // attn LN sums (x+pe)
        float2* stO = statbuf + (size_t)(i ? 4 : 1)*ROWS_X;   // offaw LN sums
        float2* stF = statbuf + (size_t)(i ? 5 : 2)*ROWS_X;   // ff LN sums
        // qkv = xab @ (g1.qkv_w) + b1@qkv_w   (xab pre-normalized; L0 from statsconvx)
        if (i == 1)
            xnorm_kernel<<<ROWS_X/4, 256, 0, stream>>>(xf, pe, nullptr, stA,
                                                       nullptr, nullptr, xab);
        mgemm_kernel<<<dim3(gmx,12), 256, 0, stream>>>(
            (const short*)xab, qkvT + (size_t)i*768*256, qkvB + i*768, nullptr, qkv,
            ROWS_X, 256, 768, 0, 1, nullptr, nullptr, nullptr, flag);
        fattn_kernel<<<dim3(16,32), 256, 0, stream>>>((const short*)qkv, tmpb);
        // out-proj (+res into xf), accumulate offaw-LN sums of new xf
        mgemm_kernel<<<dim3(gmx,4), 256, 0, stream>>>(
            (const short*)tmpb, outT + (size_t)i*256*256, out_b + i*DIM, xf, xf,
            ROWS_X, 256, 256, 0, 0, stO, nullptr, nullptr, flag);
        // xab = LN(xf;ln2) + pe ; offaw = xab @ [off|aw]_w + oab
        xnorm_kernel<<<ROWS_X/4, 256, 0, stream>>>(xf, nullptr, pe, stO,
                                                   ln2_g + i*DIM, ln2_b + i*DIM, xab);
        mgemm_kernel<<<dim3(gmx,8), 256, 0, stream>>>(
            (const short*)xab, oawT + (size_t)i*480*256, oab + i*480, nullptr, offaw,
            ROWS_X, 256, 480, 0, 0, nullptr, nullptr, nullptr, flag);
        sample2_kernel<<<ROWS_X, 256, 0, stream>>>(
            valall + (size_t)i*VLAYER, offaw, cpf, tmpb);
        // op-proj (+res into xf), accumulate ff-LN sums of new xf
        mgemm_kernel<<<dim3(gmx,4), 256, 0, stream>>>(
            (const short*)tmpb, opT + (size_t)i*256*256, op_b + i*DIM, xf, xf,
            ROWS_X, 256, 256, 0, 0, stF, nullptr, nullptr, flag);
        // xab = normalize(xf) ; ffh = gelu( xab @ (g3.ff_w1) + (b3@ff_w1 + ff_b1) )
        xnorm_kernel<<<ROWS_X/4, 256, 0, stream>>>(xf, nullptr, nullptr, stF,
                                                   nullptr, nullptr, xab);
        mgemm_kernel<<<dim3(gmx,8), 256, 0, stream>>>(
            (const short*)xab, ff1T + (size_t)i*512*256, ff1B + i*MLPD, nullptr, ffh,
            ROWS_X, 256, 512, 1, 1, nullptr, nullptr, nullptr, flag);
        // ff2 (+res). layer0: accumulate next-layer attn sums (xf+pe). layer1: write d_out.
        if (i == 0) {
            mgemm_kernel<<<dim3(gmx,4), 256, 0, stream>>>(
                (const short*)ffh, ff2T + (size_t)i*256*512, ff_b2 + i*DIM, xf, xf,
                ROWS_X, 512, 256, 0, 0, statbuf + (size_t)3*ROWS_X, pe, nullptr, flag);
        } else {
            mgemm_kernel<<<dim3(gmx,4), 256, 0, stream>>>(
                (const short*)ffh, ff2T + (size_t)i*256*512, ff_b2 + i*DIM, xf, xf,
                ROWS_X, 512, 256, 0, 0, nullptr, nullptr, d_out, flag);
        }
    }
}

// Round 8
// 543.075 us; speedup vs baseline: 1.1588x; 1.0269x over previous
//
#include <hip/hip_runtime.h>
#include <hip/hip_bf16.h>
#include <math.h>

#define DIM 256
#define NB 4
#define LQ 1000
#define MLPD 512
#define LIN 21824
#define ROWS_X 4000
#define ROWS_SRC 87296
#define ATT_SCALE 0.17677669529663687f  /* 32^-0.5 */
#define LDK 72   /* padded LDS row (bf16 elems): 144 B, 16B-aligned */
#define VLAYER ((size_t)ROWS_SRC*256)

typedef __hip_bfloat16 bf16;
typedef __attribute__((ext_vector_type(8))) short short8;
typedef __attribute__((ext_vector_type(4))) float floatx4;

__device__ __forceinline__ float rdv(const void* p, int f, size_t i){
    if (f) return ((const float*)p)[i];
    unsigned u = ((unsigned)((const unsigned short*)p)[i]) << 16;
    union { unsigned u; float f; } c; c.u = u; return c.f;
}
__device__ __forceinline__ short f2bs(float v){
    bf16 h = __float2bfloat16(v);
    return *reinterpret_cast<short*>(&h);
}
__device__ __forceinline__ float bs2f(short s){
    union { unsigned u; float f; } c; c.u = ((unsigned)(unsigned short)s) << 16; return c.f;
}

// ---------- dtype detect ----------
__global__ void detect_kernel(const void* __restrict__ x, int* __restrict__ flag){
    const unsigned short* u = (const unsigned short*)x;
    int t = threadIdx.x;
    bool hit = false;
    #pragma unroll
    for (int k = 0; k < 4; ++k) {
        unsigned short b = u[(t*4 + k)*2];
        union { unsigned u; float f; } c; c.u = ((unsigned)b) << 16;
        if (!(fabsf(c.f) <= 1000.f)) hit = true;
    }
    unsigned long long m = __ballot(hit);
    __shared__ unsigned long long red[4];
    if ((t & 63) == 0) red[t >> 6] = m;
    __syncthreads();
    if (t == 0) flag[0] = ((red[0]|red[1]|red[2]|red[3]) != 0ULL) ? 1 : 0;
}

// ---------- ONE setup kernel: everything that depends only on flag ----------
// Block ranges (dispatch order: long job first, small jobs backfill):
//  [0,21824)            src LN-normalize -> srcn
//  [21824,23344)        8 weight transposes x 2 layers (1520 exact blocks)
//  [23344,26416)        biasfold (3072)
//  [26416,27416)        x convert + inline pe + attn-LN sums + xab (1000)
//  [27416,27443)        13 small conversions (27)
//  [27443,27475)        cpf (32)
//  [27475,27632)        stat-buffer zero (157)
//  [27632,27636)        catb -> oab (4)
struct SetupTab {
    const void* csrc[13]; float* cdst[13];
    const void* cp; float* cpf;
    float* statz;
    const void* offb; const void* awb; float* oab;
    const void* src; bf16* srcn;
    const void* x; const void* posw; const void* posb;
    float* xf; float2* st; bf16* xab; float* pe;
    const void* wsrc[8]; short* wdst[8]; const void* wscl[8];
    const void* bfW[3]; const void* bfBv[3]; const void* bfBase[3]; float* bfDst[3];
};
__global__ __launch_bounds__(256) void setup_kernel(SetupTab t, const int* __restrict__ flag){
    int f = flag[0];
    int bid = blockIdx.x;
    int tid = threadIdx.x;
    __shared__ float tt[32][33];
    if (bid < 21824) {
        // --- src LN-normalize ---
        int wave = tid >> 6, lane = tid & 63;
        int row = bid*4 + wave;
        float v0, v1, v2, v3;
        if (f) {
            float4 xx = *(const float4*)((const float*)t.src + (size_t)row*DIM + lane*4);
            v0 = xx.x; v1 = xx.y; v2 = xx.z; v3 = xx.w;
        } else {
            ushort4 u = *(const ushort4*)((const unsigned short*)t.src + (size_t)row*DIM + lane*4);
            v0 = bs2f((short)u.x); v1 = bs2f((short)u.y);
            v2 = bs2f((short)u.z); v3 = bs2f((short)u.w);
        }
        float s  = v0 + v1 + v2 + v3;
        float s2 = v0*v0 + v1*v1 + v2*v2 + v3*v3;
        #pragma unroll
        for (int o = 32; o; o >>= 1) {
            s  += __shfl_xor(s,  o, 64);
            s2 += __shfl_xor(s2, o, 64);
        }
        float mean = s * (1.f/DIM);
        float rstd = rsqrtf(s2 * (1.f/DIM) - mean*mean + 1e-5f);
        ushort4 o4;
        o4.x = (unsigned short)f2bs((v0-mean)*rstd);
        o4.y = (unsigned short)f2bs((v1-mean)*rstd);
        o4.z = (unsigned short)f2bs((v2-mean)*rstd);
        o4.w = (unsigned short)f2bs((v3-mean)*rstd);
        *(ushort4*)((unsigned short*)t.srcn + (size_t)row*DIM + lane*4) = o4;
        return;
    }
    bid -= 21824;
    if (bid < 1520) {
        // --- weight transpose: W[b][K][N] -> Wt[b][ld][K] bf16 (optional scale fold) ---
        const int cum[9] = {0,192,256,336,376,440,504,632,760};
        const int wN[8]  = {768,256,320,160,256,256,512,256};
        const int wK[8]  = {256,256,256,256,256,256,256,512};
        const int wld[8] = {768,256,480,480,256,256,512,256};
        const int wro[8] = {0,0,0,320,0,0,0,0};
        int b = bid >= 760;
        int r = b ? bid - 760 : bid;
        int j = 0;
        #pragma unroll 1
        while (r >= cum[j+1]) ++j;
        int rel = r - cum[j];
        int ncols = wN[j] >> 5;
        int k0 = (rel / ncols) * 32, n0 = (rel % ncols) * 32;
        int K = wK[j], N = wN[j];
        int tx = tid & 31, ty = tid >> 5;
        size_t base = (size_t)b * K * N;
        for (int i = ty; i < 32; i += 8)
            tt[i][tx] = rdv(t.wsrc[j], f, base + (size_t)(k0+i)*N + (n0+tx));
        __syncthreads();
        int ld = wld[j], ro = wro[j];
        const void* sc = t.wscl[j];
        for (int i = ty; i < 32; i += 8) {
            int n = n0 + i, k = k0 + tx;
            float v = tt[tx][i];
            if (sc) v *= rdv(sc, f, (size_t)b*K + k);
            t.wdst[j][(size_t)b*ld*K + (size_t)(ro+n)*K + k] = f2bs(v);
        }
        return;
    }
    bid -= 1520;
    if (bid < 3072) {
        // --- biasfold: dst[b][n] = bv[b] @ W[b][:,n] (+base) ---
        int b = bid >= 1536;
        int x = b ? bid - 1536 : bid;
        const int bN[3] = {768,512,256};
        int j, n;
        if (x < 768)       { j = 0; n = x; }
        else if (x < 1280) { j = 1; n = x - 768; }
        else               { j = 2; n = x - 1280; }
        int N = bN[j];
        int k = tid;
        float part = rdv(t.bfBv[j], f, (size_t)b*256 + k) *
                     rdv(t.bfW[j], f, (size_t)b*256*N + (size_t)k*N + n);
        #pragma unroll
        for (int o = 32; o; o >>= 1) part += __shfl_xor(part, o, 64);
        __shared__ float red[4];
        int wave = k >> 6, lane = k & 63;
        if (lane == 0) red[wave] = part;
        __syncthreads();
        if (k == 0) {
            float s = red[0] + red[1] + red[2] + red[3];
            if (t.bfBase[j]) s += rdv(t.bfBase[j], f, (size_t)b*N + n);
            t.bfDst[j][(size_t)b*N + n] = s;
        }
        return;
    }
    bid -= 3072;
    if (bid < 1000) {
        // --- x convert + inline pe + attn-LN sums + xab ---
        int wave = tid >> 6, lane = tid & 63;
        int row = bid*4 + wave;
        int c = lane*4;
        float4 v;
        if (f) v = *(const float4*)((const float*)t.x + (size_t)row*DIM + c);
        else {
            ushort4 u = *(const ushort4*)((const unsigned short*)t.x + (size_t)row*DIM + c);
            v = make_float4(bs2f((short)u.x), bs2f((short)u.y), bs2f((short)u.z), bs2f((short)u.w));
        }
        *(float4*)(t.xf + (size_t)row*DIM + c) = v;
        float cx = rdv(t.cp, f, (size_t)row*2), cy = rdv(t.cp, f, (size_t)row*2 + 1);
        float4 p;
        p.x = cx*rdv(t.posw, f, c)   + cy*rdv(t.posw, f, DIM+c)   + rdv(t.posb, f, c);
        p.y = cx*rdv(t.posw, f, c+1) + cy*rdv(t.posw, f, DIM+c+1) + rdv(t.posb, f, c+1);
        p.z = cx*rdv(t.posw, f, c+2) + cy*rdv(t.posw, f, DIM+c+2) + rdv(t.posb, f, c+2);
        p.w = cx*rdv(t.posw, f, c+3) + cy*rdv(t.posw, f, DIM+c+3) + rdv(t.posb, f, c+3);
        *(float4*)(t.pe + (size_t)row*DIM + c) = p;
        float a0 = v.x+p.x, a1 = v.y+p.y, a2 = v.z+p.z, a3 = v.w+p.w;
        float s  = a0+a1+a2+a3;
        float s2 = a0*a0+a1*a1+a2*a2+a3*a3;
        #pragma unroll
        for (int o = 32; o; o >>= 1) {
            s  += __shfl_xor(s,  o, 64);
            s2 += __shfl_xor(s2, o, 64);
        }
        if (lane == 0) t.st[row] = make_float2(s, s2);
        float mean = s * (1.f/DIM);
        float rstd = rsqrtf(s2 * (1.f/DIM) - mean*mean + 1e-5f);
        ushort4 o4;
        o4.x = (unsigned short)f2bs((a0-mean)*rstd);
        o4.y = (unsigned short)f2bs((a1-mean)*rstd);
        o4.z = (unsigned short)f2bs((a2-mean)*rstd);
        o4.w = (unsigned short)f2bs((a3-mean)*rstd);
        *(ushort4*)((unsigned short*)t.xab + (size_t)row*DIM + c) = o4;
        return;
    }
    bid -= 1000;
    if (bid < 27) {
        const int cs[14] = {0,2,3,5,7,9,11,13,15,17,19,21,25,27};
        const int ssz[13] = {512,256,512,512,512,512,512,512,512,512,512,1024,512};
        int j = 0;
        #pragma unroll 1
        while (bid >= cs[j+1]) ++j;
        int i = (bid - cs[j])*256 + tid;
        if (i < ssz[j]) t.cdst[j][i] = rdv(t.csrc[j], f, i);
        return;
    }
    bid -= 27;
    if (bid < 32) {
        int i = bid*256 + tid;
        if (i < ROWS_X*2) t.cpf[i] = rdv(t.cp, f, i);
        return;
    }
    bid -= 32;
    if (bid < 157) {
        int i = bid*256 + tid;
        if (i < 5*ROWS_X*2) t.statz[i] = 0.f;
        return;
    }
    bid -= 157;
    {
        int i = bid*256 + tid;
        if (i >= 960) return;
        int layer = i / 480, idx = i - layer*480;
        float v = (idx < 320) ? rdv(t.offb, f, (size_t)layer*320 + idx)
                              : rdv(t.awb,  f, (size_t)layer*160 + idx - 320);
        t.oab[i] = v;
    }
}

// ---------- xnorm: A' = LN-normalize(a [+pre]) [*g+b] [+post] -> bf16 ----------
__global__ __launch_bounds__(256) void xnorm_kernel(const float* __restrict__ a,
        const float* __restrict__ pre, const float* __restrict__ post,
        const float2* __restrict__ sums, const float* __restrict__ g,
        const float* __restrict__ b, bf16* __restrict__ out){
    int wave = threadIdx.x >> 6, lane = threadIdx.x & 63;
    int row = blockIdx.x*4 + wave;
    float4 x = *(const float4*)(a + (size_t)row*DIM + lane*4);
    if (pre) {
        float4 p = *(const float4*)(pre + (size_t)row*DIM + lane*4);
        x.x += p.x; x.y += p.y; x.z += p.z; x.w += p.w;
    }
    float2 st = sums[row];
    float mean = st.x * (1.f/256.f);
    float rstd = rsqrtf(st.y*(1.f/256.f) - mean*mean + 1e-5f);
    float v0 = (x.x-mean)*rstd, v1 = (x.y-mean)*rstd;
    float v2 = (x.z-mean)*rstd, v3 = (x.w-mean)*rstd;
    if (g) {
        int c = lane*4;
        float4 gv = *(const float4*)(g + c);
        float4 bv = *(const float4*)(b + c);
        v0 = v0*gv.x + bv.x; v1 = v1*gv.y + bv.y;
        v2 = v2*gv.z + bv.z; v3 = v3*gv.w + bv.w;
    }
    if (post) {
        float4 p = *(const float4*)(post + (size_t)row*DIM + lane*4);
        v0 += p.x; v1 += p.y; v2 += p.z; v3 += p.w;
    }
    ushort4 o4;
    o4.x = (unsigned short)f2bs(v0); o4.y = (unsigned short)f2bs(v1);
    o4.z = (unsigned short)f2bs(v2); o4.w = (unsigned short)f2bs(v3);
    *(ushort4*)((unsigned short*)out + (size_t)row*DIM + lane*4) = o4;
}

// ---------- MFMA GEMM 64x64, bf16 A only, register-prefetch staging ----------
__global__ __launch_bounds__(256) void mgemm_kernel(
    const short* __restrict__ A, const short* __restrict__ Wt,
    const float* __restrict__ bias, const float* __restrict__ res,
    void* __restrict__ Cout, int M, int K, int N, int act, int cbf,
    float2* __restrict__ statacc, const float* __restrict__ sepe,
    void* __restrict__ fin, const int* __restrict__ flag){
    __shared__ short As[64*LDK];
    __shared__ short Bs[64*LDK];
    int tid = threadIdx.x;
    int wave = tid >> 6, lane = tid & 63;
    int wm = wave >> 1, wn = wave & 1;
    int quad = lane >> 4, l16 = lane & 15;
    int row0 = blockIdx.x*64, col0 = blockIdx.y*64;
    floatx4 acc[2][2];
    #pragma unroll
    for (int i = 0; i < 2; ++i)
        #pragma unroll
        for (int j = 0; j < 2; ++j)
            acc[i][j] = (floatx4){0.f,0.f,0.f,0.f};

    int r  = tid >> 2;
    int kc = (tid & 3) * 16;
    int gr = row0 + r;
    int gc = col0 + r;
    const short8 z8 = {0,0,0,0,0,0,0,0};

    short8 ra0, ra1, rb0, rb1;
    if (gr < M) {
        const short8* p = (const short8*)(A + (size_t)gr*K + kc);
        ra0 = p[0]; ra1 = p[1];
    }
    if (gc < N) {
        const short8* p = (const short8*)(Wt + (size_t)gc*K + kc);
        rb0 = p[0]; rb1 = p[1];
    }

    for (int k0 = 0; k0 < K; k0 += 64) {
        short8 a0 = z8, a1 = z8;
        if (gr < M) { a0 = ra0; a1 = ra1; }
        *(short8*)&As[r*LDK + kc]     = a0;
        *(short8*)&As[r*LDK + kc + 8] = a1;
        short8 b0 = z8, b1 = z8;
        if (gc < N) { b0 = rb0; b1 = rb1; }
        *(short8*)&Bs[r*LDK + kc]     = b0;
        *(short8*)&Bs[r*LDK + kc + 8] = b1;
        // issue next k-step's loads before the barrier (latency hides under MFMA)
        int kn = k0 + 64;
        if (kn < K) {
            if (gr < M) {
                const short8* p = (const short8*)(A + (size_t)gr*K + kn + kc);
                ra0 = p[0]; ra1 = p[1];
            }
            if (gc < N) {
                const short8* p = (const short8*)(Wt + (size_t)gc*K + kn + kc);
                rb0 = p[0]; rb1 = p[1];
            }
        }
        __syncthreads();
        #pragma unroll
        for (int kb = 0; kb < 64; kb += 32) {
            short8 af[2], bfr[2];
            #pragma unroll
            for (int mi = 0; mi < 2; ++mi)
                af[mi] = *(const short8*)&As[(wm*32 + mi*16 + l16)*LDK + kb + quad*8];
            #pragma unroll
            for (int ni = 0; ni < 2; ++ni)
                bfr[ni] = *(const short8*)&Bs[(wn*32 + ni*16 + l16)*LDK + kb + quad*8];
            #pragma unroll
            for (int mi = 0; mi < 2; ++mi)
                #pragma unroll
                for (int ni = 0; ni < 2; ++ni)
                    acc[mi][ni] = __builtin_amdgcn_mfma_f32_16x16x32_bf16(
                        af[mi], bfr[ni], acc[mi][ni], 0, 0, 0);
        }
        __syncthreads();
    }
    // epilogue
    float vout[2][2][4];
    #pragma unroll
    for (int mi = 0; mi < 2; ++mi) {
        int rbase = row0 + wm*32 + mi*16 + quad*4;
        #pragma unroll
        for (int ni = 0; ni < 2; ++ni) {
            int c = col0 + wn*32 + ni*16 + l16;
            #pragma unroll
            for (int r2 = 0; r2 < 4; ++r2) {
                int rr = rbase + r2;
                float v = 0.f;
                if (c < N && rr < M) {
                    v = acc[mi][ni][r2];
                    if (bias) v += bias[c];
                    if (act) {  // tanh-gelu == v*sigmoid(2y)
                        float z = fminf(1.5957691216057308f*(v + 0.044715f*v*v*v), 60.f);
                        float e = __expf(z);
                        v = v * e / (e + 1.f);
                    }
                    if (res) v += res[(size_t)rr*N + c];
                }
                vout[mi][ni][r2] = v;
            }
        }
    }
    int fflag = 0;
    if (fin) fflag = flag[0];
    #pragma unroll
    for (int mi = 0; mi < 2; ++mi) {
        int rbase = row0 + wm*32 + mi*16 + quad*4;
        #pragma unroll
        for (int ni = 0; ni < 2; ++ni) {
            int c = col0 + wn*32 + ni*16 + l16;
            if (c >= N) continue;
            #pragma unroll
            for (int r2 = 0; r2 < 4; ++r2) {
                int rr = rbase + r2;
                if (rr >= M) continue;
                float v = vout[mi][ni][r2];
                if (fin) {
                    float w = isfinite(v) ? v : 0.f;
                    if (fflag) ((float*)fin)[(size_t)rr*N + c] = w;
                    else       ((bf16*)fin)[(size_t)rr*N + c] = __float2bfloat16(w);
                } else if (cbf) ((bf16*)Cout)[(size_t)rr*N + c] = __float2bfloat16(v);
                else            ((float*)Cout)[(size_t)rr*N + c] = v;
            }
        }
    }
    if (statacc) {
        #pragma unroll
        for (int mi = 0; mi < 2; ++mi) {
            int rbase = row0 + wm*32 + mi*16 + quad*4;
            #pragma unroll
            for (int r2 = 0; r2 < 4; ++r2) {
                int rr = rbase + r2;
                float sv = 0.f, sq = 0.f;
                #pragma unroll
                for (int ni = 0; ni < 2; ++ni) {
                    int c = col0 + wn*32 + ni*16 + l16;
                    float v = vout[mi][ni][r2];
                    if (sepe && rr < M) v += sepe[(size_t)rr*256 + c];
                    sv += v; sq += v*v;
                }
                #pragma unroll
                for (int o = 1; o < 16; o <<= 1) {
                    sv += __shfl_xor(sv, o, 64);
                    sq += __shfl_xor(sq, o, 64);
                }
                if (l16 == 0 && rr < M) {
                    atomicAdd(&statacc[rr].x, sv);
                    atomicAdd(&statacc[rr].y, sq);
                }
            }
        }
    }
}

// ---------- MFMA GEMM 128x128, both layers' value proj ----------
// 1D grid 2728 with XCD-aware swizzle: the 4 col-tiles of one row-panel map to
// bids {g*32+s, +8, +16, +24} -> all same (bid%8) -> same XCD -> A-panel L2 reuse.
// Epilogue stages C through LDS -> coalesced 16B head-major stores.
__global__ __launch_bounds__(256) void mgemm128_kernel(
    const short* __restrict__ A, const short* __restrict__ Wt,
    const float* __restrict__ bias, bf16* __restrict__ valall){
    const int K = 256;
    __shared__ short lds[2*128*LDK];   // As | Bs; reused as C-tile (128x136) in epilogue
    short* As = lds;
    short* Bs = lds + 128*LDK;
    int tid = threadIdx.x;
    int wave = tid >> 6, lane = tid & 63;
    int wm = wave >> 1, wn = wave & 1;
    int quad = lane >> 4, l16 = lane & 15;
    int bid = blockIdx.x;
    int panel, col;
    if (bid < 2720) {
        int g = bid >> 5, w = bid & 31;
        panel = g*8 + (w & 7);
        col = w >> 3;
    } else {
        int idx = bid - 2720;
        panel = 680 + (idx >> 2);
        col = idx & 3;
    }
    int row0 = panel*128, col0 = col*128;
    floatx4 acc[4][4];
    #pragma unroll
    for (int i = 0; i < 4; ++i)
        #pragma unroll
        for (int j = 0; j < 4; ++j)
            acc[i][j] = (floatx4){0.f,0.f,0.f,0.f};

    short8 pa[2][2], pb2[2][2];
    #pragma unroll
    for (int i = 0; i < 2; ++i) {
        int idx = tid + i*256;
        int rr = idx >> 2, kk = (idx & 3)*16;
        const short8* p = (const short8*)(A + (size_t)(row0+rr)*K + kk);
        pa[i][0] = p[0]; pa[i][1] = p[1];
        const short8* pb = (const short8*)(Wt + (size_t)(col0+rr)*K + kk);
        pb2[i][0] = pb[0]; pb2[i][1] = pb[1];
    }
    for (int k0 = 0; k0 < K; k0 += 64) {
        #pragma unroll
        for (int i = 0; i < 2; ++i) {
            int idx = tid + i*256;
            int rr = idx >> 2, kk = (idx & 3)*16;
            *(short8*)&As[rr*LDK + kk]     = pa[i][0];
            *(short8*)&As[rr*LDK + kk + 8] = pa[i][1];
            *(short8*)&Bs[rr*LDK + kk]     = pb2[i][0];
            *(short8*)&Bs[rr*LDK + kk + 8] = pb2[i][1];
        }
        int kn = k0 + 64;
        if (kn < K) {
            #pragma unroll
            for (int i = 0; i < 2; ++i) {
                int idx = tid + i*256;
                int rr = idx >> 2, kk = (idx & 3)*16;
                const short8* p = (const short8*)(A + (size_t)(row0+rr)*K + kn + kk);
                pa[i][0] = p[0]; pa[i][1] = p[1];
                const short8* pb = (const short8*)(Wt + (size_t)(col0+rr)*K + kn + kk);
                pb2[i][0] = pb[0]; pb2[i][1] = pb[1];
            }
        }
        __syncthreads();
        #pragma unroll
        for (int kb = 0; kb < 64; kb += 32) {
            short8 af[4], bfr[4];
            #pragma unroll
            for (int mi = 0; mi < 4; ++mi)
                af[mi] = *(const short8*)&As[(wm*64 + mi*16 + l16)*LDK + kb + quad*8];
            #pragma unroll
            for (int ni = 0; ni < 4; ++ni)
                bfr[ni] = *(const short8*)&Bs[(wn*64 + ni*16 + l16)*LDK + kb + quad*8];
            #pragma unroll
            for (int mi = 0; mi < 4; ++mi)
                #pragma unroll
                for (int ni = 0; ni < 4; ++ni)
                    acc[mi][ni] = __builtin_amdgcn_mfma_f32_16x16x32_bf16(
                        af[mi], bfr[ni], acc[mi][ni], 0, 0, 0);
        }
        __syncthreads();
    }
    // ---- epilogue: C tile -> LDS (bf16, +bias) -> coalesced head-major stores ----
    short* Cs = lds;   // 128 x 136 shorts = 34816 B <= 36864 B
    #pragma unroll
    for (int mi = 0; mi < 4; ++mi) {
        int lr = wm*64 + mi*16 + quad*4;
        #pragma unroll
        for (int ni = 0; ni < 4; ++ni) {
            int lc = wn*64 + ni*16 + l16;
            float bv = bias[col0 + lc];
            #pragma unroll
            for (int r2 = 0; r2 < 4; ++r2)
                Cs[(lr + r2)*136 + lc] = f2bs(acc[mi][ni][r2] + bv);
        }
    }
    __syncthreads();
    #pragma unroll
    for (int g = 0; g < 4; ++g) {
        int cbase = col0 + g*32;
        int l = cbase >> 8, h = (cbase & 255) >> 5;
        #pragma unroll
        for (int p = 0; p < 2; ++p) {
            int idx = p*256 + tid;
            int rr2 = idx >> 2;          // 0..127
            int dc = (idx & 3) * 8;      // 0,8,16,24
            short8 v = *(const short8*)&Cs[rr2*136 + g*32 + dc];
            int grr = row0 + rr2;
            unsigned n = (unsigned)grr / (unsigned)LIN;
            int pos = grr - (int)n*LIN;
            *(short8*)((short*)valall + (size_t)l*VLAYER
                       + ((size_t)(n*8+h)*LIN + pos)*32 + dc) = v;
        }
    }
}

// ---------- fused flash attention with K/V register prefetch ----------
__global__ __launch_bounds__(256) void fattn_kernel(const short* __restrict__ qkv,
                                                    bf16* __restrict__ out){
    int nh = blockIdx.y;
    int n = nh >> 3, h = nh & 7;
    int q0 = blockIdx.x * 64;
    __shared__ short Ks[64*40];
    __shared__ short VsT[32*72];
    __shared__ short Ps[64*72];
    int tid = threadIdx.x;
    int wave = tid >> 6, lane = tid & 63;
    int quad = lane >> 4, l16 = lane & 15;
    int r = tid >> 2, c8 = (tid & 3) * 8;
    const short8 z8 = {0,0,0,0,0,0,0,0};

    short8 qf = z8;
    {
        int gq = q0 + wave*16 + l16;
        if (gq < LQ) {
            short8 s = *(const short8*)(qkv + ((size_t)(n*LQ+gq))*768 + h*32 + quad*8);
            #pragma unroll
            for (int j = 0; j < 8; ++j) qf[j] = f2bs(bs2f(s[j]) * ATT_SCALE);
        }
    }
    floatx4 acc[2];
    acc[0] = (floatx4){0.f,0.f,0.f,0.f};
    acc[1] = (floatx4){0.f,0.f,0.f,0.f};
    float m[4], lsum[4];
    #pragma unroll
    for (int i = 0; i < 4; ++i) { m[i] = -3.0e38f; lsum[i] = 0.f; }

    short8 kvp = z8, vvp = z8;
    if (r < LQ) {
        const short* rp = qkv + ((size_t)(n*LQ+r))*768;
        kvp = *(const short8*)(rp + 256 + h*32 + c8);
        vvp = *(const short8*)(rp + 512 + h*32 + c8);
    }
    for (int k0 = 0; k0 < LQ; k0 += 64) {
        *(short8*)&Ks[r*40 + c8] = kvp;
        #pragma unroll
        for (int j = 0; j < 8; ++j) VsT[(c8+j)*72 + r] = vvp[j];
        short8 kvn = z8, vvn = z8;
        if (k0 + 64 < LQ) {
            int gk = k0 + 64 + r;
            if (gk < LQ) {
                const short* rp = qkv + ((size_t)(n*LQ+gk))*768;
                kvn = *(const short8*)(rp + 256 + h*32 + c8);
                vvn = *(const short8*)(rp + 512 + h*32 + c8);
            }
        }
        __syncthreads();
        floatx4 s4[4];
        #pragma unroll
        for (int kg = 0; kg < 4; ++kg) {
            short8 bfr = *(const short8*)&Ks[(kg*16 + l16)*40 + quad*8];
            s4[kg] = __builtin_amdgcn_mfma_f32_16x16x32_bf16(
                qf, bfr, (floatx4){0.f,0.f,0.f,0.f}, 0, 0, 0);
        }
        if (k0 + 64 > LQ) {
            #pragma unroll
            for (int kg = 0; kg < 4; ++kg)
                if (k0 + kg*16 + l16 >= LQ)
                    s4[kg] = (floatx4){-3.0e38f,-3.0e38f,-3.0e38f,-3.0e38f};
        }
        float fac[4], psum[4];
        #pragma unroll
        for (int r2 = 0; r2 < 4; ++r2) {
            float v = fmaxf(fmaxf(s4[0][r2], s4[1][r2]), fmaxf(s4[2][r2], s4[3][r2]));
            v = fmaxf(v, __shfl_xor(v, 1, 64));
            v = fmaxf(v, __shfl_xor(v, 2, 64));
            v = fmaxf(v, __shfl_xor(v, 4, 64));
            v = fmaxf(v, __shfl_xor(v, 8, 64));
            float mn = fmaxf(m[r2], v);
            fac[r2] = __expf(m[r2] - mn);
            m[r2] = mn;
            psum[r2] = 0.f;
        }
        #pragma unroll
        for (int kg = 0; kg < 4; ++kg)
            #pragma unroll
            for (int r2 = 0; r2 < 4; ++r2) {
                float pv = __expf(s4[kg][r2] - m[r2]);
                psum[r2] += pv;
                Ps[(wave*16 + quad*4 + r2)*72 + kg*16 + l16] = f2bs(pv);
            }
        #pragma unroll
        for (int r2 = 0; r2 < 4; ++r2) {
            psum[r2] += __shfl_xor(psum[r2], 1, 64);
            psum[r2] += __shfl_xor(psum[r2], 2, 64);
            psum[r2] += __shfl_xor(psum[r2], 4, 64);
            psum[r2] += __shfl_xor(psum[r2], 8, 64);
            lsum[r2] = lsum[r2]*fac[r2] + psum[r2];
        }
        #pragma unroll
        for (int ni = 0; ni < 2; ++ni)
            #pragma unroll
            for (int r2 = 0; r2 < 4; ++r2)
                acc[ni][r2] *= fac[r2];
        #pragma unroll
        for (int kb = 0; kb < 64; kb += 32) {
            short8 pf = *(const short8*)&Ps[(wave*16 + l16)*72 + kb + quad*8];
            #pragma unroll
            for (int ni = 0; ni < 2; ++ni) {
                short8 vf = *(const short8*)&VsT[(ni*16 + l16)*72 + kb + quad*8];
                acc[ni] = __builtin_amdgcn_mfma_f32_16x16x32_bf16(pf, vf, acc[ni], 0, 0, 0);
            }
        }
        __syncthreads();
        kvp = kvn; vvp = vvn;
    }
    #pragma unroll
    for (int r2 = 0; r2 < 4; ++r2) {
        int row = q0 + wave*16 + quad*4 + r2;
        if (row >= LQ) continue;
        float inv = 1.f / lsum[r2];
        #pragma unroll
        for (int ni = 0; ni < 2; ++ni)
            out[((size_t)(n*LQ+row))*256 + h*32 + ni*16 + l16] =
                __float2bfloat16(acc[ni][r2] * inv);
    }
}

// ---------- deformable sampling, head-major value layout ----------
__global__ __launch_bounds__(256) void sample2_kernel(
        const bf16* __restrict__ value, const float* __restrict__ offaw,
        const float* __restrict__ cp, bf16* __restrict__ out){
    int nq = blockIdx.x;
    int n = nq / LQ;
    int d = threadIdx.x & 31, h = threadIdx.x >> 5;
    float cx = cp[nq*2], cy = cp[nq*2+1];
    const float* rowp = offaw + (size_t)nq*480;
    float o0 = rowp[h*40 + d];
    float o1 = (d < 8) ? rowp[h*40 + 32 + d] : 0.f;
    float logit = (d < 20) ? rowp[320 + h*20 + d] : -3.0e38f;
    float mx = logit;
    #pragma unroll
    for (int off = 16; off; off >>= 1) mx = fmaxf(mx, __shfl_xor(mx, off, 32));
    float p = (d < 20) ? __expf(logit - mx) : 0.f;
    float sm = p;
    #pragma unroll
    for (int off = 16; off; off >>= 1) sm += __shfl_xor(sm, off, 32);
    p *= (1.f / sm);

    const int HW[5] = {128,64,32,16,8};
    const int ST[5] = {0,16384,20480,21504,21760};
    float acc = 0.f;
    #pragma unroll
    for (int l = 0; l < 5; ++l) {
        int hw = HW[l];
        float fhw = (float)hw;
        size_t vb = ((size_t)(n*8 + h)*LIN + ST[l])*32 + d;
        #pragma unroll
        for (int pi = 0; pi < 4; ++pi) {
            const int idx = l*4 + pi;
            float w  = __shfl(p, idx, 32);
            float ox = (2*idx < 32)   ? __shfl(o0, 2*idx, 32)   : __shfl(o1, 2*idx-32, 32);
            float oy = (2*idx+1 < 32) ? __shfl(o0, 2*idx+1, 32) : __shfl(o1, 2*idx+1-32, 32);
            float gx = cx*fhw + ox - 0.5f;
            float gy = cy*fhw + oy - 0.5f;
            float x0f = floorf(gx), y0f = floorf(gy);
            float lx = gx - x0f, ly = gy - y0f;
            int x0 = (int)x0f, y0 = (int)y0f;
            int x1 = x0 + 1, y1 = y0 + 1;
            bool bx0 = (unsigned)x0 < (unsigned)hw, bx1 = (unsigned)x1 < (unsigned)hw;
            bool by0 = (unsigned)y0 < (unsigned)hw, by1 = (unsigned)y1 < (unsigned)hw;
            int x0c = min(max(x0, 0), hw-1), x1c = min(max(x1, 0), hw-1);
            int y0c = min(max(y0, 0), hw-1), y1c = min(max(y1, 0), hw-1);
            float v00 = __bfloat162float(value[vb + (size_t)(y0c*hw + x0c)*32]);
            float v01 = __bfloat162float(value[vb + (size_t)(y0c*hw + x1c)*32]);
            float v10 = __bfloat162float(value[vb + (size_t)(y1c*hw + x0c)*32]);
            float v11 = __bfloat162float(value[vb + (size_t)(y1c*hw + x1c)*32]);
            float w00 = (bx0 && by0) ? (1.f-ly)*(1.f-lx)*w : 0.f;
            float w01 = (bx1 && by0) ? (1.f-ly)*lx*w       : 0.f;
            float w10 = (bx0 && by1) ? ly*(1.f-lx)*w       : 0.f;
            float w11 = (bx1 && by1) ? ly*lx*w             : 0.f;
            acc = fmaf(w00, v00, acc);
            acc = fmaf(w01, v01, acc);
            acc = fmaf(w10, v10, acc);
            acc = fmaf(w11, v11, acc);
        }
    }
    out[(size_t)nq*256 + h*32 + d] = __float2bfloat16(acc);
}

extern "C" void kernel_launch(void* const* d_in, const int* in_sizes, int n_in,
                              void* d_out, int out_size, void* d_ws, size_t ws_size,
                              hipStream_t stream){
    const void* x_raw  = d_in[0];
    const void* src    = d_in[1];
    const void* cp_raw = d_in[2];
    char* ws = (char*)d_ws;
    size_t off = 0;
    auto alloc = [&](size_t bytes){ size_t p = off; off += (bytes + 255) & ~(size_t)255; return p; };
    int*   flag  = (int*)(ws + alloc(256));
    float* xf    = (float*)(ws + alloc((size_t)ROWS_X*DIM*4));
    float* pe    = (float*)(ws + alloc((size_t)ROWS_X*DIM*4));
    bf16*  tmpb  = (bf16*)(ws + alloc((size_t)ROWS_X*DIM*2));
    bf16*  xab   = (bf16*)(ws + alloc((size_t)ROWS_X*DIM*2));
    bf16*  qkv   = (bf16*)(ws + alloc((size_t)ROWS_X*768*2));
    bf16*  ffh   = (bf16*)(ws + alloc((size_t)ROWS_X*MLPD*2));
    float* offaw = (float*)(ws + alloc((size_t)ROWS_X*480*4));
    float* cpf   = (float*)(ws + alloc((size_t)ROWS_X*2*4));
    float* oab   = (float*)(ws + alloc((size_t)2*480*4));
    float2* statbuf = (float2*)(ws + alloc((size_t)6*ROWS_X*8));
    float* qkvB  = (float*)(ws + alloc((size_t)2*768*4));
    float* ff1B  = (float*)(ws + alloc((size_t)2*512*4));
    float* valB  = (float*)(ws + alloc((size_t)2*256*4));
    const int sidx[13] = {5,6,7,8,11,12,13,19,21,22,23,25,27};
    const int ssz[13]  = {512,256,512,512,512,512,512,512,512,512,512,1024,512};
    float* sp[13];
    for (int j = 0; j < 13; ++j) sp[j] = (float*)(ws + alloc((size_t)ssz[j]*4));
    short* qkvT = (short*)(ws + alloc((size_t)2*768*256*2));
    short* outT = (short*)(ws + alloc((size_t)2*256*256*2));
    short* oawT = (short*)(ws + alloc((size_t)2*480*256*2));
    short* valT = (short*)(ws + alloc((size_t)2*256*256*2));
    short* opT  = (short*)(ws + alloc((size_t)2*256*256*2));
    short* ff1T = (short*)(ws + alloc((size_t)2*512*256*2));
    short* ff2T = (short*)(ws + alloc((size_t)2*256*512*2));
    bf16*  srcn = (bf16*)(ws + alloc((size_t)ROWS_SRC*DIM*2));
    bf16*  valall = (bf16*)(ws + alloc((size_t)2*ROWS_SRC*DIM*2));
    (void)ws_size; (void)in_sizes; (void)n_in; (void)out_size;

    float* ln2_g = sp[5];  float* ln2_b = sp[6];
    float* out_b = sp[4];
    float* op_b  = sp[8];
    float* ff_b2 = sp[12];

    detect_kernel<<<1, 256, 0, stream>>>(x_raw, flag);
    {
        SetupTab t;
        for (int j = 0; j < 13; ++j) { t.csrc[j] = d_in[sidx[j]]; t.cdst[j] = sp[j]; }
        t.cp = cp_raw; t.cpf = cpf;
        t.statz = (float*)(statbuf + ROWS_X);
        t.offb = d_in[15]; t.awb = d_in[17]; t.oab = oab;
        t.src = src; t.srcn = srcn;
        t.x = x_raw; t.posw = d_in[5]; t.posb = d_in[6];
        t.xf = xf; t.st = statbuf; t.xab = xab; t.pe = pe;
        const int widx[8] = {9,10,14,16,18,20,24,26};
        short* wdst[8] = {qkvT, outT, oawT, oawT, valT, opT, ff1T, ff2T};
        const void* wscl[8] = {d_in[7], nullptr, nullptr, nullptr, d_in[12], nullptr, d_in[22], nullptr};
        for (int j = 0; j < 8; ++j) { t.wsrc[j] = d_in[widx[j]]; t.wdst[j] = wdst[j]; t.wscl[j] = wscl[j]; }
        t.bfW[0] = d_in[9];  t.bfBv[0] = d_in[8];  t.bfBase[0] = nullptr;  t.bfDst[0] = qkvB;
        t.bfW[1] = d_in[24]; t.bfBv[1] = d_in[23]; t.bfBase[1] = d_in[25]; t.bfDst[1] = ff1B;
        t.bfW[2] = d_in[18]; t.bfBv[2] = d_in[13]; t.bfBase[2] = d_in[19]; t.bfDst[2] = valB;
        setup_kernel<<<27636, 256, 0, stream>>>(t, flag);
    }
    // both layers' value projections in one dispatch (XCD-grouped 1D grid)
    mgemm128_kernel<<<(ROWS_SRC/128)*4, 256, 0, stream>>>(
        (const short*)srcn, valT, valB, valall);

    int gmx = (ROWS_X + 63) / 64;   // 63
    for (int i = 0; i < 2; ++i) {
        float2* stA = statbuf + (size_t)(i ? 3 : 0)*ROWS_X;   // attn LN sums (x+pe)
        float2* stO = statbuf + (size_t)(i ? 4 : 1)*ROWS_X;   // offaw LN sums
        float2* stF = statbuf + (size_t)(i ? 5 : 2)*ROWS_X;   // ff LN sums
        // qkv = xab @ (g1.qkv_w) + b1@qkv_w   (xab pre-normalized; L0 from setup)
        if (i == 1)
            xnorm_kernel<<<ROWS_X/4, 256, 0, stream>>>(xf, pe, nullptr, stA,
                                                       nullptr, nullptr, xab);
        mgemm_kernel<<<dim3(gmx,12), 256, 0, stream>>>(
            (const short*)xab, qkvT + (size_t)i*768*256, qkvB + i*768, nullptr, qkv,
            ROWS_X, 256, 768, 0, 1, nullptr, nullptr, nullptr, flag);
        fattn_kernel<<<dim3(16,32), 256, 0, stream>>>((const short*)qkv, tmpb);
        // out-proj (+res into xf), accumulate offaw-LN sums of new xf
        mgemm_kernel<<<dim3(gmx,4), 256, 0, stream>>>(
            (const short*)tmpb, outT + (size_t)i*256*256, out_b + i*DIM, xf, xf,
            ROWS_X, 256, 256, 0, 0, stO, nullptr, nullptr, flag);
        // xab = LN(xf;ln2) + pe ; offaw = xab @ [off|aw]_w + oab
        xnorm_kernel<<<ROWS_X/4, 256, 0, stream>>>(xf, nullptr, pe, stO,
                                                   ln2_g + i*DIM, ln2_b + i*DIM, xab);
        mgemm_kernel<<<dim3(gmx,8), 256, 0, stream>>>(
            (const short*)xab, oawT + (size_t)i*480*256, oab + i*480, nullptr, offaw,
            ROWS_X, 256, 480, 0, 0, nullptr, nullptr, nullptr, flag);
        sample2_kernel<<<ROWS_X, 256, 0, stream>>>(
            valall + (size_t)i*VLAYER, offaw, cpf, tmpb);
        // op-proj (+res into xf), accumulate ff-LN sums of new xf
        mgemm_kernel<<<dim3(gmx,4), 256, 0, stream>>>(
            (const short*)tmpb, opT + (size_t)i*256*256, op_b + i*DIM, xf, xf,
            ROWS_X, 256, 256, 0, 0, stF, nullptr, nullptr, flag);
        // xab = normalize(xf) ; ffh = gelu( xab @ (g3.ff_w1) + (b3@ff_w1 + ff_b1) )
        xnorm_kernel<<<ROWS_X/4, 256, 0, stream>>>(xf, nullptr, nullptr, stF,
                                                   nullptr, nullptr, xab);
        mgemm_kernel<<<dim3(gmx,8), 256, 0, stream>>>(
            (const short*)xab, ff1T + (size_t)i*512*256, ff1B + i*MLPD, nullptr, ffh,
            ROWS_X, 256, 512, 1, 1, nullptr, nullptr, nullptr, flag);
        // ff2 (+res). layer0: accumulate next-layer attn sums (xf+pe). layer1: write d_out.
        if (i == 0) {
            mgemm_kernel<<<dim3(gmx,4), 256, 0, stream>>>(
                (const short*)ffh, ff2T + (size_t)i*256*512, ff_b2 + i*DIM, xf, xf,
                ROWS_X, 512, 256, 0, 0, statbuf + (size_t)3*ROWS_X, pe, nullptr, flag);
        } else {
            mgemm_kernel<<<dim3(gmx,4), 256, 0, stream>>>(
                (const short*)ffh, ff2T + (size_t)i*256*512, ff_b2 + i*DIM, xf, xf,
                ROWS_X, 512, 256, 0, 0, nullptr, nullptr, d_out, flag);
        }
    }
}

// Round 9
// 542.685 us; speedup vs baseline: 1.1596x; 1.0007x over previous
//
#include <hip/hip_runtime.h>
#include <hip/hip_bf16.h>
#include <math.h>

#define DIM 256
#define NB 4
#define LQ 1000
#define MLPD 512
#define LIN 21824
#define ROWS_X 4000
#define ROWS_SRC 87296
#define ATT_SCALE 0.17677669529663687f  /* 32^-0.5 */
#define LDK 72   /* padded LDS row (bf16 elems): 144 B, 16B-aligned */
#define VLAYER ((size_t)ROWS_SRC*256)

typedef __hip_bfloat16 bf16;
typedef __attribute__((ext_vector_type(8))) short short8;
typedef __attribute__((ext_vector_type(4))) float floatx4;

__device__ __forceinline__ float rdv(const void* p, int f, size_t i){
    if (f) return ((const float*)p)[i];
    unsigned u = ((unsigned)((const unsigned short*)p)[i]) << 16;
    union { unsigned u; float f; } c; c.u = u; return c.f;
}
__device__ __forceinline__ short f2bs(float v){
    bf16 h = __float2bfloat16(v);
    return *reinterpret_cast<short*>(&h);
}
__device__ __forceinline__ float bs2f(short s){
    union { unsigned u; float f; } c; c.u = ((unsigned)(unsigned short)s) << 16; return c.f;
}

// ---------- dtype detect ----------
__global__ void detect_kernel(const void* __restrict__ x, int* __restrict__ flag){
    const unsigned short* u = (const unsigned short*)x;
    int t = threadIdx.x;
    bool hit = false;
    #pragma unroll
    for (int k = 0; k < 4; ++k) {
        unsigned short b = u[(t*4 + k)*2];
        union { unsigned u; float f; } c; c.u = ((unsigned)b) << 16;
        if (!(fabsf(c.f) <= 1000.f)) hit = true;
    }
    unsigned long long m = __ballot(hit);
    __shared__ unsigned long long red[4];
    if ((t & 63) == 0) red[t >> 6] = m;
    __syncthreads();
    if (t == 0) flag[0] = ((red[0]|red[1]|red[2]|red[3]) != 0ULL) ? 1 : 0;
}

// ---------- ONE setup kernel: everything that depends only on flag ----------
// Block ranges (dispatch order: long job first, small jobs backfill):
//  [0,10912)            src LN-normalize -> srcn (1 row / 32 lanes, 16B/lane)
//  [10912,12432)        8 weight transposes x 2 layers (1520 exact blocks)
//  [12432,15504)        biasfold (3072)
//  [15504,16504)        x convert + inline pe + attn-LN sums + xab (1000)
//  [16504,16531)        13 small conversions (27)
//  [16531,16563)        cpf (32)
//  [16563,16720)        stat-buffer zero (157)
//  [16720,16724)        catb -> oab (4)
struct SetupTab {
    const void* csrc[13]; float* cdst[13];
    const void* cp; float* cpf;
    float* statz;
    const void* offb; const void* awb; float* oab;
    const void* src; bf16* srcn;
    const void* x; const void* posw; const void* posb;
    float* xf; float2* st; bf16* xab; float* pe;
    const void* wsrc[8]; short* wdst[8]; const void* wscl[8];
    const void* bfW[3]; const void* bfBv[3]; const void* bfBase[3]; float* bfDst[3];
};
__global__ __launch_bounds__(256) void setup_kernel(SetupTab t, const int* __restrict__ flag){
    int f = flag[0];
    int bid = blockIdx.x;
    int tid = threadIdx.x;
    __shared__ float tt[32][33];
    if (bid < 10912) {
        // --- src LN-normalize: 8 rows/block, 1 row per 32 lanes, 16B/lane ---
        int half = tid >> 5, l = tid & 31;
        int row = bid*8 + half;
        float v[8];
        if (f) {
            const float4* p = (const float4*)((const float*)t.src + (size_t)row*DIM + l*8);
            float4 a = p[0], b = p[1];
            v[0]=a.x; v[1]=a.y; v[2]=a.z; v[3]=a.w;
            v[4]=b.x; v[5]=b.y; v[6]=b.z; v[7]=b.w;
        } else {
            short8 u = *(const short8*)((const short*)t.src + (size_t)row*DIM + l*8);
            #pragma unroll
            for (int j = 0; j < 8; ++j) v[j] = bs2f(u[j]);
        }
        float s = 0.f, s2 = 0.f;
        #pragma unroll
        for (int j = 0; j < 8; ++j) { s += v[j]; s2 += v[j]*v[j]; }
        #pragma unroll
        for (int o = 16; o; o >>= 1) {
            s  += __shfl_xor(s,  o, 32);
            s2 += __shfl_xor(s2, o, 32);
        }
        float mean = s * (1.f/DIM);
        float rstd = rsqrtf(s2 * (1.f/DIM) - mean*mean + 1e-5f);
        short8 o8;
        #pragma unroll
        for (int j = 0; j < 8; ++j) o8[j] = f2bs((v[j]-mean)*rstd);
        *(short8*)((short*)t.srcn + (size_t)row*DIM + l*8) = o8;
        return;
    }
    bid -= 10912;
    if (bid < 1520) {
        // --- weight transpose: W[b][K][N] -> Wt[b][ld][K] bf16 (optional scale fold) ---
        const int cum[9] = {0,192,256,336,376,440,504,632,760};
        const int wN[8]  = {768,256,320,160,256,256,512,256};
        const int wK[8]  = {256,256,256,256,256,256,256,512};
        const int wld[8] = {768,256,480,480,256,256,512,256};
        const int wro[8] = {0,0,0,320,0,0,0,0};
        int b = bid >= 760;
        int r = b ? bid - 760 : bid;
        int j = 0;
        #pragma unroll 1
        while (r >= cum[j+1]) ++j;
        int rel = r - cum[j];
        int ncols = wN[j] >> 5;
        int k0 = (rel / ncols) * 32, n0 = (rel % ncols) * 32;
        int K = wK[j], N = wN[j];
        int tx = tid & 31, ty = tid >> 5;
        size_t base = (size_t)b * K * N;
        for (int i = ty; i < 32; i += 8)
            tt[i][tx] = rdv(t.wsrc[j], f, base + (size_t)(k0+i)*N + (n0+tx));
        __syncthreads();
        int ld = wld[j], ro = wro[j];
        const void* sc = t.wscl[j];
        for (int i = ty; i < 32; i += 8) {
            int n = n0 + i, k = k0 + tx;
            float v = tt[tx][i];
            if (sc) v *= rdv(sc, f, (size_t)b*K + k);
            t.wdst[j][(size_t)b*ld*K + (size_t)(ro+n)*K + k] = f2bs(v);
        }
        return;
    }
    bid -= 1520;
    if (bid < 3072) {
        // --- biasfold: dst[b][n] = bv[b] @ W[b][:,n] (+base) ---
        int b = bid >= 1536;
        int x = b ? bid - 1536 : bid;
        const int bN[3] = {768,512,256};
        int j, n;
        if (x < 768)       { j = 0; n = x; }
        else if (x < 1280) { j = 1; n = x - 768; }
        else               { j = 2; n = x - 1280; }
        int N = bN[j];
        int k = tid;
        float part = rdv(t.bfBv[j], f, (size_t)b*256 + k) *
                     rdv(t.bfW[j], f, (size_t)b*256*N + (size_t)k*N + n);
        #pragma unroll
        for (int o = 32; o; o >>= 1) part += __shfl_xor(part, o, 64);
        __shared__ float red[4];
        int wave = k >> 6, lane = k & 63;
        if (lane == 0) red[wave] = part;
        __syncthreads();
        if (k == 0) {
            float s = red[0] + red[1] + red[2] + red[3];
            if (t.bfBase[j]) s += rdv(t.bfBase[j], f, (size_t)b*N + n);
            t.bfDst[j][(size_t)b*N + n] = s;
        }
        return;
    }
    bid -= 3072;
    if (bid < 1000) {
        // --- x convert + inline pe + attn-LN sums + xab ---
        int wave = tid >> 6, lane = tid & 63;
        int row = bid*4 + wave;
        int c = lane*4;
        float4 v;
        if (f) v = *(const float4*)((const float*)t.x + (size_t)row*DIM + c);
        else {
            ushort4 u = *(const ushort4*)((const unsigned short*)t.x + (size_t)row*DIM + c);
            v = make_float4(bs2f((short)u.x), bs2f((short)u.y), bs2f((short)u.z), bs2f((short)u.w));
        }
        *(float4*)(t.xf + (size_t)row*DIM + c) = v;
        float cx = rdv(t.cp, f, (size_t)row*2), cy = rdv(t.cp, f, (size_t)row*2 + 1);
        float4 p;
        p.x = cx*rdv(t.posw, f, c)   + cy*rdv(t.posw, f, DIM+c)   + rdv(t.posb, f, c);
        p.y = cx*rdv(t.posw, f, c+1) + cy*rdv(t.posw, f, DIM+c+1) + rdv(t.posb, f, c+1);
        p.z = cx*rdv(t.posw, f, c+2) + cy*rdv(t.posw, f, DIM+c+2) + rdv(t.posb, f, c+2);
        p.w = cx*rdv(t.posw, f, c+3) + cy*rdv(t.posw, f, DIM+c+3) + rdv(t.posb, f, c+3);
        *(float4*)(t.pe + (size_t)row*DIM + c) = p;
        float a0 = v.x+p.x, a1 = v.y+p.y, a2 = v.z+p.z, a3 = v.w+p.w;
        float s  = a0+a1+a2+a3;
        float s2 = a0*a0+a1*a1+a2*a2+a3*a3;
        #pragma unroll
        for (int o = 32; o; o >>= 1) {
            s  += __shfl_xor(s,  o, 64);
            s2 += __shfl_xor(s2, o, 64);
        }
        if (lane == 0) t.st[row] = make_float2(s, s2);
        float mean = s * (1.f/DIM);
        float rstd = rsqrtf(s2 * (1.f/DIM) - mean*mean + 1e-5f);
        ushort4 o4;
        o4.x = (unsigned short)f2bs((a0-mean)*rstd);
        o4.y = (unsigned short)f2bs((a1-mean)*rstd);
        o4.z = (unsigned short)f2bs((a2-mean)*rstd);
        o4.w = (unsigned short)f2bs((a3-mean)*rstd);
        *(ushort4*)((unsigned short*)t.xab + (size_t)row*DIM + c) = o4;
        return;
    }
    bid -= 1000;
    if (bid < 27) {
        const int cs[14] = {0,2,3,5,7,9,11,13,15,17,19,21,25,27};
        const int ssz[13] = {512,256,512,512,512,512,512,512,512,512,512,1024,512};
        int j = 0;
        #pragma unroll 1
        while (bid >= cs[j+1]) ++j;
        int i = (bid - cs[j])*256 + tid;
        if (i < ssz[j]) t.cdst[j][i] = rdv(t.csrc[j], f, i);
        return;
    }
    bid -= 27;
    if (bid < 32) {
        int i = bid*256 + tid;
        if (i < ROWS_X*2) t.cpf[i] = rdv(t.cp, f, i);
        return;
    }
    bid -= 32;
    if (bid < 157) {
        int i = bid*256 + tid;
        if (i < 5*ROWS_X*2) t.statz[i] = 0.f;
        return;
    }
    bid -= 157;
    {
        int i = bid*256 + tid;
        if (i >= 960) return;
        int layer = i / 480, idx = i - layer*480;
        float v = (idx < 320) ? rdv(t.offb, f, (size_t)layer*320 + idx)
                              : rdv(t.awb,  f, (size_t)layer*160 + idx - 320);
        t.oab[i] = v;
    }
}

// ---------- xnorm: A' = LN-normalize(a [+pre]) [*g+b] [+post] -> bf16 ----------
__global__ __launch_bounds__(256) void xnorm_kernel(const float* __restrict__ a,
        const float* __restrict__ pre, const float* __restrict__ post,
        const float2* __restrict__ sums, const float* __restrict__ g,
        const float* __restrict__ b, bf16* __restrict__ out){
    int wave = threadIdx.x >> 6, lane = threadIdx.x & 63;
    int row = blockIdx.x*4 + wave;
    float4 x = *(const float4*)(a + (size_t)row*DIM + lane*4);
    if (pre) {
        float4 p = *(const float4*)(pre + (size_t)row*DIM + lane*4);
        x.x += p.x; x.y += p.y; x.z += p.z; x.w += p.w;
    }
    float2 st = sums[row];
    float mean = st.x * (1.f/256.f);
    float rstd = rsqrtf(st.y*(1.f/256.f) - mean*mean + 1e-5f);
    float v0 = (x.x-mean)*rstd, v1 = (x.y-mean)*rstd;
    float v2 = (x.z-mean)*rstd, v3 = (x.w-mean)*rstd;
    if (g) {
        int c = lane*4;
        float4 gv = *(const float4*)(g + c);
        float4 bv = *(const float4*)(b + c);
        v0 = v0*gv.x + bv.x; v1 = v1*gv.y + bv.y;
        v2 = v2*gv.z + bv.z; v3 = v3*gv.w + bv.w;
    }
    if (post) {
        float4 p = *(const float4*)(post + (size_t)row*DIM + lane*4);
        v0 += p.x; v1 += p.y; v2 += p.z; v3 += p.w;
    }
    ushort4 o4;
    o4.x = (unsigned short)f2bs(v0); o4.y = (unsigned short)f2bs(v1);
    o4.z = (unsigned short)f2bs(v2); o4.w = (unsigned short)f2bs(v3);
    *(ushort4*)((unsigned short*)out + (size_t)row*DIM + lane*4) = o4;
}

// ---------- MFMA GEMM 64x64, bf16 A only, register-prefetch staging ----------
__global__ __launch_bounds__(256) void mgemm_kernel(
    const short* __restrict__ A, const short* __restrict__ Wt,
    const float* __restrict__ bias, const float* __restrict__ res,
    void* __restrict__ Cout, int M, int K, int N, int act, int cbf,
    float2* __restrict__ statacc, const float* __restrict__ sepe,
    void* __restrict__ fin, const int* __restrict__ flag){
    __shared__ short As[64*LDK];
    __shared__ short Bs[64*LDK];
    int tid = threadIdx.x;
    int wave = tid >> 6, lane = tid & 63;
    int wm = wave >> 1, wn = wave & 1;
    int quad = lane >> 4, l16 = lane & 15;
    int row0 = blockIdx.x*64, col0 = blockIdx.y*64;
    floatx4 acc[2][2];
    #pragma unroll
    for (int i = 0; i < 2; ++i)
        #pragma unroll
        for (int j = 0; j < 2; ++j)
            acc[i][j] = (floatx4){0.f,0.f,0.f,0.f};

    int r  = tid >> 2;
    int kc = (tid & 3) * 16;
    int gr = row0 + r;
    int gc = col0 + r;
    const short8 z8 = {0,0,0,0,0,0,0,0};

    short8 ra0, ra1, rb0, rb1;
    if (gr < M) {
        const short8* p = (const short8*)(A + (size_t)gr*K + kc);
        ra0 = p[0]; ra1 = p[1];
    }
    if (gc < N) {
        const short8* p = (const short8*)(Wt + (size_t)gc*K + kc);
        rb0 = p[0]; rb1 = p[1];
    }

    for (int k0 = 0; k0 < K; k0 += 64) {
        short8 a0 = z8, a1 = z8;
        if (gr < M) { a0 = ra0; a1 = ra1; }
        *(short8*)&As[r*LDK + kc]     = a0;
        *(short8*)&As[r*LDK + kc + 8] = a1;
        short8 b0 = z8, b1 = z8;
        if (gc < N) { b0 = rb0; b1 = rb1; }
        *(short8*)&Bs[r*LDK + kc]     = b0;
        *(short8*)&Bs[r*LDK + kc + 8] = b1;
        // issue next k-step's loads before the barrier (latency hides under MFMA)
        int kn = k0 + 64;
        if (kn < K) {
            if (gr < M) {
                const short8* p = (const short8*)(A + (size_t)gr*K + kn + kc);
                ra0 = p[0]; ra1 = p[1];
            }
            if (gc < N) {
                const short8* p = (const short8*)(Wt + (size_t)gc*K + kn + kc);
                rb0 = p[0]; rb1 = p[1];
            }
        }
        __syncthreads();
        #pragma unroll
        for (int kb = 0; kb < 64; kb += 32) {
            short8 af[2], bfr[2];
            #pragma unroll
            for (int mi = 0; mi < 2; ++mi)
                af[mi] = *(const short8*)&As[(wm*32 + mi*16 + l16)*LDK + kb + quad*8];
            #pragma unroll
            for (int ni = 0; ni < 2; ++ni)
                bfr[ni] = *(const short8*)&Bs[(wn*32 + ni*16 + l16)*LDK + kb + quad*8];
            #pragma unroll
            for (int mi = 0; mi < 2; ++mi)
                #pragma unroll
                for (int ni = 0; ni < 2; ++ni)
                    acc[mi][ni] = __builtin_amdgcn_mfma_f32_16x16x32_bf16(
                        af[mi], bfr[ni], acc[mi][ni], 0, 0, 0);
        }
        __syncthreads();
    }
    // epilogue
    float vout[2][2][4];
    #pragma unroll
    for (int mi = 0; mi < 2; ++mi) {
        int rbase = row0 + wm*32 + mi*16 + quad*4;
        #pragma unroll
        for (int ni = 0; ni < 2; ++ni) {
            int c = col0 + wn*32 + ni*16 + l16;
            #pragma unroll
            for (int r2 = 0; r2 < 4; ++r2) {
                int rr = rbase + r2;
                float v = 0.f;
                if (c < N && rr < M) {
                    v = acc[mi][ni][r2];
                    if (bias) v += bias[c];
                    if (act) {  // tanh-gelu == v*sigmoid(2y)
                        float z = fminf(1.5957691216057308f*(v + 0.044715f*v*v*v), 60.f);
                        float e = __expf(z);
                        v = v * e / (e + 1.f);
                    }
                    if (res) v += res[(size_t)rr*N + c];
                }
                vout[mi][ni][r2] = v;
            }
        }
    }
    int fflag = 0;
    if (fin) fflag = flag[0];
    #pragma unroll
    for (int mi = 0; mi < 2; ++mi) {
        int rbase = row0 + wm*32 + mi*16 + quad*4;
        #pragma unroll
        for (int ni = 0; ni < 2; ++ni) {
            int c = col0 + wn*32 + ni*16 + l16;
            if (c >= N) continue;
            #pragma unroll
            for (int r2 = 0; r2 < 4; ++r2) {
                int rr = rbase + r2;
                if (rr >= M) continue;
                float v = vout[mi][ni][r2];
                if (fin) {
                    float w = isfinite(v) ? v : 0.f;
                    if (fflag) ((float*)fin)[(size_t)rr*N + c] = w;
                    else       ((bf16*)fin)[(size_t)rr*N + c] = __float2bfloat16(w);
                } else if (cbf) ((bf16*)Cout)[(size_t)rr*N + c] = __float2bfloat16(v);
                else            ((float*)Cout)[(size_t)rr*N + c] = v;
            }
        }
    }
    if (statacc) {
        #pragma unroll
        for (int mi = 0; mi < 2; ++mi) {
            int rbase = row0 + wm*32 + mi*16 + quad*4;
            #pragma unroll
            for (int r2 = 0; r2 < 4; ++r2) {
                int rr = rbase + r2;
                float sv = 0.f, sq = 0.f;
                #pragma unroll
                for (int ni = 0; ni < 2; ++ni) {
                    int c = col0 + wn*32 + ni*16 + l16;
                    float v = vout[mi][ni][r2];
                    if (sepe && rr < M) v += sepe[(size_t)rr*256 + c];
                    sv += v; sq += v*v;
                }
                #pragma unroll
                for (int o = 1; o < 16; o <<= 1) {
                    sv += __shfl_xor(sv, o, 64);
                    sq += __shfl_xor(sq, o, 64);
                }
                if (l16 == 0 && rr < M) {
                    atomicAdd(&statacc[rr].x, sv);
                    atomicAdd(&statacc[rr].y, sq);
                }
            }
        }
    }
}

// ---------- MFMA GEMM 128x128, both layers' value proj ----------
// 1D grid 2728 with XCD-aware swizzle: the 4 col-tiles of one row-panel map to
// bids {g*32+s, +8, +16, +24} -> all same (bid%8) -> same XCD -> A-panel L2 reuse.
// Epilogue stages C through LDS -> coalesced 16B head-major stores.
__global__ __launch_bounds__(256) void mgemm128_kernel(
    const short* __restrict__ A, const short* __restrict__ Wt,
    const float* __restrict__ bias, bf16* __restrict__ valall){
    const int K = 256;
    __shared__ short lds[2*128*LDK];   // As | Bs; reused as C-tile (128x136) in epilogue
    short* As = lds;
    short* Bs = lds + 128*LDK;
    int tid = threadIdx.x;
    int wave = tid >> 6, lane = tid & 63;
    int wm = wave >> 1, wn = wave & 1;
    int quad = lane >> 4, l16 = lane & 15;
    int bid = blockIdx.x;
    int panel, col;
    if (bid < 2720) {
        int g = bid >> 5, w = bid & 31;
        panel = g*8 + (w & 7);
        col = w >> 3;
    } else {
        int idx = bid - 2720;
        panel = 680 + (idx >> 2);
        col = idx & 3;
    }
    int row0 = panel*128, col0 = col*128;
    floatx4 acc[4][4];
    #pragma unroll
    for (int i = 0; i < 4; ++i)
        #pragma unroll
        for (int j = 0; j < 4; ++j)
            acc[i][j] = (floatx4){0.f,0.f,0.f,0.f};

    short8 pa[2][2], pb2[2][2];
    #pragma unroll
    for (int i = 0; i < 2; ++i) {
        int idx = tid + i*256;
        int rr = idx >> 2, kk = (idx & 3)*16;
        const short8* p = (const short8*)(A + (size_t)(row0+rr)*K + kk);
        pa[i][0] = p[0]; pa[i][1] = p[1];
        const short8* pb = (const short8*)(Wt + (size_t)(col0+rr)*K + kk);
        pb2[i][0] = pb[0]; pb2[i][1] = pb[1];
    }
    for (int k0 = 0; k0 < K; k0 += 64) {
        #pragma unroll
        for (int i = 0; i < 2; ++i) {
            int idx = tid + i*256;
            int rr = idx >> 2, kk = (idx & 3)*16;
            *(short8*)&As[rr*LDK + kk]     = pa[i][0];
            *(short8*)&As[rr*LDK + kk + 8] = pa[i][1];
            *(short8*)&Bs[rr*LDK + kk]     = pb2[i][0];
            *(short8*)&Bs[rr*LDK + kk + 8] = pb2[i][1];
        }
        int kn = k0 + 64;
        if (kn < K) {
            #pragma unroll
            for (int i = 0; i < 2; ++i) {
                int idx = tid + i*256;
                int rr = idx >> 2, kk = (idx & 3)*16;
                const short8* p = (const short8*)(A + (size_t)(row0+rr)*K + kn + kk);
                pa[i][0] = p[0]; pa[i][1] = p[1];
                const short8* pb = (const short8*)(Wt + (size_t)(col0+rr)*K + kn + kk);
                pb2[i][0] = pb[0]; pb2[i][1] = pb[1];
            }
        }
        __syncthreads();
        #pragma unroll
        for (int kb = 0; kb < 64; kb += 32) {
            short8 af[4], bfr[4];
            #pragma unroll
            for (int mi = 0; mi < 4; ++mi)
                af[mi] = *(const short8*)&As[(wm*64 + mi*16 + l16)*LDK + kb + quad*8];
            #pragma unroll
            for (int ni = 0; ni < 4; ++ni)
                bfr[ni] = *(const short8*)&Bs[(wn*64 + ni*16 + l16)*LDK + kb + quad*8];
            #pragma unroll
            for (int mi = 0; mi < 4; ++mi)
                #pragma unroll
                for (int ni = 0; ni < 4; ++ni)
                    acc[mi][ni] = __builtin_amdgcn_mfma_f32_16x16x32_bf16(
                        af[mi], bfr[ni], acc[mi][ni], 0, 0, 0);
        }
        __syncthreads();
    }
    // ---- epilogue: C tile -> LDS (bf16, +bias) -> coalesced head-major stores ----
    short* Cs = lds;   // 128 x 136 shorts = 34816 B <= 36864 B
    #pragma unroll
    for (int mi = 0; mi < 4; ++mi) {
        int lr = wm*64 + mi*16 + quad*4;
        #pragma unroll
        for (int ni = 0; ni < 4; ++ni) {
            int lc = wn*64 + ni*16 + l16;
            float bv = bias[col0 + lc];
            #pragma unroll
            for (int r2 = 0; r2 < 4; ++r2)
                Cs[(lr + r2)*136 + lc] = f2bs(acc[mi][ni][r2] + bv);
        }
    }
    __syncthreads();
    #pragma unroll
    for (int g = 0; g < 4; ++g) {
        int cbase = col0 + g*32;
        int l = cbase >> 8, h = (cbase & 255) >> 5;
        #pragma unroll
        for (int p = 0; p < 2; ++p) {
            int idx = p*256 + tid;
            int rr2 = idx >> 2;          // 0..127
            int dc = (idx & 3) * 8;      // 0,8,16,24
            short8 v = *(const short8*)&Cs[rr2*136 + g*32 + dc];
            int grr = row0 + rr2;
            unsigned n = (unsigned)grr / (unsigned)LIN;
            int pos = grr - (int)n*LIN;
            *(short8*)((short*)valall + (size_t)l*VLAYER
                       + ((size_t)(n*8+h)*LIN + pos)*32 + dc) = v;
        }
    }
}

// ---------- fused flash attention with K/V register prefetch ----------
__global__ __launch_bounds__(256) void fattn_kernel(const short* __restrict__ qkv,
                                                    bf16* __restrict__ out){
    int nh = blockIdx.y;
    int n = nh >> 3, h = nh & 7;
    int q0 = blockIdx.x * 64;
    __shared__ short Ks[64*40];
    __shared__ short VsT[32*72];
    __shared__ short Ps[64*72];
    int tid = threadIdx.x;
    int wave = tid >> 6, lane = tid & 63;
    int quad = lane >> 4, l16 = lane & 15;
    int r = tid >> 2, c8 = (tid & 3) * 8;
    const short8 z8 = {0,0,0,0,0,0,0,0};

    short8 qf = z8;
    {
        int gq = q0 + wave*16 + l16;
        if (gq < LQ) {
            short8 s = *(const short8*)(qkv + ((size_t)(n*LQ+gq))*768 + h*32 + quad*8);
            #pragma unroll
            for (int j = 0; j < 8; ++j) qf[j] = f2bs(bs2f(s[j]) * ATT_SCALE);
        }
    }
    floatx4 acc[2];
    acc[0] = (floatx4){0.f,0.f,0.f,0.f};
    acc[1] = (floatx4){0.f,0.f,0.f,0.f};
    float m[4], lsum[4];
    #pragma unroll
    for (int i = 0; i < 4; ++i) { m[i] = -3.0e38f; lsum[i] = 0.f; }

    short8 kvp = z8, vvp = z8;
    if (r < LQ) {
        const short* rp = qkv + ((size_t)(n*LQ+r))*768;
        kvp = *(const short8*)(rp + 256 + h*32 + c8);
        vvp = *(const short8*)(rp + 512 + h*32 + c8);
    }
    for (int k0 = 0; k0 < LQ; k0 += 64) {
        *(short8*)&Ks[r*40 + c8] = kvp;
        #pragma unroll
        for (int j = 0; j < 8; ++j) VsT[(c8+j)*72 + r] = vvp[j];
        short8 kvn = z8, vvn = z8;
        if (k0 + 64 < LQ) {
            int gk = k0 + 64 + r;
            if (gk < LQ) {
                const short* rp = qkv + ((size_t)(n*LQ+gk))*768;
                kvn = *(const short8*)(rp + 256 + h*32 + c8);
                vvn = *(const short8*)(rp + 512 + h*32 + c8);
            }
        }
        __syncthreads();
        floatx4 s4[4];
        #pragma unroll
        for (int kg = 0; kg < 4; ++kg) {
            short8 bfr = *(const short8*)&Ks[(kg*16 + l16)*40 + quad*8];
            s4[kg] = __builtin_amdgcn_mfma_f32_16x16x32_bf16(
                qf, bfr, (floatx4){0.f,0.f,0.f,0.f}, 0, 0, 0);
        }
        if (k0 + 64 > LQ) {
            #pragma unroll
            for (int kg = 0; kg < 4; ++kg)
                if (k0 + kg*16 + l16 >= LQ)
                    s4[kg] = (floatx4){-3.0e38f,-3.0e38f,-3.0e38f,-3.0e38f};
        }
        float fac[4], psum[4];
        #pragma unroll
        for (int r2 = 0; r2 < 4; ++r2) {
            float v = fmaxf(fmaxf(s4[0][r2], s4[1][r2]), fmaxf(s4[2][r2], s4[3][r2]));
            v = fmaxf(v, __shfl_xor(v, 1, 64));
            v = fmaxf(v, __shfl_xor(v, 2, 64));
            v = fmaxf(v, __shfl_xor(v, 4, 64));
            v = fmaxf(v, __shfl_xor(v, 8, 64));
            float mn = fmaxf(m[r2], v);
            fac[r2] = __expf(m[r2] - mn);
            m[r2] = mn;
            psum[r2] = 0.f;
        }
        #pragma unroll
        for (int kg = 0; kg < 4; ++kg)
            #pragma unroll
            for (int r2 = 0; r2 < 4; ++r2) {
                float pv = __expf(s4[kg][r2] - m[r2]);
                psum[r2] += pv;
                Ps[(wave*16 + quad*4 + r2)*72 + kg*16 + l16] = f2bs(pv);
            }
        #pragma unroll
        for (int r2 = 0; r2 < 4; ++r2) {
            psum[r2] += __shfl_xor(psum[r2], 1, 64);
            psum[r2] += __shfl_xor(psum[r2], 2, 64);
            psum[r2] += __shfl_xor(psum[r2], 4, 64);
            psum[r2] += __shfl_xor(psum[r2], 8, 64);
            lsum[r2] = lsum[r2]*fac[r2] + psum[r2];
        }
        #pragma unroll
        for (int ni = 0; ni < 2; ++ni)
            #pragma unroll
            for (int r2 = 0; r2 < 4; ++r2)
                acc[ni][r2] *= fac[r2];
        #pragma unroll
        for (int kb = 0; kb < 64; kb += 32) {
            short8 pf = *(const short8*)&Ps[(wave*16 + l16)*72 + kb + quad*8];
            #pragma unroll
            for (int ni = 0; ni < 2; ++ni) {
                short8 vf = *(const short8*)&VsT[(ni*16 + l16)*72 + kb + quad*8];
                acc[ni] = __builtin_amdgcn_mfma_f32_16x16x32_bf16(pf, vf, acc[ni], 0, 0, 0);
            }
        }
        __syncthreads();
        kvp = kvn; vvp = vvn;
    }
    #pragma unroll
    for (int r2 = 0; r2 < 4; ++r2) {
        int row = q0 + wave*16 + quad*4 + r2;
        if (row >= LQ) continue;
        float inv = 1.f / lsum[r2];
        #pragma unroll
        for (int ni = 0; ni < 2; ++ni)
            out[((size_t)(n*LQ+row))*256 + h*32 + ni*16 + l16] =
                __float2bfloat16(acc[ni][r2] * inv);
    }
}

// ---------- deformable sampling, head-major value layout ----------
__global__ __launch_bounds__(256) void sample2_kernel(
        const bf16* __restrict__ value, const float* __restrict__ offaw,
        const float* __restrict__ cp, bf16* __restrict__ out){
    int nq = blockIdx.x;
    int n = nq / LQ;
    int d = threadIdx.x & 31, h = threadIdx.x >> 5;
    float cx = cp[nq*2], cy = cp[nq*2+1];
    const float* rowp = offaw + (size_t)nq*480;
    float o0 = rowp[h*40 + d];
    float o1 = (d < 8) ? rowp[h*40 + 32 + d] : 0.f;
    float logit = (d < 20) ? rowp[320 + h*20 + d] : -3.0e38f;
    float mx = logit;
    #pragma unroll
    for (int off = 16; off; off >>= 1) mx = fmaxf(mx, __shfl_xor(mx, off, 32));
    float p = (d < 20) ? __expf(logit - mx) : 0.f;
    float sm = p;
    #pragma unroll
    for (int off = 16; off; off >>= 1) sm += __shfl_xor(sm, off, 32);
    p *= (1.f / sm);

    const int HW[5] = {128,64,32,16,8};
    const int ST[5] = {0,16384,20480,21504,21760};
    float acc = 0.f;
    #pragma unroll
    for (int l = 0; l < 5; ++l) {
        int hw = HW[l];
        float fhw = (float)hw;
        size_t vb = ((size_t)(n*8 + h)*LIN + ST[l])*32 + d;
        #pragma unroll
        for (int pi = 0; pi < 4; ++pi) {
            const int idx = l*4 + pi;
            float w  = __shfl(p, idx, 32);
            float ox = (2*idx < 32)   ? __shfl(o0, 2*idx, 32)   : __shfl(o1, 2*idx-32, 32);
            float oy = (2*idx+1 < 32) ? __shfl(o0, 2*idx+1, 32) : __shfl(o1, 2*idx+1-32, 32);
            float gx = cx*fhw + ox - 0.5f;
            float gy = cy*fhw + oy - 0.5f;
            float x0f = floorf(gx), y0f = floorf(gy);
            float lx = gx - x0f, ly = gy - y0f;
            int x0 = (int)x0f, y0 = (int)y0f;
            int x1 = x0 + 1, y1 = y0 + 1;
            bool bx0 = (unsigned)x0 < (unsigned)hw, bx1 = (unsigned)x1 < (unsigned)hw;
            bool by0 = (unsigned)y0 < (unsigned)hw, by1 = (unsigned)y1 < (unsigned)hw;
            int x0c = min(max(x0, 0), hw-1), x1c = min(max(x1, 0), hw-1);
            int y0c = min(max(y0, 0), hw-1), y1c = min(max(y1, 0), hw-1);
            float v00 = __bfloat162float(value[vb + (size_t)(y0c*hw + x0c)*32]);
            float v01 = __bfloat162float(value[vb + (size_t)(y0c*hw + x1c)*32]);
            float v10 = __bfloat162float(value[vb + (size_t)(y1c*hw + x0c)*32]);
            float v11 = __bfloat162float(value[vb + (size_t)(y1c*hw + x1c)*32]);
            float w00 = (bx0 && by0) ? (1.f-ly)*(1.f-lx)*w : 0.f;
            float w01 = (bx1 && by0) ? (1.f-ly)*lx*w       : 0.f;
            float w10 = (bx0 && by1) ? ly*(1.f-lx)*w       : 0.f;
            float w11 = (bx1 && by1) ? ly*lx*w             : 0.f;
            acc = fmaf(w00, v00, acc);
            acc = fmaf(w01, v01, acc);
            acc = fmaf(w10, v10, acc);
            acc = fmaf(w11, v11, acc);
        }
    }
    out[(size_t)nq*256 + h*32 + d] = __float2bfloat16(acc);
}

extern "C" void kernel_launch(void* const* d_in, const int* in_sizes, int n_in,
                              void* d_out, int out_size, void* d_ws, size_t ws_size,
                              hipStream_t stream){
    const void* x_raw  = d_in[0];
    const void* src    = d_in[1];
    const void* cp_raw = d_in[2];
    char* ws = (char*)d_ws;
    size_t off = 0;
    auto alloc = [&](size_t bytes){ size_t p = off; off += (bytes + 255) & ~(size_t)255; return p; };
    int*   flag  = (int*)(ws + alloc(256));
    float* xf    = (float*)(ws + alloc((size_t)ROWS_X*DIM*4));
    float* pe    = (float*)(ws + alloc((size_t)ROWS_X*DIM*4));
    bf16*  tmpb  = (bf16*)(ws + alloc((size_t)ROWS_X*DIM*2));
    bf16*  xab   = (bf16*)(ws + alloc((size_t)ROWS_X*DIM*2));
    bf16*  qkv   = (bf16*)(ws + alloc((size_t)ROWS_X*768*2));
    bf16*  ffh   = (bf16*)(ws + alloc((size_t)ROWS_X*MLPD*2));
    float* offaw = (float*)(ws + alloc((size_t)ROWS_X*480*4));
    float* cpf   = (float*)(ws + alloc((size_t)ROWS_X*2*4));
    float* oab   = (float*)(ws + alloc((size_t)2*480*4));
    float2* statbuf = (float2*)(ws + alloc((size_t)6*ROWS_X*8));
    float* qkvB  = (float*)(ws + alloc((size_t)2*768*4));
    float* ff1B  = (float*)(ws + alloc((size_t)2*512*4));
    float* valB  = (float*)(ws + alloc((size_t)2*256*4));
    const int sidx[13] = {5,6,7,8,11,12,13,19,21,22,23,25,27};
    const int ssz[13]  = {512,256,512,512,512,512,512,512,512,512,512,1024,512};
    float* sp[13];
    for (int j = 0; j < 13; ++j) sp[j] = (float*)(ws + alloc((size_t)ssz[j]*4));
    short* qkvT = (short*)(ws + alloc((size_t)2*768*256*2));
    short* outT = (short*)(ws + alloc((size_t)2*256*256*2));
    short* oawT = (short*)(ws + alloc((size_t)2*480*256*2));
    short* valT = (short*)(ws + alloc((size_t)2*256*256*2));
    short* opT  = (short*)(ws + alloc((size_t)2*256*256*2));
    short* ff1T = (short*)(ws + alloc((size_t)2*512*256*2));
    short* ff2T = (short*)(ws + alloc((size_t)2*256*512*2));
    bf16*  srcn = (bf16*)(ws + alloc((size_t)ROWS_SRC*DIM*2));
    bf16*  valall = (bf16*)(ws + alloc((size_t)2*ROWS_SRC*DIM*2));
    (void)ws_size; (void)in_sizes; (void)n_in; (void)out_size;

    float* ln2_g = sp[5];  float* ln2_b = sp[6];
    float* out_b = sp[4];
    float* op_b  = sp[8];
    float* ff_b2 = sp[12];

    detect_kernel<<<1, 256, 0, stream>>>(x_raw, flag);
    {
        SetupTab t;
        for (int j = 0; j < 13; ++j) { t.csrc[j] = d_in[sidx[j]]; t.cdst[j] = sp[j]; }
        t.cp = cp_raw; t.cpf = cpf;
        t.statz = (float*)(statbuf + ROWS_X);
        t.offb = d_in[15]; t.awb = d_in[17]; t.oab = oab;
        t.src = src; t.srcn = srcn;
        t.x = x_raw; t.posw = d_in[5]; t.posb = d_in[6];
        t.xf = xf; t.st = statbuf; t.xab = xab; t.pe = pe;
        const int widx[8] = {9,10,14,16,18,20,24,26};
        short* wdst[8] = {qkvT, outT, oawT, oawT, valT, opT, ff1T, ff2T};
        const void* wscl[8] = {d_in[7], nullptr, nullptr, nullptr, d_in[12], nullptr, d_in[22], nullptr};
        for (int j = 0; j < 8; ++j) { t.wsrc[j] = d_in[widx[j]]; t.wdst[j] = wdst[j]; t.wscl[j] = wscl[j]; }
        t.bfW[0] = d_in[9];  t.bfBv[0] = d_in[8];  t.bfBase[0] = nullptr;  t.bfDst[0] = qkvB;
        t.bfW[1] = d_in[24]; t.bfBv[1] = d_in[23]; t.bfBase[1] = d_in[25]; t.bfDst[1] = ff1B;
        t.bfW[2] = d_in[18]; t.bfBv[2] = d_in[13]; t.bfBase[2] = d_in[19]; t.bfDst[2] = valB;
        setup_kernel<<<16724, 256, 0, stream>>>(t, flag);
    }
    // both layers' value projections in one dispatch (XCD-grouped 1D grid)
    mgemm128_kernel<<<(ROWS_SRC/128)*4, 256, 0, stream>>>(
        (const short*)srcn, valT, valB, valall);

    int gmx = (ROWS_X + 63) / 64;   // 63
    for (int i = 0; i < 2; ++i) {
        float2* stA = statbuf + (size_t)(i ? 3 : 0)*ROWS_X;   // attn LN sums (x+pe)
        float2* stO = statbuf + (size_t)(i ? 4 : 1)*ROWS_X;   // offaw LN sums
        float2* stF = statbuf + (size_t)(i ? 5 : 2)*ROWS_X;   // ff LN sums
        // qkv = xab @ (g1.qkv_w) + b1@qkv_w   (xab pre-normalized; L0 from setup)
        if (i == 1)
            xnorm_kernel<<<ROWS_X/4, 256, 0, stream>>>(xf, pe, nullptr, stA,
                                                       nullptr, nullptr, xab);
        mgemm_kernel<<<dim3(gmx,12), 256, 0, stream>>>(
            (const short*)xab, qkvT + (size_t)i*768*256, qkvB + i*768, nullptr, qkv,
            ROWS_X, 256, 768, 0, 1, nullptr, nullptr, nullptr, flag);
        fattn_kernel<<<dim3(16,32), 256, 0, stream>>>((const short*)qkv, tmpb);
        // out-proj (+res into xf), accumulate offaw-LN sums of new xf
        mgemm_kernel<<<dim3(gmx,4), 256, 0, stream>>>(
            (const short*)tmpb, outT + (size_t)i*256*256, out_b + i*DIM, xf, xf,
            ROWS_X, 256, 256, 0, 0, stO, nullptr, nullptr, flag);
        // xab = LN(xf;ln2) + pe ; offaw = xab @ [off|aw]_w + oab
        xnorm_kernel<<<ROWS_X/4, 256, 0, stream>>>(xf, nullptr, pe, stO,
                                                   ln2_g + i*DIM, ln2_b + i*DIM, xab);
        mgemm_kernel<<<dim3(gmx,8), 256, 0, stream>>>(
            (const short*)xab, oawT + (size_t)i*480*256, oab + i*480, nullptr, offaw,
            ROWS_X, 256, 480, 0, 0, nullptr, nullptr, nullptr, flag);
        sample2_kernel<<<ROWS_X, 256, 0, stream>>>(
            valall + (size_t)i*VLAYER, offaw, cpf, tmpb);
        // op-proj (+res into xf), accumulate ff-LN sums of new xf
        mgemm_kernel<<<dim3(gmx,4), 256, 0, stream>>>(
            (const short*)tmpb, opT + (size_t)i*256*256, op_b + i*DIM, xf, xf,
            ROWS_X, 256, 256, 0, 0, stF, nullptr, nullptr, flag);
        // xab = normalize(xf) ; ffh = gelu( xab @ (g3.ff_w1) + (b3@ff_w1 + ff_b1) )
        xnorm_kernel<<<ROWS_X/4, 256, 0, stream>>>(xf, nullptr, nullptr, stF,
                                                   nullptr, nullptr, xab);
        mgemm_kernel<<<dim3(gmx,8), 256, 0, stream>>>(
            (const short*)xab, ff1T + (size_t)i*512*256, ff1B + i*MLPD, nullptr, ffh,
            ROWS_X, 256, 512, 1, 1, nullptr, nullptr, nullptr, flag);
        // ff2 (+res). layer0: accumulate next-layer attn sums (xf+pe). layer1: write d_out.
        if (i == 0) {
            mgemm_kernel<<<dim3(gmx,4), 256, 0, stream>>>(
                (const short*)ffh, ff2T + (size_t)i*256*512, ff_b2 + i*DIM, xf, xf,
                ROWS_X, 512, 256, 0, 0, statbuf + (size_t)3*ROWS_X, pe, nullptr, flag);
        } else {
            mgemm_kernel<<<dim3(gmx,4), 256, 0, stream>>>(
                (const short*)ffh, ff2T + (size_t)i*256*512, ff_b2 + i*DIM, xf, xf,
                ROWS_X, 512, 256, 0, 0, nullptr, nullptr, d_out, flag);
        }
    }
}